// Round 16
// baseline (354.755 us; speedup 1.0000x reference)
//
#include <hip/hip_runtime.h>
#include <math.h>

#define CC 128
#define HH 64
#define RBD 8
#define WDIM 512

typedef __attribute__((ext_vector_type(8))) short short8v;
typedef __attribute__((ext_vector_type(4))) float f32x4;

__device__ __forceinline__ float silu_f(float x) {
    return x / (1.0f + __expf(-x));
}

__device__ __forceinline__ unsigned short f2bf(float x) {
    unsigned int b = __float_as_uint(x);
    unsigned int r = (b + 0x7FFFu + ((b >> 16) & 1u)) >> 16;
    return (unsigned short)r;
}

__device__ __forceinline__ float bf2f(unsigned short u) {
    return __uint_as_float(((unsigned int)u) << 16);
}

// ---------------- prep: fragment tables + transposed node-out weights ---------
__global__ void k_prep(const float* __restrict__ w0, const float* __restrict__ w1,
                       const float* __restrict__ w2, const float* __restrict__ w3,
                       const float* __restrict__ W20, const float* __restrict__ W21,
                       const float* __restrict__ Wsk0, const float* __restrict__ Wsk1,
                       float* __restrict__ w0T, float* __restrict__ w1T,
                       float* __restrict__ w2T, float* __restrict__ w3T,
                       unsigned short* __restrict__ w3bs,
                       unsigned short* __restrict__ w0b,
                       unsigned short* __restrict__ w1b,
                       unsigned short* __restrict__ w2b,
                       float* __restrict__ W20T, float* __restrict__ W21T,
                       float* __restrict__ Wsk0T, float* __restrict__ Wsk1T,
                       int NS) {
    int i = blockIdx.x * blockDim.x + threadIdx.x;
    if (i < 64 * 8) { int m = i / 8, k = i % 8; w0T[i] = w0[k * 64 + m]; }
    if (i < 64 * 64) { int m = i / 64, k = i % 64; w1T[i] = w1[k * 64 + m]; w2T[i] = w2[k * 64 + m]; }
    if (i < 512 * 64) { int j = i / 64, k = i % 64; w3T[i] = w3[k * 512 + j]; }
    if (i < 32768) {
        int t = i >> 10, ch = (i >> 9) & 1, lane = (i >> 3) & 63, j = i & 7;
        int k = ch * 32 + 8 * (lane >> 4) + j;
        int n = t * 16 + (lane & 15);
        w3bs[i] = f2bf(w3[k * 512 + n]);
    }
    if (i < 2048) {
        int t = i >> 9, lane = (i >> 3) & 63, j = i & 7;
        int k = 8 * (lane >> 4) + j;
        int col = t * 16 + (lane & 15);
        w0b[i] = (k < RBD) ? f2bf(w0[k * 64 + col]) : (unsigned short)0;
    }
    if (i < 4096) {
        int f = i >> 9, lane = (i >> 3) & 63, j = i & 7;
        int ks = f >> 2, t = f & 3;
        int k = ks * 32 + 8 * (lane >> 4) + j;
        int col = t * 16 + (lane & 15);
        w1b[i] = f2bf(w1[k * 64 + col]);
        w2b[i] = f2bf(w2[k * 64 + col]);
    }
    // transposed node-out weights: [d][cc] rows
    if (i < 65536) { int d = i >> 8, cc = i & 255; W20T[i] = W20[cc * 256 + d]; }
    if (i < 32768) { int d = i >> 8, cc = i & 255; W21T[i] = W21[cc * 128 + d]; }
    if (i < NS * 32768) {
        int s = i >> 15, r = i & 32767, d = r >> 7, cc = r & 127;
        W20T[0] += 0.f; // no-op guard keep
        Wsk0T[i] = Wsk0[((size_t)(s * 128 + cc)) * 256 + d];
    }
    if (i < NS * 16384) {
        int s = i >> 14, r = i & 16383, d = r >> 7, cc = r & 127;
        Wsk1T[i] = Wsk1[((size_t)(s * 128 + cc)) * 128 + d];
    }
}

// ---------------- CSR build (edges by receiver) + species hist (merged) -------
__global__ void k_hist(const int* __restrict__ rcv, int* __restrict__ deg, int E_,
                       const int* __restrict__ species, int* __restrict__ scnt, int N) {
    int e = blockIdx.x * blockDim.x + threadIdx.x;
    if (e < E_) atomicAdd(&deg[rcv[e]], 1);
    if (e < N) atomicAdd(&scnt[species[e]], 1);
}

__global__ __launch_bounds__(1024) void k_scan(const int* __restrict__ deg,
                                               int* __restrict__ off, int N) {
    __shared__ int s[1024];
    int t = threadIdx.x;
    int b = t * 4;
    int a0 = (b + 0 < N) ? deg[b + 0] : 0;
    int a1 = (b + 1 < N) ? deg[b + 1] : 0;
    int a2 = (b + 2 < N) ? deg[b + 2] : 0;
    int a3 = (b + 3 < N) ? deg[b + 3] : 0;
    int part = a0 + a1 + a2 + a3;
    s[t] = part;
    __syncthreads();
    for (int d = 1; d < 1024; d <<= 1) {
        int v = (t >= d) ? s[t - d] : 0;
        __syncthreads();
        s[t] += v;
        __syncthreads();
    }
    int excl = s[t] - part;
    if (b + 0 <= N) off[b + 0] = excl;
    if (b + 1 <= N) off[b + 1] = excl + a0;
    if (b + 2 <= N) off[b + 2] = excl + a0 + a1;
    if (b + 3 <= N) off[b + 3] = excl + a0 + a1 + a2;
}

__global__ void k_sscan(const int* __restrict__ scnt, int* __restrict__ soff, int NS) {
    if (threadIdx.x == 0) {
        int acc = 0;
        for (int s = 0; s < NS; s++) { soff[s] = acc; acc += scnt[s]; }
        soff[NS] = acc;
    }
}

__global__ void k_scatter(const int* __restrict__ rcv, const int* __restrict__ off,
                          int* __restrict__ cur, int* __restrict__ elist, int E_,
                          const int* __restrict__ species, const int* __restrict__ soff,
                          int* __restrict__ scur, int* __restrict__ nlist, int N) {
    int e = blockIdx.x * blockDim.x + threadIdx.x;
    if (e < E_) {
        int r = rcv[e];
        int p = atomicAdd(&cur[r], 1);
        elist[off[r] + p] = e;
    }
    if (e < N) {
        int s = species[e];
        int p = atomicAdd(&scur[s], 1);
        nlist[soff[s] + p] = e;
    }
}

// ---------------- edge meta: permuted unit vectors + senders ----------------
__global__ void k_emeta(const int* __restrict__ elist, const int* __restrict__ snd,
                        const float* __restrict__ evec,
                        float4* __restrict__ up, int* __restrict__ sp, int E_) {
    int p = blockIdx.x * blockDim.x + threadIdx.x;
    if (p >= E_) return;
    int e = elist[p];
    float e0 = evec[(size_t)e * 3 + 0];
    float e1 = evec[(size_t)e * 3 + 1];
    float e2 = evec[(size_t)e * 3 + 2];
    float rn = sqrtf(e0 * e0 + e1 * e1 + e2 * e2);
    float inv = 1.0f / fmaxf(rn, 1e-12f);
    up[p] = make_float4(e0 * inv, e1 * inv, e2 * inv, 0.f);
    sp[p] = snd[e];
}

// ---------------- node linear (planar y1: [3][N][C]) — 2 nodes/block ----------
__global__ __launch_bounds__(128) void k_node_lin(
    const float* __restrict__ xs, const float* __restrict__ xv,
    const float* __restrict__ W10, const float* __restrict__ W11,
    float* __restrict__ y0, float* __restrict__ y1, int N) {
    const int d = threadIdx.x;
    const int n0 = blockIdx.x * 2;
    const int NP = N * CC;
    const float inv_c = 0.08838834764831845f;
    float a0[2] = {0.f, 0.f};
    float av[2][3] = {};
    #pragma unroll 4
    for (int c = 0; c < CC; c++) {
        float w10 = W10[c * CC + d];
        float w11 = W11[c * CC + d];
        #pragma unroll
        for (int n = 0; n < 2; n++) {
            a0[n] += xs[(n0 + n) * CC + c] * w10;
            #pragma unroll
            for (int i = 0; i < 3; i++)
                av[n][i] += xv[((n0 + n) * CC + c) * 3 + i] * w11;
        }
    }
    #pragma unroll
    for (int n = 0; n < 2; n++) {
        y0[(n0 + n) * CC + d] = a0[n] * inv_c;
        #pragma unroll
        for (int i = 0; i < 3; i++)
            y1[i * NP + (n0 + n) * CC + d] = av[n][i] * inv_c;
    }
}

// ---------------- shared VALU MLP body (tiers B/C) ----------------
__device__ __forceinline__ void layer64(const float4* a, float4* b,
                                        const float* __restrict__ W) {
    #pragma unroll
    for (int m = 0; m < 16; m++) {
        float s0 = 0.f, s1 = 0.f, s2 = 0.f, s3 = 0.f;
        const float* w0p = W + (4 * m + 0) * 64;
        const float* w1p = W + (4 * m + 1) * 64;
        const float* w2p = W + (4 * m + 2) * 64;
        const float* w3p = W + (4 * m + 3) * 64;
        #pragma unroll
        for (int k = 0; k < 16; k++) {
            float4 av = a[k];
            s0 += av.x * w0p[4 * k + 0] + av.y * w0p[4 * k + 1] + av.z * w0p[4 * k + 2] + av.w * w0p[4 * k + 3];
            s1 += av.x * w1p[4 * k + 0] + av.y * w1p[4 * k + 1] + av.z * w1p[4 * k + 2] + av.w * w1p[4 * k + 3];
            s2 += av.x * w2p[4 * k + 0] + av.y * w2p[4 * k + 1] + av.z * w2p[4 * k + 2] + av.w * w2p[4 * k + 3];
            s3 += av.x * w3p[4 * k + 0] + av.y * w3p[4 * k + 1] + av.z * w3p[4 * k + 2] + av.w * w3p[4 * k + 3];
        }
        b[m] = make_float4(silu_f(s0), silu_f(s1), silu_f(s2), silu_f(s3));
    }
}

__device__ __forceinline__ void mlp_body(
    const float* __restrict__ rb, int e,
    const float* __restrict__ w0T, const float* __restrict__ w1T,
    const float* __restrict__ w2T, float4* a) {
    float rbv[RBD];
    #pragma unroll
    for (int k = 0; k < RBD; k++) rbv[k] = rb[(size_t)e * RBD + k];
    float4 b[16];
    #pragma unroll
    for (int m = 0; m < 16; m++) {
        float s0 = 0.f, s1 = 0.f, s2 = 0.f, s3 = 0.f;
        #pragma unroll
        for (int k = 0; k < RBD; k++) {
            float rv = rbv[k];
            s0 += rv * w0T[(4 * m + 0) * RBD + k];
            s1 += rv * w0T[(4 * m + 1) * RBD + k];
            s2 += rv * w0T[(4 * m + 2) * RBD + k];
            s3 += rv * w0T[(4 * m + 3) * RBD + k];
        }
        a[m] = make_float4(silu_f(s0), silu_f(s1), silu_f(s2), silu_f(s3));
    }
    layer64(a, b, w1T);
    layer64(b, a, w2T);   // a holds h2
}

// ---------------- tier A: fused MFMA MLP + w3 GEMM -> pair-packed Wq ---------
__global__ __launch_bounds__(256) void k_mlpw3(
    const float* __restrict__ rb, const int* __restrict__ elist,
    const unsigned short* __restrict__ w0b, const unsigned short* __restrict__ w1b,
    const unsigned short* __restrict__ w2b, const unsigned short* __restrict__ w3bs,
    unsigned int* __restrict__ Wq, int E_) {
    const int lane = threadIdx.x & 63;
    const int wv = threadIdx.x >> 6;
    const int rbk = blockIdx.x * 4 + wv;
    const int col = lane & 15;
    const int grp = lane >> 4;

    __shared__ unsigned short hbuf[4][16][72];

    short8v a0 = (short8v){0, 0, 0, 0, 0, 0, 0, 0};
    if (grp == 0) {
        int e = elist[rbk * 16 + col];
        const float* rp = rb + (size_t)e * RBD;
        #pragma unroll
        for (int j = 0; j < RBD; j++) a0[j] = (short)f2bf(rp[j]);
    }
    f32x4 acc[4];
    {
        const unsigned short* bp = w0b + (size_t)lane * 8;
        #pragma unroll
        for (int t = 0; t < 4; t++) {
            short8v b = *(const short8v*)(bp + (size_t)t * 512);
            acc[t] = __builtin_amdgcn_mfma_f32_16x16x32_bf16(
                a0, b, (f32x4){0.f, 0.f, 0.f, 0.f}, 0, 0, 0);
        }
    }
    #pragma unroll
    for (int t = 0; t < 4; t++)
        #pragma unroll
        for (int r = 0; r < 4; r++)
            hbuf[wv][grp * 4 + r][t * 16 + col] = f2bf(silu_f(acc[t][r]));
    __syncthreads();

    {
        short8v aA = *(const short8v*)&hbuf[wv][col][8 * grp];
        short8v aB = *(const short8v*)&hbuf[wv][col][32 + 8 * grp];
        const unsigned short* bp = w1b + (size_t)lane * 8;
        #pragma unroll
        for (int t = 0; t < 4; t++) {
            short8v b0 = *(const short8v*)(bp + (size_t)(0 + t) * 512);
            short8v b1 = *(const short8v*)(bp + (size_t)(4 + t) * 512);
            f32x4 c = __builtin_amdgcn_mfma_f32_16x16x32_bf16(
                aA, b0, (f32x4){0.f, 0.f, 0.f, 0.f}, 0, 0, 0);
            acc[t] = __builtin_amdgcn_mfma_f32_16x16x32_bf16(aB, b1, c, 0, 0, 0);
        }
    }
    __syncthreads();
    #pragma unroll
    for (int t = 0; t < 4; t++)
        #pragma unroll
        for (int r = 0; r < 4; r++)
            hbuf[wv][grp * 4 + r][t * 16 + col] = f2bf(silu_f(acc[t][r]));
    __syncthreads();

    {
        short8v aA = *(const short8v*)&hbuf[wv][col][8 * grp];
        short8v aB = *(const short8v*)&hbuf[wv][col][32 + 8 * grp];
        const unsigned short* bp = w2b + (size_t)lane * 8;
        #pragma unroll
        for (int t = 0; t < 4; t++) {
            short8v b0 = *(const short8v*)(bp + (size_t)(0 + t) * 512);
            short8v b1 = *(const short8v*)(bp + (size_t)(4 + t) * 512);
            f32x4 c = __builtin_amdgcn_mfma_f32_16x16x32_bf16(
                aA, b0, (f32x4){0.f, 0.f, 0.f, 0.f}, 0, 0, 0);
            acc[t] = __builtin_amdgcn_mfma_f32_16x16x32_bf16(aB, b1, c, 0, 0, 0);
        }
    }
    __syncthreads();
    #pragma unroll
    for (int t = 0; t < 4; t++)
        #pragma unroll
        for (int r = 0; r < 4; r++)
            hbuf[wv][grp * 4 + r][t * 16 + col] = f2bf(silu_f(acc[t][r]));
    __syncthreads();

    short8v A0 = *(const short8v*)&hbuf[wv][col][8 * grp];
    short8v A1 = *(const short8v*)&hbuf[wv][col][32 + 8 * grp];

    f32x4 wacc[32];
    #pragma unroll
    for (int t = 0; t < 32; t++) wacc[t] = (f32x4){0.f, 0.f, 0.f, 0.f};

    const unsigned short* bbase = w3bs + (size_t)lane * 8;
    #pragma unroll
    for (int t = 0; t < 32; t++) {
        short8v b0 = *(const short8v*)(bbase + (size_t)(t * 2 + 0) * 512);
        short8v b1 = *(const short8v*)(bbase + (size_t)(t * 2 + 1) * 512);
        wacc[t] = __builtin_amdgcn_mfma_f32_16x16x32_bf16(A0, b0, wacc[t], 0, 0, 0);
        wacc[t] = __builtin_amdgcn_mfma_f32_16x16x32_bf16(A1, b1, wacc[t], 0, 0, 0);
    }

    const int rowq = grp * 4;
    const int jbase = rbk * 16 + rowq;
    #pragma unroll
    for (int t = 0; t < 16; t++) {
        #pragma unroll
        for (int rr = 0; rr < 4; rr++) {
            unsigned lo = f2bf(wacc[t][rr]);
            unsigned hi = f2bf(wacc[t + 16][rr]);
            Wq[(size_t)(jbase + rr) * 256 + t * 16 + col] = lo | (hi << 16);
        }
    }
}

// ---------------- tier A gather: edge-major, 4-edge unrolled, planar out -----
__global__ __launch_bounds__(256) void k_gather_em(
    const int* __restrict__ off, const float4* __restrict__ up,
    const int* __restrict__ sp, const unsigned int* __restrict__ Wq,
    const float* __restrict__ y0, const float* __restrict__ y1, int NP, int N256,
    float* __restrict__ agg_s, float* __restrict__ agg_v) {
    const int r = blockIdx.x;
    const int tid = threadIdx.x;
    const int half = tid >> 7;
    const int c = tid & 127;
    const int start = off[r];
    const int end = off[r + 1];

    float accs = 0.f, av0 = 0.f, av1 = 0.f, av2 = 0.f;
    const float SQ3 = 1.7320508075688772f;

    auto proc = [&](unsigned wq, float4 u, int s) {
        float wa = bf2f((unsigned short)(wq & 0xFFFFu));
        float wb = bf2f((unsigned short)(wq >> 16));
        if (half == 0) {
            float f = y0[(size_t)s * CC + c];
            accs += f * wa;
            float bb = f * wb * SQ3;
            av0 += bb * u.x; av1 += bb * u.y; av2 += bb * u.z;
        } else {
            float f0 = y1[0 * NP + s * CC + c];
            float f1 = y1[1 * NP + s * CC + c];
            float f2 = y1[2 * NP + s * CC + c];
            accs += (f0 * u.x + f1 * u.y + f2 * u.z) * wa;
            av0 += f0 * wb; av1 += f1 * wb; av2 += f2 * wb;
        }
    };

    int j = start;
    for (; j + 4 <= end; j += 4) {
        unsigned wq0 = Wq[(size_t)(j + 0) * 256 + tid];
        unsigned wq1 = Wq[(size_t)(j + 1) * 256 + tid];
        unsigned wq2 = Wq[(size_t)(j + 2) * 256 + tid];
        unsigned wq3 = Wq[(size_t)(j + 3) * 256 + tid];
        float4 u0 = up[j + 0], u1 = up[j + 1], u2 = up[j + 2], u3 = up[j + 3];
        int s0 = __builtin_amdgcn_readfirstlane(sp[j + 0]);
        int s1 = __builtin_amdgcn_readfirstlane(sp[j + 1]);
        int s2 = __builtin_amdgcn_readfirstlane(sp[j + 2]);
        int s3 = __builtin_amdgcn_readfirstlane(sp[j + 3]);
        proc(wq0, u0, s0);
        proc(wq1, u1, s1);
        proc(wq2, u2, s2);
        proc(wq3, u3, s3);
    }
    for (; j < end; j++) {
        unsigned wq = Wq[(size_t)j * 256 + tid];
        float4 u = up[j];
        int s = __builtin_amdgcn_readfirstlane(sp[j]);
        proc(wq, u, s);
    }

    agg_s[(size_t)r * 256 + tid] = accs;
    agg_v[0 * N256 + (size_t)r * 256 + tid] = av0;
    agg_v[1 * N256 + (size_t)r * 256 + tid] = av1;
    agg_v[2 * N256 + (size_t)r * 256 + tid] = av2;
}

// ---------------- tier B: VALU writer (grouped layout) + its gather ----------------
__global__ __launch_bounds__(256) void k_mlp_wp(
    const float* __restrict__ rb, const int* __restrict__ elist,
    const float* __restrict__ w0T, const float* __restrict__ w1T,
    const float* __restrict__ w2T, const float* __restrict__ w3T,
    unsigned short* __restrict__ Wp, int E_) {
    int p = blockIdx.x * blockDim.x + threadIdx.x;
    if (p >= E_) return;
    int e = elist[p];
    const int c0 = blockIdx.y * 128;

    float4 a[16];
    mlp_body(rb, e, w0T, w1T, w2T, a);

    const size_t E4 = (size_t)E_ * 4;
    for (int c = c0; c < c0 + 128; c += 8) {
        float s[8];
        #pragma unroll
        for (int q = 0; q < 8; q++) {
            const float* rp = w3T + (size_t)(c + q) * 64;
            float t0 = 0.f, t1 = 0.f, t2 = 0.f, t3 = 0.f;
            #pragma unroll
            for (int k = 0; k < 16; k++) {
                float4 h = a[k];
                t0 += h.x * rp[4 * k + 0];
                t1 += h.y * rp[4 * k + 1];
                t2 += h.z * rp[4 * k + 2];
                t3 += h.w * rp[4 * k + 3];
            }
            s[q] = (t0 + t1) + (t2 + t3);
        }
        ushort4 pk0 = make_ushort4(f2bf(s[0]), f2bf(s[1]), f2bf(s[2]), f2bf(s[3]));
        ushort4 pk1 = make_ushort4(f2bf(s[4]), f2bf(s[5]), f2bf(s[6]), f2bf(s[7]));
        *(ushort4*)(Wp + (size_t)(c >> 2) * E4 + (size_t)p * 4) = pk0;
        *(ushort4*)(Wp + (size_t)((c >> 2) + 1) * E4 + (size_t)p * 4) = pk1;
    }
}

__global__ __launch_bounds__(512, 2) void k_gather_wg(
    const int* __restrict__ off, const int* __restrict__ elist,
    const int* __restrict__ snd, const float* __restrict__ evec,
    const unsigned short* __restrict__ Wp, int E_,
    const float* __restrict__ y0, const float* __restrict__ y1, int NP, int N256,
    float* __restrict__ agg_s, float* __restrict__ agg_v) {
    const int r = blockIdx.x;
    const int tid = threadIdx.x;
    const int part = tid >> 7;
    const int c = tid & 127;

    const int start = off[r];
    const int end = off[r + 1];

    const unsigned short* __restrict__ wstream =
        Wp + (size_t)(tid >> 2) * ((size_t)E_ * 4) + (tid & 3);

    float acc0 = 0.f, acc1 = 0.f, acc2 = 0.f;
    const float SQ3 = 1.7320508075688772f;

    #pragma unroll 2
    for (int j = start; j < end; j++) {
        int e = elist[j];
        e = __builtin_amdgcn_readfirstlane(e);
        int s = snd[e];
        s = __builtin_amdgcn_readfirstlane(s);

        float e0 = evec[(size_t)e * 3 + 0];
        float e1 = evec[(size_t)e * 3 + 1];
        float e2 = evec[(size_t)e * 3 + 2];
        float rn = sqrtf(e0 * e0 + e1 * e1 + e2 * e2);
        float inv = 1.0f / fmaxf(rn, 1e-12f);
        float ux = e0 * inv, uy = e1 * inv, uz = e2 * inv;

        float w = bf2f(wstream[(size_t)j * 4]);

        if (part == 0) {
            acc0 += y0[(size_t)s * CC + c] * w;
        } else if (part == 1) {
            float f = y1[0 * NP + s * CC + c] * ux
                    + y1[1 * NP + s * CC + c] * uy
                    + y1[2 * NP + s * CC + c] * uz;
            acc0 += f * w;
        } else if (part == 2) {
            float bb = y0[(size_t)s * CC + c] * w * SQ3;
            acc0 += bb * ux; acc1 += bb * uy; acc2 += bb * uz;
        } else {
            acc0 += y1[0 * NP + s * CC + c] * w;
            acc1 += y1[1 * NP + s * CC + c] * w;
            acc2 += y1[2 * NP + s * CC + c] * w;
        }
    }

    if (part == 0) {
        agg_s[(size_t)r * 256 + c] = acc0;
    } else if (part == 1) {
        agg_s[(size_t)r * 256 + 128 + c] = acc0;
    } else if (part == 2) {
        agg_v[0 * N256 + (size_t)r * 256 + c] = acc0;
        agg_v[1 * N256 + (size_t)r * 256 + c] = acc1;
        agg_v[2 * N256 + (size_t)r * 256 + c] = acc2;
    } else {
        agg_v[0 * N256 + (size_t)r * 256 + 128 + c] = acc0;
        agg_v[1 * N256 + (size_t)r * 256 + 128 + c] = acc1;
        agg_v[2 * N256 + (size_t)r * 256 + 128 + c] = acc2;
    }
}

// ---------------- tier C: f32 h2 fallback ----------------
__global__ void k_mlp(const float* __restrict__ rb,
                      const float* __restrict__ w0T, const float* __restrict__ w1T,
                      const float* __restrict__ w2T,
                      float* __restrict__ h2, int E_) {
    int e = blockIdx.x * blockDim.x + threadIdx.x;
    if (e >= E_) return;
    float4 a[16];
    mlp_body(rb, e, w0T, w1T, w2T, a);
    float4* out = (float4*)(h2 + (size_t)e * HH);
    #pragma unroll
    for (int q = 0; q < 16; q++) out[q] = a[q];
}

__global__ __launch_bounds__(512, 1) void k_gather_h2(
    const int* __restrict__ off, const int* __restrict__ elist,
    const int* __restrict__ snd, const float* __restrict__ evec,
    const float* __restrict__ h2, const float* __restrict__ w3T,
    const float* __restrict__ y0, const float* __restrict__ y1, int NP, int N256,
    float* __restrict__ agg_s, float* __restrict__ agg_v) {
    const int r = blockIdx.x;
    const int tid = threadIdx.x;
    const int part = tid >> 7;
    const int c = tid & 127;

    const float4* wp = (const float4*)(w3T + (size_t)tid * 64);
    const int start = off[r];
    const int end = off[r + 1];

    float acc0 = 0.f, acc1 = 0.f, acc2 = 0.f;
    const float SQ3 = 1.7320508075688772f;

    for (int j = start; j < end; j++) {
        int e = elist[j];
        e = __builtin_amdgcn_readfirstlane(e);
        int s = snd[e];
        s = __builtin_amdgcn_readfirstlane(s);

        float e0 = evec[(size_t)e * 3 + 0];
        float e1 = evec[(size_t)e * 3 + 1];
        float e2 = evec[(size_t)e * 3 + 2];
        float rn = sqrtf(e0 * e0 + e1 * e1 + e2 * e2);
        float inv = 1.0f / fmaxf(rn, 1e-12f);
        float ux = e0 * inv, uy = e1 * inv, uz = e2 * inv;

        const float4* __restrict__ hp = (const float4*)(h2 + ((size_t)e << 6));
        float ws0 = 0.f, ws1 = 0.f, ws2 = 0.f, ws3 = 0.f;
        #pragma unroll
        for (int k = 0; k < 16; k++) {
            float4 h = hp[k];
            float4 wv = wp[k];
            ws0 += h.x * wv.x; ws1 += h.y * wv.y; ws2 += h.z * wv.z; ws3 += h.w * wv.w;
        }
        float w = (ws0 + ws1) + (ws2 + ws3);

        if (part == 0) {
            acc0 += y0[(size_t)s * CC + c] * w;
        } else if (part == 1) {
            float f = y1[0 * NP + s * CC + c] * ux
                    + y1[1 * NP + s * CC + c] * uy
                    + y1[2 * NP + s * CC + c] * uz;
            acc0 += f * w;
        } else if (part == 2) {
            float bb = y0[(size_t)s * CC + c] * w * SQ3;
            acc0 += bb * ux; acc1 += bb * uy; acc2 += bb * uz;
        } else {
            acc0 += y1[0 * NP + s * CC + c] * w;
            acc1 += y1[1 * NP + s * CC + c] * w;
            acc2 += y1[2 * NP + s * CC + c] * w;
        }
    }

    if (part == 0) {
        agg_s[(size_t)r * 256 + c] = acc0;
    } else if (part == 1) {
        agg_s[(size_t)r * 256 + 128 + c] = acc0;
    } else if (part == 2) {
        agg_v[0 * N256 + (size_t)r * 256 + c] = acc0;
        agg_v[1 * N256 + (size_t)r * 256 + c] = acc1;
        agg_v[2 * N256 + (size_t)r * 256 + c] = acc2;
    } else {
        agg_v[0 * N256 + (size_t)r * 256 + 128 + c] = acc0;
        agg_v[1 * N256 + (size_t)r * 256 + 128 + c] = acc1;
        agg_v[2 * N256 + (size_t)r * 256 + 128 + c] = acc2;
    }
}

// ---------------- node output: transposed weights + planar LDS ----------------
// Species-sorted 4-node blocks; weights read as float4 rows [d][cc] (VMEM /4);
// agg_v is planar [3][N*256] -> LDS av_p[i][n][cc] staged coalesced; phase-B
// LDS reads are float4 uniform broadcasts.
__global__ __launch_bounds__(256) void k_node_out(
    const float* __restrict__ agg_s, const float* __restrict__ agg_v,
    const float* __restrict__ xs, const float* __restrict__ xv,
    const float* __restrict__ W20T, const float* __restrict__ W21T,
    const float* __restrict__ Wsk0T, const float* __restrict__ Wsk1T,
    const int* __restrict__ nlist, const int* __restrict__ species,
    float* __restrict__ out, int N, int N256) {
    const int tid = threadIdx.x;
    const int b0 = blockIdx.x * 4;
    const int nid0 = nlist[min(b0 + 0, N - 1)];
    const int nid1 = nlist[min(b0 + 1, N - 1)];
    const int nid2 = nlist[min(b0 + 2, N - 1)];
    const int nid3 = nlist[min(b0 + 3, N - 1)];

    __shared__ float as_l[4 * 256];
    __shared__ float av_p[12 * 256];   // [(i*4+n)][cc]
    __shared__ float xs_l[4 * 128];
    __shared__ float xv_p[12 * 128];   // [(i*4+n)][cc]
    __shared__ float s_l[4 * 256];

    {
        as_l[0 * 256 + tid] = agg_s[(size_t)nid0 * 256 + tid];
        as_l[1 * 256 + tid] = agg_s[(size_t)nid1 * 256 + tid];
        as_l[2 * 256 + tid] = agg_s[(size_t)nid2 * 256 + tid];
        as_l[3 * 256 + tid] = agg_s[(size_t)nid3 * 256 + tid];
        #pragma unroll
        for (int i = 0; i < 3; i++) {
            av_p[(i * 4 + 0) * 256 + tid] = agg_v[i * N256 + (size_t)nid0 * 256 + tid];
            av_p[(i * 4 + 1) * 256 + tid] = agg_v[i * N256 + (size_t)nid1 * 256 + tid];
            av_p[(i * 4 + 2) * 256 + tid] = agg_v[i * N256 + (size_t)nid2 * 256 + tid];
            av_p[(i * 4 + 3) * 256 + tid] = agg_v[i * N256 + (size_t)nid3 * 256 + tid];
        }
        if (tid < 128) {
            xs_l[0 * 128 + tid] = xs[(size_t)nid0 * 128 + tid];
            xs_l[1 * 128 + tid] = xs[(size_t)nid1 * 128 + tid];
            xs_l[2 * 128 + tid] = xs[(size_t)nid2 * 128 + tid];
            xs_l[3 * 128 + tid] = xs[(size_t)nid3 * 128 + tid];
            #pragma unroll
            for (int i = 0; i < 3; i++) {
                xv_p[(i * 4 + 0) * 128 + tid] = xv[((size_t)nid0 * 128 + tid) * 3 + i];
                xv_p[(i * 4 + 1) * 128 + tid] = xv[((size_t)nid1 * 128 + tid) * 3 + i];
                xv_p[(i * 4 + 2) * 128 + tid] = xv[((size_t)nid2 * 128 + tid) * 3 + i];
                xv_p[(i * 4 + 3) * 128 + tid] = xv[((size_t)nid3 * 128 + tid) * 3 + i];
            }
        }
    }
    const int sp0 = species[nid0], sp1 = species[nid1];
    const int sp2 = species[nid2], sp3 = species[nid3];
    const bool uni = (sp0 == sp1) && (sp1 == sp2) && (sp2 == sp3);
    __syncthreads();

    const float k_mat = 0.17677669529663687f * 0.0625f; // inv_nb * inv_2c
    const float inv_c = 0.08838834764831845f;

    // ---- phase A: s (256 per node), thread = channel d ----
    {
        const int d = tid;
        float am[4] = {0.f, 0.f, 0.f, 0.f};
        const float* wrow = W20T + (size_t)d * 256;
        for (int cc = 0; cc < 256; cc += 4) {
            float4 w = *(const float4*)&wrow[cc];
            #pragma unroll
            for (int n = 0; n < 4; n++) {
                float4 a = *(const float4*)&as_l[n * 256 + cc];
                am[n] += a.x * w.x + a.y * w.y + a.z * w.z + a.w * w.w;
            }
        }
        float ak[4] = {0.f, 0.f, 0.f, 0.f};
        if (uni) {
            const float* wp = Wsk0T + ((size_t)sp0 * 256 + d) * 128;
            for (int cc = 0; cc < 128; cc += 4) {
                float4 w = *(const float4*)&wp[cc];
                #pragma unroll
                for (int n = 0; n < 4; n++) {
                    float4 x = *(const float4*)&xs_l[n * 128 + cc];
                    ak[n] += x.x * w.x + x.y * w.y + x.z * w.z + x.w * w.w;
                }
            }
        } else {
            const float* wpA = Wsk0T + ((size_t)sp0 * 256 + d) * 128;
            const float* wpB = Wsk0T + ((size_t)sp1 * 256 + d) * 128;
            const float* wpC = Wsk0T + ((size_t)sp2 * 256 + d) * 128;
            const float* wpD = Wsk0T + ((size_t)sp3 * 256 + d) * 128;
            for (int cc = 0; cc < 128; cc += 4) {
                float4 wA = *(const float4*)&wpA[cc];
                float4 wB = *(const float4*)&wpB[cc];
                float4 wC = *(const float4*)&wpC[cc];
                float4 wD = *(const float4*)&wpD[cc];
                float4 x0 = *(const float4*)&xs_l[0 * 128 + cc];
                float4 x1 = *(const float4*)&xs_l[1 * 128 + cc];
                float4 x2 = *(const float4*)&xs_l[2 * 128 + cc];
                float4 x3 = *(const float4*)&xs_l[3 * 128 + cc];
                ak[0] += x0.x * wA.x + x0.y * wA.y + x0.z * wA.z + x0.w * wA.w;
                ak[1] += x1.x * wB.x + x1.y * wB.y + x1.z * wB.z + x1.w * wB.w;
                ak[2] += x2.x * wC.x + x2.y * wC.y + x2.z * wC.z + x2.w * wC.w;
                ak[3] += x3.x * wD.x + x3.y * wD.y + x3.z * wD.z + x3.w * wD.w;
            }
        }
        #pragma unroll
        for (int n = 0; n < 4; n++) s_l[n * 256 + d] = am[n] * k_mat + ak[n] * inv_c;
    }
    __syncthreads();

    if (tid < 128) {
        out[(size_t)nid0 * 512 + tid] = silu_f(s_l[0 * 256 + tid]);
        out[(size_t)nid1 * 512 + tid] = silu_f(s_l[1 * 256 + tid]);
        out[(size_t)nid2 * 512 + tid] = silu_f(s_l[2 * 256 + tid]);
        out[(size_t)nid3 * 512 + tid] = silu_f(s_l[3 * 256 + tid]);
    }

    // ---- phase B: v (128x3 per node); half = tid>>7 handles 2 nodes ----
    {
        const int d = tid & 127;
        const int half = tid >> 7;
        const int nA = half ? nid2 : nid0;
        const int nB = half ? nid3 : nid1;
        const int sA = half ? sp2 : sp0;
        const int sB = half ? sp3 : sp1;
        const int la = half ? 2 : 0;
        const int lb = half ? 3 : 1;

        float am[2][3] = {};
        const float* wrow = W21T + (size_t)d * 256;
        for (int cc = 0; cc < 256; cc += 4) {
            float4 w = *(const float4*)&wrow[cc];
            #pragma unroll
            for (int i = 0; i < 3; i++) {
                float4 aA = *(const float4*)&av_p[(i * 4 + la) * 256 + cc];
                float4 aB = *(const float4*)&av_p[(i * 4 + lb) * 256 + cc];
                am[0][i] += aA.x * w.x + aA.y * w.y + aA.z * w.z + aA.w * w.w;
                am[1][i] += aB.x * w.x + aB.y * w.y + aB.z * w.z + aB.w * w.w;
            }
        }
        float ak[2][3] = {};
        {
            const float* wpA = Wsk1T + ((size_t)sA * 128 + d) * 128;
            const float* wpB = Wsk1T + ((size_t)sB * 128 + d) * 128;
            for (int cc = 0; cc < 128; cc += 4) {
                float4 wA = *(const float4*)&wpA[cc];
                float4 wB = *(const float4*)&wpB[cc];
                #pragma unroll
                for (int i = 0; i < 3; i++) {
                    float4 xA = *(const float4*)&xv_p[(i * 4 + la) * 128 + cc];
                    float4 xB = *(const float4*)&xv_p[(i * 4 + lb) * 128 + cc];
                    ak[0][i] += xA.x * wA.x + xA.y * wA.y + xA.z * wA.z + xA.w * wA.w;
                    ak[1][i] += xB.x * wB.x + xB.y * wB.y + xB.z * wB.z + xB.w * wB.w;
                }
            }
        }
        float gA = silu_f(s_l[la * 256 + 128 + d]);
        float gB = silu_f(s_l[lb * 256 + 128 + d]);
        float* oA = out + (size_t)nA * 512 + 128 + d * 3;
        float* oB = out + (size_t)nB * 512 + 128 + d * 3;
        #pragma unroll
        for (int i = 0; i < 3; i++) {
            oA[i] = (am[0][i] * k_mat + ak[0][i] * inv_c) * gA;
            oB[i] = (am[1][i] * k_mat + ak[1][i] * inv_c) * gB;
        }
    }
}

extern "C" void kernel_launch(void* const* d_in, const int* in_sizes, int n_in,
                              void* d_out, int out_size, void* d_ws, size_t ws_size,
                              hipStream_t stream) {
    const float* xs   = (const float*)d_in[0];
    const float* xv   = (const float*)d_in[1];
    const float* evec = (const float*)d_in[2];
    const float* rb   = (const float*)d_in[3];
    const float* W10  = (const float*)d_in[4];
    const float* W11  = (const float*)d_in[5];
    const float* w0   = (const float*)d_in[6];
    const float* w1   = (const float*)d_in[7];
    const float* w2   = (const float*)d_in[8];
    const float* w3   = (const float*)d_in[9];
    const float* W20  = (const float*)d_in[10];
    const float* W21  = (const float*)d_in[11];
    const float* Wsk0 = (const float*)d_in[12];
    const float* Wsk1 = (const float*)d_in[13];
    const int* species = (const int*)d_in[14];
    const int* snd = (const int*)d_in[15];
    const int* rcv = (const int*)d_in[16];

    const int N = in_sizes[0] / CC;   // 4000
    const int E = in_sizes[2] / 3;    // 128000
    const int NP = N * CC;
    const int N256 = N * 256;
    int NS = in_sizes[12] / (CC * 2 * CC);   // 5
    if (NS < 1) NS = 1;
    if (NS > 16) NS = 16;

    float* ws   = (float*)d_ws;
    float* y0   = ws;
    float* y1   = y0 + (size_t)N * CC;
    float* aggs = y1 + (size_t)N * CC * 3;
    float* aggv = aggs + (size_t)N * 2 * CC;          // planar [3][N*256]
    float* w0T  = aggv + (size_t)N * 2 * CC * 3;
    float* w1T  = w0T + 64 * 8;
    float* w2T  = w1T + 64 * 64;
    float* w3T  = w2T + 64 * 64;
    unsigned short* w3bs = (unsigned short*)(w3T + 512 * 64);
    unsigned short* w0b  = w3bs + 32768;
    unsigned short* w1b  = w0b + 2048;
    unsigned short* w2b  = w1b + 4096;
    float* W20T  = (float*)(w2b + 4096);              // 65536
    float* W21T  = W20T + 65536;                      // 32768
    float* Wsk0T = W21T + 32768;                      // NS*32768
    float* Wsk1T = Wsk0T + (size_t)NS * 32768;        // NS*16384
    int*   deg  = (int*)(Wsk1T + (size_t)NS * 16384);
    int*   cur  = deg + 4096;
    int*   off  = cur + 4096;
    int*   elist = off + 4160;
    float4* up  = (float4*)(elist + E);
    int*   sp   = (int*)(up + E);
    int*   scnt = sp + E;                    // 64
    int*   soff = scnt + 64;                 // 72
    int*   scur = soff + 72;                 // 64
    int*   nlist = scur + 64;                // N
    void*  big  = (void*)(nlist + N);

    size_t base_bytes = (size_t)((char*)big - (char*)d_ws);
    size_t wq_bytes   = (size_t)E * 256 * sizeof(unsigned int);
    size_t need_A = base_bytes + wq_bytes;
    size_t need_B = base_bytes + (size_t)E * WDIM * sizeof(unsigned short);

    unsigned int*   Wq  = (unsigned int*)big;
    unsigned short* Wp  = (unsigned short*)big;

    hipMemsetAsync(deg, 0, 2 * 4096 * sizeof(int), stream);
    hipMemsetAsync(scnt, 0, 200 * sizeof(int), stream);
    hipLaunchKernelGGL(k_hist, dim3((E + 255) / 256), dim3(256), 0, stream,
                       rcv, deg, E, species, scnt, N);
    hipLaunchKernelGGL(k_scan, dim3(1), dim3(1024), 0, stream, deg, off, N);
    hipLaunchKernelGGL(k_sscan, dim3(1), dim3(64), 0, stream, scnt, soff, NS);
    hipLaunchKernelGGL(k_scatter, dim3((E + 255) / 256), dim3(256), 0, stream,
                       rcv, off, cur, elist, E, species, soff, scur, nlist, N);
    hipLaunchKernelGGL(k_prep, dim3(768), dim3(256), 0, stream,
                       w0, w1, w2, w3, W20, W21, Wsk0, Wsk1,
                       w0T, w1T, w2T, w3T, w3bs, w0b, w1b, w2b,
                       W20T, W21T, Wsk0T, Wsk1T, NS);
    hipLaunchKernelGGL(k_node_lin, dim3(N / 2), dim3(128), 0, stream,
                       xs, xv, W10, W11, y0, y1, N);

    if (ws_size >= need_A && (E % 64) == 0) {
        hipLaunchKernelGGL(k_emeta, dim3((E + 255) / 256), dim3(256), 0, stream,
                           elist, snd, evec, up, sp, E);
        hipLaunchKernelGGL(k_mlpw3, dim3(E / 64), dim3(256), 0, stream,
                           rb, elist, w0b, w1b, w2b, w3bs, Wq, E);
        hipLaunchKernelGGL(k_gather_em, dim3(N), dim3(256), 0, stream,
                           off, up, sp, Wq, y0, y1, NP, N256, aggs, aggv);
    } else if (ws_size >= need_B) {
        hipLaunchKernelGGL(k_mlp_wp, dim3((E + 255) / 256, 4), dim3(256), 0, stream,
                           rb, elist, w0T, w1T, w2T, w3T, Wp, E);
        hipLaunchKernelGGL(k_gather_wg, dim3(N), dim3(512), 0, stream,
                           off, elist, snd, evec, Wp, E, y0, y1, NP, N256, aggs, aggv);
    } else {
        hipLaunchKernelGGL(k_mlp, dim3((E + 255) / 256), dim3(256), 0, stream,
                           rb, w0T, w1T, w2T, (float*)big, E);
        hipLaunchKernelGGL(k_gather_h2, dim3(N), dim3(512), 0, stream,
                           off, elist, snd, evec, (const float*)big, w3T,
                           y0, y1, NP, N256, aggs, aggv);
    }

    hipLaunchKernelGGL(k_node_out, dim3((N + 3) / 4), dim3(256), 0, stream,
                       aggs, aggv, xs, xv, W20T, W21T, Wsk0T, Wsk1T, nlist, species,
                       (float*)d_out, N, N256);
}

// Round 17
// 296.825 us; speedup vs baseline: 1.1952x; 1.1952x over previous
//
#include <hip/hip_runtime.h>
#include <math.h>

#define CC 128
#define HH 64
#define RBD 8
#define WDIM 512

typedef __attribute__((ext_vector_type(8))) short short8v;
typedef __attribute__((ext_vector_type(4))) float f32x4;

__device__ __forceinline__ float silu_f(float x) {
    return x / (1.0f + __expf(-x));
}

__device__ __forceinline__ unsigned short f2bf(float x) {
    unsigned int b = __float_as_uint(x);
    unsigned int r = (b + 0x7FFFu + ((b >> 16) & 1u)) >> 16;
    return (unsigned short)r;
}

__device__ __forceinline__ float bf2f(unsigned short u) {
    return __uint_as_float(((unsigned int)u) << 16);
}

// ---------------- prep: transposed weights (tier B/C) + MFMA fragment tables ----
__global__ void k_prep(const float* __restrict__ w0, const float* __restrict__ w1,
                       const float* __restrict__ w2, const float* __restrict__ w3,
                       float* __restrict__ w0T, float* __restrict__ w1T,
                       float* __restrict__ w2T, float* __restrict__ w3T,
                       unsigned short* __restrict__ w3bs,
                       unsigned short* __restrict__ w0b,
                       unsigned short* __restrict__ w1b,
                       unsigned short* __restrict__ w2b) {
    int i = blockIdx.x * blockDim.x + threadIdx.x;
    if (i < 64 * 8) { int m = i / 8, k = i % 8; w0T[i] = w0[k * 64 + m]; }
    if (i < 64 * 64) { int m = i / 64, k = i % 64; w1T[i] = w1[k * 64 + m]; w2T[i] = w2[k * 64 + m]; }
    if (i < 512 * 64) { int j = i / 64, k = i % 64; w3T[i] = w3[k * 512 + j]; }
    if (i < 32768) {
        int t = i >> 10, ch = (i >> 9) & 1, lane = (i >> 3) & 63, j = i & 7;
        int k = ch * 32 + 8 * (lane >> 4) + j;
        int n = t * 16 + (lane & 15);
        w3bs[i] = f2bf(w3[k * 512 + n]);
    }
    if (i < 2048) {
        int t = i >> 9, lane = (i >> 3) & 63, j = i & 7;
        int k = 8 * (lane >> 4) + j;
        int col = t * 16 + (lane & 15);
        w0b[i] = (k < RBD) ? f2bf(w0[k * 64 + col]) : (unsigned short)0;
    }
    if (i < 4096) {
        int f = i >> 9, lane = (i >> 3) & 63, j = i & 7;
        int ks = f >> 2, t = f & 3;
        int k = ks * 32 + 8 * (lane >> 4) + j;
        int col = t * 16 + (lane & 15);
        w1b[i] = f2bf(w1[k * 64 + col]);
        w2b[i] = f2bf(w2[k * 64 + col]);
    }
}

// ---------------- CSR build (merged edge + species histograms) ----------------
__global__ void k_hist(const int* __restrict__ rcv, int* __restrict__ deg, int E_,
                       const int* __restrict__ species, int* __restrict__ scnt, int N) {
    int e = blockIdx.x * blockDim.x + threadIdx.x;
    if (e < E_) atomicAdd(&deg[rcv[e]], 1);
    if (e < N) atomicAdd(&scnt[species[e]], 1);
}

__global__ __launch_bounds__(1024) void k_scan(const int* __restrict__ deg,
                                               int* __restrict__ off, int N,
                                               const int* __restrict__ scnt,
                                               int* __restrict__ soff, int NS) {
    __shared__ int s[1024];
    int t = threadIdx.x;
    int b = t * 4;
    int a0 = (b + 0 < N) ? deg[b + 0] : 0;
    int a1 = (b + 1 < N) ? deg[b + 1] : 0;
    int a2 = (b + 2 < N) ? deg[b + 2] : 0;
    int a3 = (b + 3 < N) ? deg[b + 3] : 0;
    int part = a0 + a1 + a2 + a3;
    s[t] = part;
    __syncthreads();
    for (int d = 1; d < 1024; d <<= 1) {
        int v = (t >= d) ? s[t - d] : 0;
        __syncthreads();
        s[t] += v;
        __syncthreads();
    }
    int excl = s[t] - part;
    if (b + 0 <= N) off[b + 0] = excl;
    if (b + 1 <= N) off[b + 1] = excl + a0;
    if (b + 2 <= N) off[b + 2] = excl + a0 + a1;
    if (b + 3 <= N) off[b + 3] = excl + a0 + a1 + a2;
    if (t == 0) {
        int acc = 0;
        for (int q = 0; q < NS; q++) { soff[q] = acc; acc += scnt[q]; }
        soff[NS] = acc;
    }
}

__global__ void k_scatter(const int* __restrict__ rcv, const int* __restrict__ off,
                          int* __restrict__ cur, int* __restrict__ elist, int E_,
                          const int* __restrict__ species, const int* __restrict__ soff,
                          int* __restrict__ scur, int* __restrict__ nlist, int N) {
    int e = blockIdx.x * blockDim.x + threadIdx.x;
    if (e < E_) {
        int r = rcv[e];
        int p = atomicAdd(&cur[r], 1);
        elist[off[r] + p] = e;
    }
    if (e < N) {
        int s = species[e];
        int p = atomicAdd(&scur[s], 1);
        nlist[soff[s] + p] = e;
    }
}

// ---------------- node linear (planar y1: [3][N][C]) — 2 nodes/block ----------
__global__ __launch_bounds__(128) void k_node_lin(
    const float* __restrict__ xs, const float* __restrict__ xv,
    const float* __restrict__ W10, const float* __restrict__ W11,
    float* __restrict__ y0, float* __restrict__ y1, int N) {
    const int d = threadIdx.x;
    const int n0 = blockIdx.x * 2;
    const int NP = N * CC;
    const float inv_c = 0.08838834764831845f;
    float a0[2] = {0.f, 0.f};
    float av[2][3] = {};
    #pragma unroll 4
    for (int c = 0; c < CC; c++) {
        float w10 = W10[c * CC + d];
        float w11 = W11[c * CC + d];
        #pragma unroll
        for (int n = 0; n < 2; n++) {
            a0[n] += xs[(n0 + n) * CC + c] * w10;
            #pragma unroll
            for (int i = 0; i < 3; i++)
                av[n][i] += xv[((n0 + n) * CC + c) * 3 + i] * w11;
        }
    }
    #pragma unroll
    for (int n = 0; n < 2; n++) {
        y0[(n0 + n) * CC + d] = a0[n] * inv_c;
        #pragma unroll
        for (int i = 0; i < 3; i++)
            y1[i * NP + (n0 + n) * CC + d] = av[n][i] * inv_c;
    }
}

// ---------------- shared VALU MLP body (tiers B/C) ----------------
__device__ __forceinline__ void layer64(const float4* a, float4* b,
                                        const float* __restrict__ W) {
    #pragma unroll
    for (int m = 0; m < 16; m++) {
        float s0 = 0.f, s1 = 0.f, s2 = 0.f, s3 = 0.f;
        const float* w0p = W + (4 * m + 0) * 64;
        const float* w1p = W + (4 * m + 1) * 64;
        const float* w2p = W + (4 * m + 2) * 64;
        const float* w3p = W + (4 * m + 3) * 64;
        #pragma unroll
        for (int k = 0; k < 16; k++) {
            float4 av = a[k];
            s0 += av.x * w0p[4 * k + 0] + av.y * w0p[4 * k + 1] + av.z * w0p[4 * k + 2] + av.w * w0p[4 * k + 3];
            s1 += av.x * w1p[4 * k + 0] + av.y * w1p[4 * k + 1] + av.z * w1p[4 * k + 2] + av.w * w1p[4 * k + 3];
            s2 += av.x * w2p[4 * k + 0] + av.y * w2p[4 * k + 1] + av.z * w2p[4 * k + 2] + av.w * w2p[4 * k + 3];
            s3 += av.x * w3p[4 * k + 0] + av.y * w3p[4 * k + 1] + av.z * w3p[4 * k + 2] + av.w * w3p[4 * k + 3];
        }
        b[m] = make_float4(silu_f(s0), silu_f(s1), silu_f(s2), silu_f(s3));
    }
}

__device__ __forceinline__ void mlp_body(
    const float* __restrict__ rb, int e,
    const float* __restrict__ w0T, const float* __restrict__ w1T,
    const float* __restrict__ w2T, float4* a) {
    float rbv[RBD];
    #pragma unroll
    for (int k = 0; k < RBD; k++) rbv[k] = rb[(size_t)e * RBD + k];
    float4 b[16];
    #pragma unroll
    for (int m = 0; m < 16; m++) {
        float s0 = 0.f, s1 = 0.f, s2 = 0.f, s3 = 0.f;
        #pragma unroll
        for (int k = 0; k < RBD; k++) {
            float rv = rbv[k];
            s0 += rv * w0T[(4 * m + 0) * RBD + k];
            s1 += rv * w0T[(4 * m + 1) * RBD + k];
            s2 += rv * w0T[(4 * m + 2) * RBD + k];
            s3 += rv * w0T[(4 * m + 3) * RBD + k];
        }
        a[m] = make_float4(silu_f(s0), silu_f(s1), silu_f(s2), silu_f(s3));
    }
    layer64(a, b, w1T);
    layer64(b, a, w2T);   // a holds h2
}

// ---------------- tier A: fused MFMA MLP + w3 GEMM + emeta -> Wq --------------
// Block handles 64 edges (4 waves x 16). Threads <64 also produce edge meta
// (unit vectors + senders) for the block's 64 elist positions (folds k_emeta).
__global__ __launch_bounds__(256) void k_mlpw3(
    const float* __restrict__ rb, const int* __restrict__ elist,
    const int* __restrict__ snd, const float* __restrict__ evec,
    const unsigned short* __restrict__ w0b, const unsigned short* __restrict__ w1b,
    const unsigned short* __restrict__ w2b, const unsigned short* __restrict__ w3bs,
    unsigned int* __restrict__ Wq, float4* __restrict__ up, int* __restrict__ sp,
    int E_) {
    const int lane = threadIdx.x & 63;
    const int wv = threadIdx.x >> 6;
    const int rbk = blockIdx.x * 4 + wv;
    const int col = lane & 15;
    const int grp = lane >> 4;

    // folded emeta: threads 0..63 handle the block's 64 edges
    if (threadIdx.x < 64) {
        int p = blockIdx.x * 64 + threadIdx.x;
        if (p < E_) {
            int e = elist[p];
            float e0 = evec[(size_t)e * 3 + 0];
            float e1 = evec[(size_t)e * 3 + 1];
            float e2 = evec[(size_t)e * 3 + 2];
            float rn = sqrtf(e0 * e0 + e1 * e1 + e2 * e2);
            float inv = 1.0f / fmaxf(rn, 1e-12f);
            up[p] = make_float4(e0 * inv, e1 * inv, e2 * inv, 0.f);
            sp[p] = snd[e];
        }
    }

    __shared__ unsigned short hbuf[4][16][72];

    short8v a0 = (short8v){0, 0, 0, 0, 0, 0, 0, 0};
    if (grp == 0) {
        int e = elist[rbk * 16 + col];
        const float* rp = rb + (size_t)e * RBD;
        #pragma unroll
        for (int j = 0; j < RBD; j++) a0[j] = (short)f2bf(rp[j]);
    }
    f32x4 acc[4];
    {
        const unsigned short* bp = w0b + (size_t)lane * 8;
        #pragma unroll
        for (int t = 0; t < 4; t++) {
            short8v b = *(const short8v*)(bp + (size_t)t * 512);
            acc[t] = __builtin_amdgcn_mfma_f32_16x16x32_bf16(
                a0, b, (f32x4){0.f, 0.f, 0.f, 0.f}, 0, 0, 0);
        }
    }
    #pragma unroll
    for (int t = 0; t < 4; t++)
        #pragma unroll
        for (int r = 0; r < 4; r++)
            hbuf[wv][grp * 4 + r][t * 16 + col] = f2bf(silu_f(acc[t][r]));
    __syncthreads();

    {
        short8v aA = *(const short8v*)&hbuf[wv][col][8 * grp];
        short8v aB = *(const short8v*)&hbuf[wv][col][32 + 8 * grp];
        const unsigned short* bp = w1b + (size_t)lane * 8;
        #pragma unroll
        for (int t = 0; t < 4; t++) {
            short8v b0 = *(const short8v*)(bp + (size_t)(0 + t) * 512);
            short8v b1 = *(const short8v*)(bp + (size_t)(4 + t) * 512);
            f32x4 c = __builtin_amdgcn_mfma_f32_16x16x32_bf16(
                aA, b0, (f32x4){0.f, 0.f, 0.f, 0.f}, 0, 0, 0);
            acc[t] = __builtin_amdgcn_mfma_f32_16x16x32_bf16(aB, b1, c, 0, 0, 0);
        }
    }
    __syncthreads();
    #pragma unroll
    for (int t = 0; t < 4; t++)
        #pragma unroll
        for (int r = 0; r < 4; r++)
            hbuf[wv][grp * 4 + r][t * 16 + col] = f2bf(silu_f(acc[t][r]));
    __syncthreads();

    {
        short8v aA = *(const short8v*)&hbuf[wv][col][8 * grp];
        short8v aB = *(const short8v*)&hbuf[wv][col][32 + 8 * grp];
        const unsigned short* bp = w2b + (size_t)lane * 8;
        #pragma unroll
        for (int t = 0; t < 4; t++) {
            short8v b0 = *(const short8v*)(bp + (size_t)(0 + t) * 512);
            short8v b1 = *(const short8v*)(bp + (size_t)(4 + t) * 512);
            f32x4 c = __builtin_amdgcn_mfma_f32_16x16x32_bf16(
                aA, b0, (f32x4){0.f, 0.f, 0.f, 0.f}, 0, 0, 0);
            acc[t] = __builtin_amdgcn_mfma_f32_16x16x32_bf16(aB, b1, c, 0, 0, 0);
        }
    }
    __syncthreads();
    #pragma unroll
    for (int t = 0; t < 4; t++)
        #pragma unroll
        for (int r = 0; r < 4; r++)
            hbuf[wv][grp * 4 + r][t * 16 + col] = f2bf(silu_f(acc[t][r]));
    __syncthreads();

    short8v A0 = *(const short8v*)&hbuf[wv][col][8 * grp];
    short8v A1 = *(const short8v*)&hbuf[wv][col][32 + 8 * grp];

    f32x4 wacc[32];
    #pragma unroll
    for (int t = 0; t < 32; t++) wacc[t] = (f32x4){0.f, 0.f, 0.f, 0.f};

    const unsigned short* bbase = w3bs + (size_t)lane * 8;
    #pragma unroll
    for (int t = 0; t < 32; t++) {
        short8v b0 = *(const short8v*)(bbase + (size_t)(t * 2 + 0) * 512);
        short8v b1 = *(const short8v*)(bbase + (size_t)(t * 2 + 1) * 512);
        wacc[t] = __builtin_amdgcn_mfma_f32_16x16x32_bf16(A0, b0, wacc[t], 0, 0, 0);
        wacc[t] = __builtin_amdgcn_mfma_f32_16x16x32_bf16(A1, b1, wacc[t], 0, 0, 0);
    }

    const int rowq = grp * 4;
    const int jbase = rbk * 16 + rowq;
    #pragma unroll
    for (int t = 0; t < 16; t++) {
        #pragma unroll
        for (int rr = 0; rr < 4; rr++) {
            unsigned lo = f2bf(wacc[t][rr]);
            unsigned hi = f2bf(wacc[t + 16][rr]);
            Wq[(size_t)(jbase + rr) * 256 + t * 16 + col] = lo | (hi << 16);
        }
    }
}

// ---------------- tier A gather: edge-major, 4-edge unrolled ----------------
__global__ __launch_bounds__(256, 4) void k_gather_em(
    const int* __restrict__ off, const float4* __restrict__ up,
    const int* __restrict__ sp, const unsigned int* __restrict__ Wq,
    const float* __restrict__ y0, const float* __restrict__ y1, int NP,
    float* __restrict__ agg_s, float* __restrict__ agg_v) {
    const int r = blockIdx.x;
    const int tid = threadIdx.x;
    const int half = tid >> 7;
    const int c = tid & 127;
    const int start = off[r];
    const int end = off[r + 1];

    float accs = 0.f, av0 = 0.f, av1 = 0.f, av2 = 0.f;
    const float SQ3 = 1.7320508075688772f;

    auto proc = [&](unsigned wq, float4 u, int s) {
        float wa = bf2f((unsigned short)(wq & 0xFFFFu));
        float wb = bf2f((unsigned short)(wq >> 16));
        if (half == 0) {
            float f = y0[(size_t)s * CC + c];
            accs += f * wa;
            float bb = f * wb * SQ3;
            av0 += bb * u.x; av1 += bb * u.y; av2 += bb * u.z;
        } else {
            float f0 = y1[0 * NP + s * CC + c];
            float f1 = y1[1 * NP + s * CC + c];
            float f2 = y1[2 * NP + s * CC + c];
            accs += (f0 * u.x + f1 * u.y + f2 * u.z) * wa;
            av0 += f0 * wb; av1 += f1 * wb; av2 += f2 * wb;
        }
    };

    int j = start;
    for (; j + 4 <= end; j += 4) {
        unsigned wq0 = Wq[(size_t)(j + 0) * 256 + tid];
        unsigned wq1 = Wq[(size_t)(j + 1) * 256 + tid];
        unsigned wq2 = Wq[(size_t)(j + 2) * 256 + tid];
        unsigned wq3 = Wq[(size_t)(j + 3) * 256 + tid];
        float4 u0 = up[j + 0], u1 = up[j + 1], u2 = up[j + 2], u3 = up[j + 3];
        int s0 = __builtin_amdgcn_readfirstlane(sp[j + 0]);
        int s1 = __builtin_amdgcn_readfirstlane(sp[j + 1]);
        int s2 = __builtin_amdgcn_readfirstlane(sp[j + 2]);
        int s3 = __builtin_amdgcn_readfirstlane(sp[j + 3]);
        proc(wq0, u0, s0);
        proc(wq1, u1, s1);
        proc(wq2, u2, s2);
        proc(wq3, u3, s3);
    }
    for (; j < end; j++) {
        unsigned wq = Wq[(size_t)j * 256 + tid];
        float4 u = up[j];
        int s = __builtin_amdgcn_readfirstlane(sp[j]);
        proc(wq, u, s);
    }

    agg_s[(size_t)r * 256 + tid] = accs;
    float* o = agg_v + ((size_t)r * 256 + tid) * 3;
    o[0] = av0; o[1] = av1; o[2] = av2;
}

// ---------------- tier B: VALU writer (grouped layout) + its gather ----------------
__global__ __launch_bounds__(256) void k_mlp_wp(
    const float* __restrict__ rb, const int* __restrict__ elist,
    const float* __restrict__ w0T, const float* __restrict__ w1T,
    const float* __restrict__ w2T, const float* __restrict__ w3T,
    unsigned short* __restrict__ Wp, int E_) {
    int p = blockIdx.x * blockDim.x + threadIdx.x;
    if (p >= E_) return;
    int e = elist[p];
    const int c0 = blockIdx.y * 128;

    float4 a[16];
    mlp_body(rb, e, w0T, w1T, w2T, a);

    const size_t E4 = (size_t)E_ * 4;
    for (int c = c0; c < c0 + 128; c += 8) {
        float s[8];
        #pragma unroll
        for (int q = 0; q < 8; q++) {
            const float* rp = w3T + (size_t)(c + q) * 64;
            float t0 = 0.f, t1 = 0.f, t2 = 0.f, t3 = 0.f;
            #pragma unroll
            for (int k = 0; k < 16; k++) {
                float4 h = a[k];
                t0 += h.x * rp[4 * k + 0];
                t1 += h.y * rp[4 * k + 1];
                t2 += h.z * rp[4 * k + 2];
                t3 += h.w * rp[4 * k + 3];
            }
            s[q] = (t0 + t1) + (t2 + t3);
        }
        ushort4 pk0 = make_ushort4(f2bf(s[0]), f2bf(s[1]), f2bf(s[2]), f2bf(s[3]));
        ushort4 pk1 = make_ushort4(f2bf(s[4]), f2bf(s[5]), f2bf(s[6]), f2bf(s[7]));
        *(ushort4*)(Wp + (size_t)(c >> 2) * E4 + (size_t)p * 4) = pk0;
        *(ushort4*)(Wp + (size_t)((c >> 2) + 1) * E4 + (size_t)p * 4) = pk1;
    }
}

__global__ __launch_bounds__(512, 2) void k_gather_wg(
    const int* __restrict__ off, const int* __restrict__ elist,
    const int* __restrict__ snd, const float* __restrict__ evec,
    const unsigned short* __restrict__ Wp, int E_,
    const float* __restrict__ y0, const float* __restrict__ y1, int NP,
    float* __restrict__ agg_s, float* __restrict__ agg_v) {
    const int r = blockIdx.x;
    const int tid = threadIdx.x;
    const int part = tid >> 7;
    const int c = tid & 127;

    const int start = off[r];
    const int end = off[r + 1];

    const unsigned short* __restrict__ wstream =
        Wp + (size_t)(tid >> 2) * ((size_t)E_ * 4) + (tid & 3);

    float acc0 = 0.f, acc1 = 0.f, acc2 = 0.f;
    const float SQ3 = 1.7320508075688772f;

    #pragma unroll 2
    for (int j = start; j < end; j++) {
        int e = elist[j];
        e = __builtin_amdgcn_readfirstlane(e);
        int s = snd[e];
        s = __builtin_amdgcn_readfirstlane(s);

        float e0 = evec[(size_t)e * 3 + 0];
        float e1 = evec[(size_t)e * 3 + 1];
        float e2 = evec[(size_t)e * 3 + 2];
        float rn = sqrtf(e0 * e0 + e1 * e1 + e2 * e2);
        float inv = 1.0f / fmaxf(rn, 1e-12f);
        float ux = e0 * inv, uy = e1 * inv, uz = e2 * inv;

        float w = bf2f(wstream[(size_t)j * 4]);

        if (part == 0) {
            acc0 += y0[(size_t)s * CC + c] * w;
        } else if (part == 1) {
            float f = y1[0 * NP + s * CC + c] * ux
                    + y1[1 * NP + s * CC + c] * uy
                    + y1[2 * NP + s * CC + c] * uz;
            acc0 += f * w;
        } else if (part == 2) {
            float bb = y0[(size_t)s * CC + c] * w * SQ3;
            acc0 += bb * ux; acc1 += bb * uy; acc2 += bb * uz;
        } else {
            acc0 += y1[0 * NP + s * CC + c] * w;
            acc1 += y1[1 * NP + s * CC + c] * w;
            acc2 += y1[2 * NP + s * CC + c] * w;
        }
    }

    if (part == 0) {
        agg_s[(size_t)r * 256 + c] = acc0;
    } else if (part == 1) {
        agg_s[(size_t)r * 256 + 128 + c] = acc0;
    } else if (part == 2) {
        float* o = agg_v + ((size_t)r * 256 + c) * 3;
        o[0] = acc0; o[1] = acc1; o[2] = acc2;
    } else {
        float* o = agg_v + ((size_t)r * 256 + 128 + c) * 3;
        o[0] = acc0; o[1] = acc1; o[2] = acc2;
    }
}

// ---------------- tier C: f32 h2 fallback ----------------
__global__ void k_mlp(const float* __restrict__ rb,
                      const float* __restrict__ w0T, const float* __restrict__ w1T,
                      const float* __restrict__ w2T,
                      float* __restrict__ h2, int E_) {
    int e = blockIdx.x * blockDim.x + threadIdx.x;
    if (e >= E_) return;
    float4 a[16];
    mlp_body(rb, e, w0T, w1T, w2T, a);
    float4* out = (float4*)(h2 + (size_t)e * HH);
    #pragma unroll
    for (int q = 0; q < 16; q++) out[q] = a[q];
}

__global__ __launch_bounds__(512, 1) void k_gather_h2(
    const int* __restrict__ off, const int* __restrict__ elist,
    const int* __restrict__ snd, const float* __restrict__ evec,
    const float* __restrict__ h2, const float* __restrict__ w3T,
    const float* __restrict__ y0, const float* __restrict__ y1, int NP,
    float* __restrict__ agg_s, float* __restrict__ agg_v) {
    const int r = blockIdx.x;
    const int tid = threadIdx.x;
    const int part = tid >> 7;
    const int c = tid & 127;

    const float4* wp = (const float4*)(w3T + (size_t)tid * 64);
    const int start = off[r];
    const int end = off[r + 1];

    float acc0 = 0.f, acc1 = 0.f, acc2 = 0.f;
    const float SQ3 = 1.7320508075688772f;

    for (int j = start; j < end; j++) {
        int e = elist[j];
        e = __builtin_amdgcn_readfirstlane(e);
        int s = snd[e];
        s = __builtin_amdgcn_readfirstlane(s);

        float e0 = evec[(size_t)e * 3 + 0];
        float e1 = evec[(size_t)e * 3 + 1];
        float e2 = evec[(size_t)e * 3 + 2];
        float rn = sqrtf(e0 * e0 + e1 * e1 + e2 * e2);
        float inv = 1.0f / fmaxf(rn, 1e-12f);
        float ux = e0 * inv, uy = e1 * inv, uz = e2 * inv;

        const float4* __restrict__ hp = (const float4*)(h2 + ((size_t)e << 6));
        float ws0 = 0.f, ws1 = 0.f, ws2 = 0.f, ws3 = 0.f;
        #pragma unroll
        for (int k = 0; k < 16; k++) {
            float4 h = hp[k];
            float4 wv = wp[k];
            ws0 += h.x * wv.x; ws1 += h.y * wv.y; ws2 += h.z * wv.z; ws3 += h.w * wv.w;
        }
        float w = (ws0 + ws1) + (ws2 + ws3);

        if (part == 0) {
            acc0 += y0[(size_t)s * CC + c] * w;
        } else if (part == 1) {
            float f = y1[0 * NP + s * CC + c] * ux
                    + y1[1 * NP + s * CC + c] * uy
                    + y1[2 * NP + s * CC + c] * uz;
            acc0 += f * w;
        } else if (part == 2) {
            float bb = y0[(size_t)s * CC + c] * w * SQ3;
            acc0 += bb * ux; acc1 += bb * uy; acc2 += bb * uz;
        } else {
            acc0 += y1[0 * NP + s * CC + c] * w;
            acc1 += y1[1 * NP + s * CC + c] * w;
            acc2 += y1[2 * NP + s * CC + c] * w;
        }
    }

    if (part == 0) {
        agg_s[(size_t)r * 256 + c] = acc0;
    } else if (part == 1) {
        agg_s[(size_t)r * 256 + 128 + c] = acc0;
    } else if (part == 2) {
        float* o = agg_v + ((size_t)r * 256 + c) * 3;
        o[0] = acc0; o[1] = acc1; o[2] = acc2;
    } else {
        float* o = agg_v + ((size_t)r * 256 + 128 + c) * 3;
        o[0] = acc0; o[1] = acc1; o[2] = acc2;
    }
}

// ---------------- node output (r15 structure: species-sorted, coalesced W) ----
__global__ __launch_bounds__(256) void k_node_out(
    const float* __restrict__ agg_s, const float* __restrict__ agg_v,
    const float* __restrict__ xs, const float* __restrict__ xv,
    const float* __restrict__ W20, const float* __restrict__ W21,
    const float* __restrict__ Wsk0, const float* __restrict__ Wsk1,
    const int* __restrict__ nlist, const int* __restrict__ species,
    float* __restrict__ out, int N) {
    const int tid = threadIdx.x;
    const int b0 = blockIdx.x * 4;
    const int nid0 = nlist[min(b0 + 0, N - 1)];
    const int nid1 = nlist[min(b0 + 1, N - 1)];
    const int nid2 = nlist[min(b0 + 2, N - 1)];
    const int nid3 = nlist[min(b0 + 3, N - 1)];

    __shared__ float as_l[4 * 256];
    __shared__ float av_l[4 * 768];
    __shared__ float xs_l[4 * 128];
    __shared__ float xv_l[4 * 384];
    __shared__ float s_l[4 * 256];

    {
        as_l[0 * 256 + tid] = agg_s[(size_t)nid0 * 256 + tid];
        as_l[1 * 256 + tid] = agg_s[(size_t)nid1 * 256 + tid];
        as_l[2 * 256 + tid] = agg_s[(size_t)nid2 * 256 + tid];
        as_l[3 * 256 + tid] = agg_s[(size_t)nid3 * 256 + tid];
        for (int i = tid; i < 768; i += 256) {
            av_l[0 * 768 + i] = agg_v[(size_t)nid0 * 768 + i];
            av_l[1 * 768 + i] = agg_v[(size_t)nid1 * 768 + i];
            av_l[2 * 768 + i] = agg_v[(size_t)nid2 * 768 + i];
            av_l[3 * 768 + i] = agg_v[(size_t)nid3 * 768 + i];
        }
        if (tid < 128) {
            xs_l[0 * 128 + tid] = xs[(size_t)nid0 * 128 + tid];
            xs_l[1 * 128 + tid] = xs[(size_t)nid1 * 128 + tid];
            xs_l[2 * 128 + tid] = xs[(size_t)nid2 * 128 + tid];
            xs_l[3 * 128 + tid] = xs[(size_t)nid3 * 128 + tid];
        }
        for (int i = tid; i < 384; i += 256) {
            xv_l[0 * 384 + i] = xv[(size_t)nid0 * 384 + i];
            xv_l[1 * 384 + i] = xv[(size_t)nid1 * 384 + i];
            xv_l[2 * 384 + i] = xv[(size_t)nid2 * 384 + i];
            xv_l[3 * 384 + i] = xv[(size_t)nid3 * 384 + i];
        }
    }
    const int sp0 = species[nid0], sp1 = species[nid1];
    const int sp2 = species[nid2], sp3 = species[nid3];
    const bool uni = (sp0 == sp1) && (sp1 == sp2) && (sp2 == sp3);
    __syncthreads();

    const float k_mat = 0.17677669529663687f * 0.0625f; // inv_nb * inv_2c
    const float inv_c = 0.08838834764831845f;

    {
        const int d = tid;
        float am[4] = {0.f, 0.f, 0.f, 0.f};
        for (int cc = 0; cc < 256; cc++) {
            float w = W20[cc * 256 + d];
            #pragma unroll
            for (int n = 0; n < 4; n++) am[n] += as_l[n * 256 + cc] * w;
        }
        float ak[4] = {0.f, 0.f, 0.f, 0.f};
        if (uni) {
            for (int cc = 0; cc < 128; cc++) {
                float w = Wsk0[((size_t)sp0 * 128 + cc) * 256 + d];
                #pragma unroll
                for (int n = 0; n < 4; n++) ak[n] += xs_l[n * 128 + cc] * w;
            }
        } else {
            for (int cc = 0; cc < 128; cc++) {
                float w0v = Wsk0[((size_t)sp0 * 128 + cc) * 256 + d];
                float w1v = Wsk0[((size_t)sp1 * 128 + cc) * 256 + d];
                float w2v = Wsk0[((size_t)sp2 * 128 + cc) * 256 + d];
                float w3v = Wsk0[((size_t)sp3 * 128 + cc) * 256 + d];
                ak[0] += xs_l[0 * 128 + cc] * w0v;
                ak[1] += xs_l[1 * 128 + cc] * w1v;
                ak[2] += xs_l[2 * 128 + cc] * w2v;
                ak[3] += xs_l[3 * 128 + cc] * w3v;
            }
        }
        #pragma unroll
        for (int n = 0; n < 4; n++) s_l[n * 256 + d] = am[n] * k_mat + ak[n] * inv_c;
    }
    __syncthreads();

    if (tid < 128) {
        out[(size_t)nid0 * 512 + tid] = silu_f(s_l[0 * 256 + tid]);
        out[(size_t)nid1 * 512 + tid] = silu_f(s_l[1 * 256 + tid]);
        out[(size_t)nid2 * 512 + tid] = silu_f(s_l[2 * 256 + tid]);
        out[(size_t)nid3 * 512 + tid] = silu_f(s_l[3 * 256 + tid]);
    }

    {
        const int d = tid & 127;
        const int half = tid >> 7;
        const int nA = half ? nid2 : nid0;
        const int nB = half ? nid3 : nid1;
        const int sA = half ? sp2 : sp0;
        const int sB = half ? sp3 : sp1;
        const int la = half ? 2 : 0;
        const int lb = half ? 3 : 1;

        float am[2][3] = {};
        for (int cc = 0; cc < 256; cc++) {
            float w = W21[cc * 128 + d];
            #pragma unroll
            for (int i = 0; i < 3; i++) {
                am[0][i] += av_l[la * 768 + cc * 3 + i] * w;
                am[1][i] += av_l[lb * 768 + cc * 3 + i] * w;
            }
        }
        float ak[2][3] = {};
        if (uni) {
            for (int cc = 0; cc < 128; cc++) {
                float w = Wsk1[((size_t)sp0 * 128 + cc) * 128 + d];
                #pragma unroll
                for (int i = 0; i < 3; i++) {
                    ak[0][i] += xv_l[la * 384 + cc * 3 + i] * w;
                    ak[1][i] += xv_l[lb * 384 + cc * 3 + i] * w;
                }
            }
        } else {
            for (int cc = 0; cc < 128; cc++) {
                float wA = Wsk1[((size_t)sA * 128 + cc) * 128 + d];
                float wB = Wsk1[((size_t)sB * 128 + cc) * 128 + d];
                #pragma unroll
                for (int i = 0; i < 3; i++) {
                    ak[0][i] += xv_l[la * 384 + cc * 3 + i] * wA;
                    ak[1][i] += xv_l[lb * 384 + cc * 3 + i] * wB;
                }
            }
        }
        float gA = silu_f(s_l[la * 256 + 128 + d]);
        float gB = silu_f(s_l[lb * 256 + 128 + d]);
        float* oA = out + (size_t)nA * 512 + 128 + d * 3;
        float* oB = out + (size_t)nB * 512 + 128 + d * 3;
        #pragma unroll
        for (int i = 0; i < 3; i++) {
            oA[i] = (am[0][i] * k_mat + ak[0][i] * inv_c) * gA;
            oB[i] = (am[1][i] * k_mat + ak[1][i] * inv_c) * gB;
        }
    }
}

extern "C" void kernel_launch(void* const* d_in, const int* in_sizes, int n_in,
                              void* d_out, int out_size, void* d_ws, size_t ws_size,
                              hipStream_t stream) {
    const float* xs   = (const float*)d_in[0];
    const float* xv   = (const float*)d_in[1];
    const float* evec = (const float*)d_in[2];
    const float* rb   = (const float*)d_in[3];
    const float* W10  = (const float*)d_in[4];
    const float* W11  = (const float*)d_in[5];
    const float* w0   = (const float*)d_in[6];
    const float* w1   = (const float*)d_in[7];
    const float* w2   = (const float*)d_in[8];
    const float* w3   = (const float*)d_in[9];
    const float* W20  = (const float*)d_in[10];
    const float* W21  = (const float*)d_in[11];
    const float* Wsk0 = (const float*)d_in[12];
    const float* Wsk1 = (const float*)d_in[13];
    const int* species = (const int*)d_in[14];
    const int* snd = (const int*)d_in[15];
    const int* rcv = (const int*)d_in[16];

    const int N = in_sizes[0] / CC;   // 4000
    const int E = in_sizes[2] / 3;    // 128000
    const int NP = N * CC;
    int NS = in_sizes[12] / (CC * 2 * CC);   // 5
    if (NS < 1) NS = 1;
    if (NS > 63) NS = 63;

    float* ws   = (float*)d_ws;
    float* y0   = ws;
    float* y1   = y0 + (size_t)N * CC;
    float* aggs = y1 + (size_t)N * CC * 3;
    float* aggv = aggs + (size_t)N * 2 * CC;
    float* w0T  = aggv + (size_t)N * 2 * CC * 3;
    float* w1T  = w0T + 64 * 8;
    float* w2T  = w1T + 64 * 64;
    float* w3T  = w2T + 64 * 64;
    unsigned short* w3bs = (unsigned short*)(w3T + 512 * 64);
    unsigned short* w0b  = w3bs + 32768;
    unsigned short* w1b  = w0b + 2048;
    unsigned short* w2b  = w1b + 4096;
    // contiguous counter block (single memset): deg, cur, scnt, soff, scur
    int*   deg  = (int*)(w2b + 4096);
    int*   cur  = deg + 4096;
    int*   scnt = cur + 4096;                // 64
    int*   soff = scnt + 64;                 // 72
    int*   scur = soff + 72;                 // 64
    int*   off  = scur + 64;                 // 4160
    int*   elist = off + 4160;
    float4* up  = (float4*)(elist + E);
    int*   sp   = (int*)(up + E);
    int*   nlist = sp + E;                   // N
    void*  big  = (void*)(nlist + N);

    size_t base_bytes = (size_t)((char*)big - (char*)d_ws);
    size_t wq_bytes   = (size_t)E * 256 * sizeof(unsigned int);
    size_t need_A = base_bytes + wq_bytes;
    size_t need_B = base_bytes + (size_t)E * WDIM * sizeof(unsigned short);

    unsigned int*   Wq  = (unsigned int*)big;
    unsigned short* Wp  = (unsigned short*)big;

    hipMemsetAsync(deg, 0, (4096 + 4096 + 64 + 72 + 64) * sizeof(int), stream);
    hipLaunchKernelGGL(k_hist, dim3((E + 255) / 256), dim3(256), 0, stream,
                       rcv, deg, E, species, scnt, N);
    hipLaunchKernelGGL(k_scan, dim3(1), dim3(1024), 0, stream,
                       deg, off, N, scnt, soff, NS);
    hipLaunchKernelGGL(k_scatter, dim3((E + 255) / 256), dim3(256), 0, stream,
                       rcv, off, cur, elist, E, species, soff, scur, nlist, N);
    hipLaunchKernelGGL(k_prep, dim3(128), dim3(256), 0, stream,
                       w0, w1, w2, w3, w0T, w1T, w2T, w3T, w3bs, w0b, w1b, w2b);
    hipLaunchKernelGGL(k_node_lin, dim3(N / 2), dim3(128), 0, stream,
                       xs, xv, W10, W11, y0, y1, N);

    if (ws_size >= need_A && (E % 64) == 0) {
        hipLaunchKernelGGL(k_mlpw3, dim3(E / 64), dim3(256), 0, stream,
                           rb, elist, snd, evec, w0b, w1b, w2b, w3bs, Wq, up, sp, E);
        hipLaunchKernelGGL(k_gather_em, dim3(N), dim3(256), 0, stream,
                           off, up, sp, Wq, y0, y1, NP, aggs, aggv);
    } else if (ws_size >= need_B) {
        hipLaunchKernelGGL(k_mlp_wp, dim3((E + 255) / 256, 4), dim3(256), 0, stream,
                           rb, elist, w0T, w1T, w2T, w3T, Wp, E);
        hipLaunchKernelGGL(k_gather_wg, dim3(N), dim3(512), 0, stream,
                           off, elist, snd, evec, Wp, E, y0, y1, NP, aggs, aggv);
    } else {
        hipLaunchKernelGGL(k_mlp, dim3((E + 255) / 256), dim3(256), 0, stream,
                           rb, w0T, w1T, w2T, (float*)big, E);
        hipLaunchKernelGGL(k_gather_h2, dim3(N), dim3(512), 0, stream,
                           off, elist, snd, evec, (const float*)big, w3T,
                           y0, y1, NP, aggs, aggv);
    }

    hipLaunchKernelGGL(k_node_out, dim3((N + 3) / 4), dim3(256), 0, stream,
                       aggs, aggv, xs, xv, W20, W21, Wsk0, Wsk1, nlist, species,
                       (float*)d_out, N);
}

// Round 18
// 287.311 us; speedup vs baseline: 1.2347x; 1.0331x over previous
//
#include <hip/hip_runtime.h>
#include <math.h>

#define CC 128
#define HH 64
#define RBD 8
#define WDIM 512

typedef __attribute__((ext_vector_type(8))) short short8v;
typedef __attribute__((ext_vector_type(4))) float f32x4;

__device__ __forceinline__ float silu_f(float x) {
    return x / (1.0f + __expf(-x));
}

__device__ __forceinline__ unsigned short f2bf(float x) {
    unsigned int b = __float_as_uint(x);
    unsigned int r = (b + 0x7FFFu + ((b >> 16) & 1u)) >> 16;
    return (unsigned short)r;
}

__device__ __forceinline__ float bf2f(unsigned short u) {
    return __uint_as_float(((unsigned int)u) << 16);
}

// ---------------- prep: transposed weights (tier B/C) + MFMA fragment tables ----
__global__ void k_prep(const float* __restrict__ w0, const float* __restrict__ w1,
                       const float* __restrict__ w2, const float* __restrict__ w3,
                       float* __restrict__ w0T, float* __restrict__ w1T,
                       float* __restrict__ w2T, float* __restrict__ w3T,
                       unsigned short* __restrict__ w3bs,
                       unsigned short* __restrict__ w0b,
                       unsigned short* __restrict__ w1b,
                       unsigned short* __restrict__ w2b) {
    int i = blockIdx.x * blockDim.x + threadIdx.x;
    if (i < 64 * 8) { int m = i / 8, k = i % 8; w0T[i] = w0[k * 64 + m]; }
    if (i < 64 * 64) { int m = i / 64, k = i % 64; w1T[i] = w1[k * 64 + m]; w2T[i] = w2[k * 64 + m]; }
    if (i < 512 * 64) { int j = i / 64, k = i % 64; w3T[i] = w3[k * 512 + j]; }
    if (i < 32768) {
        int t = i >> 10, ch = (i >> 9) & 1, lane = (i >> 3) & 63, j = i & 7;
        int k = ch * 32 + 8 * (lane >> 4) + j;
        int n = t * 16 + (lane & 15);
        w3bs[i] = f2bf(w3[k * 512 + n]);
    }
    if (i < 2048) {
        int t = i >> 9, lane = (i >> 3) & 63, j = i & 7;
        int k = 8 * (lane >> 4) + j;
        int col = t * 16 + (lane & 15);
        w0b[i] = (k < RBD) ? f2bf(w0[k * 64 + col]) : (unsigned short)0;
    }
    if (i < 4096) {
        int f = i >> 9, lane = (i >> 3) & 63, j = i & 7;
        int ks = f >> 2, t = f & 3;
        int k = ks * 32 + 8 * (lane >> 4) + j;
        int col = t * 16 + (lane & 15);
        w1b[i] = f2bf(w1[k * 64 + col]);
        w2b[i] = f2bf(w2[k * 64 + col]);
    }
}

// ---------------- CSR build (merged edge + species histograms) ----------------
__global__ void k_hist(const int* __restrict__ rcv, int* __restrict__ deg, int E_,
                       const int* __restrict__ species, int* __restrict__ scnt, int N) {
    int e = blockIdx.x * blockDim.x + threadIdx.x;
    if (e < E_) atomicAdd(&deg[rcv[e]], 1);
    if (e < N) atomicAdd(&scnt[species[e]], 1);
}

__global__ __launch_bounds__(1024) void k_scan(const int* __restrict__ deg,
                                               int* __restrict__ off, int N,
                                               const int* __restrict__ scnt,
                                               int* __restrict__ soff, int NS) {
    __shared__ int s[1024];
    int t = threadIdx.x;
    int b = t * 4;
    int a0 = (b + 0 < N) ? deg[b + 0] : 0;
    int a1 = (b + 1 < N) ? deg[b + 1] : 0;
    int a2 = (b + 2 < N) ? deg[b + 2] : 0;
    int a3 = (b + 3 < N) ? deg[b + 3] : 0;
    int part = a0 + a1 + a2 + a3;
    s[t] = part;
    __syncthreads();
    for (int d = 1; d < 1024; d <<= 1) {
        int v = (t >= d) ? s[t - d] : 0;
        __syncthreads();
        s[t] += v;
        __syncthreads();
    }
    int excl = s[t] - part;
    if (b + 0 <= N) off[b + 0] = excl;
    if (b + 1 <= N) off[b + 1] = excl + a0;
    if (b + 2 <= N) off[b + 2] = excl + a0 + a1;
    if (b + 3 <= N) off[b + 3] = excl + a0 + a1 + a2;
    if (t == 0) {
        int acc = 0;
        for (int q = 0; q < NS; q++) { soff[q] = acc; acc += scnt[q]; }
        soff[NS] = acc;
    }
}

__global__ void k_scatter(const int* __restrict__ rcv, const int* __restrict__ off,
                          int* __restrict__ cur, int* __restrict__ elist, int E_,
                          const int* __restrict__ species, const int* __restrict__ soff,
                          int* __restrict__ scur, int* __restrict__ nlist, int N) {
    int e = blockIdx.x * blockDim.x + threadIdx.x;
    if (e < E_) {
        int r = rcv[e];
        int p = atomicAdd(&cur[r], 1);
        elist[off[r] + p] = e;
    }
    if (e < N) {
        int s = species[e];
        int p = atomicAdd(&scur[s], 1);
        nlist[soff[s] + p] = e;
    }
}

// ---------------- node linear (planar y1: [3][N][C]) — 2 nodes/block ----------
__global__ __launch_bounds__(128) void k_node_lin(
    const float* __restrict__ xs, const float* __restrict__ xv,
    const float* __restrict__ W10, const float* __restrict__ W11,
    float* __restrict__ y0, float* __restrict__ y1, int N) {
    const int d = threadIdx.x;
    const int n0 = blockIdx.x * 2;
    const int NP = N * CC;
    const float inv_c = 0.08838834764831845f;
    float a0[2] = {0.f, 0.f};
    float av[2][3] = {};
    #pragma unroll 4
    for (int c = 0; c < CC; c++) {
        float w10 = W10[c * CC + d];
        float w11 = W11[c * CC + d];
        #pragma unroll
        for (int n = 0; n < 2; n++) {
            a0[n] += xs[(n0 + n) * CC + c] * w10;
            #pragma unroll
            for (int i = 0; i < 3; i++)
                av[n][i] += xv[((n0 + n) * CC + c) * 3 + i] * w11;
        }
    }
    #pragma unroll
    for (int n = 0; n < 2; n++) {
        y0[(n0 + n) * CC + d] = a0[n] * inv_c;
        #pragma unroll
        for (int i = 0; i < 3; i++)
            y1[i * NP + (n0 + n) * CC + d] = av[n][i] * inv_c;
    }
}

// ---------------- shared VALU MLP body (tiers B/C) ----------------
__device__ __forceinline__ void layer64(const float4* a, float4* b,
                                        const float* __restrict__ W) {
    #pragma unroll
    for (int m = 0; m < 16; m++) {
        float s0 = 0.f, s1 = 0.f, s2 = 0.f, s3 = 0.f;
        const float* w0p = W + (4 * m + 0) * 64;
        const float* w1p = W + (4 * m + 1) * 64;
        const float* w2p = W + (4 * m + 2) * 64;
        const float* w3p = W + (4 * m + 3) * 64;
        #pragma unroll
        for (int k = 0; k < 16; k++) {
            float4 av = a[k];
            s0 += av.x * w0p[4 * k + 0] + av.y * w0p[4 * k + 1] + av.z * w0p[4 * k + 2] + av.w * w0p[4 * k + 3];
            s1 += av.x * w1p[4 * k + 0] + av.y * w1p[4 * k + 1] + av.z * w1p[4 * k + 2] + av.w * w1p[4 * k + 3];
            s2 += av.x * w2p[4 * k + 0] + av.y * w2p[4 * k + 1] + av.z * w2p[4 * k + 2] + av.w * w2p[4 * k + 3];
            s3 += av.x * w3p[4 * k + 0] + av.y * w3p[4 * k + 1] + av.z * w3p[4 * k + 2] + av.w * w3p[4 * k + 3];
        }
        b[m] = make_float4(silu_f(s0), silu_f(s1), silu_f(s2), silu_f(s3));
    }
}

__device__ __forceinline__ void mlp_body(
    const float* __restrict__ rb, int e,
    const float* __restrict__ w0T, const float* __restrict__ w1T,
    const float* __restrict__ w2T, float4* a) {
    float rbv[RBD];
    #pragma unroll
    for (int k = 0; k < RBD; k++) rbv[k] = rb[(size_t)e * RBD + k];
    float4 b[16];
    #pragma unroll
    for (int m = 0; m < 16; m++) {
        float s0 = 0.f, s1 = 0.f, s2 = 0.f, s3 = 0.f;
        #pragma unroll
        for (int k = 0; k < RBD; k++) {
            float rv = rbv[k];
            s0 += rv * w0T[(4 * m + 0) * RBD + k];
            s1 += rv * w0T[(4 * m + 1) * RBD + k];
            s2 += rv * w0T[(4 * m + 2) * RBD + k];
            s3 += rv * w0T[(4 * m + 3) * RBD + k];
        }
        a[m] = make_float4(silu_f(s0), silu_f(s1), silu_f(s2), silu_f(s3));
    }
    layer64(a, b, w1T);
    layer64(b, a, w2T);   // a holds h2
}

// ---------------- tier A: fused MFMA MLP + w3 GEMM + emeta -> Wq --------------
// hbuf is WAVE-PRIVATE (indexed by wv): per-wave LDS ops are in-order, so NO
// __syncthreads is needed anywhere -> waves pipeline independently (emeta on
// wave 0 overlaps other waves' MFMAs; no 4-wave lockstep at layer edges).
__global__ __launch_bounds__(256) void k_mlpw3(
    const float* __restrict__ rb, const int* __restrict__ elist,
    const int* __restrict__ snd, const float* __restrict__ evec,
    const unsigned short* __restrict__ w0b, const unsigned short* __restrict__ w1b,
    const unsigned short* __restrict__ w2b, const unsigned short* __restrict__ w3bs,
    unsigned int* __restrict__ Wq, float4* __restrict__ up, int* __restrict__ sp,
    int E_) {
    const int lane = threadIdx.x & 63;
    const int wv = threadIdx.x >> 6;
    const int rbk = blockIdx.x * 4 + wv;
    const int col = lane & 15;
    const int grp = lane >> 4;

    // folded emeta: threads 0..63 handle the block's 64 edges (no barrier dep)
    if (threadIdx.x < 64) {
        int p = blockIdx.x * 64 + threadIdx.x;
        if (p < E_) {
            int e = elist[p];
            float e0 = evec[(size_t)e * 3 + 0];
            float e1 = evec[(size_t)e * 3 + 1];
            float e2 = evec[(size_t)e * 3 + 2];
            float rn = sqrtf(e0 * e0 + e1 * e1 + e2 * e2);
            float inv = 1.0f / fmaxf(rn, 1e-12f);
            up[p] = make_float4(e0 * inv, e1 * inv, e2 * inv, 0.f);
            sp[p] = snd[e];
        }
    }

    __shared__ unsigned short hbuf[4][16][72];

    short8v a0 = (short8v){0, 0, 0, 0, 0, 0, 0, 0};
    if (grp == 0) {
        int e = elist[rbk * 16 + col];
        const float* rp = rb + (size_t)e * RBD;
        #pragma unroll
        for (int j = 0; j < RBD; j++) a0[j] = (short)f2bf(rp[j]);
    }
    f32x4 acc[4];
    {
        const unsigned short* bp = w0b + (size_t)lane * 8;
        #pragma unroll
        for (int t = 0; t < 4; t++) {
            short8v b = *(const short8v*)(bp + (size_t)t * 512);
            acc[t] = __builtin_amdgcn_mfma_f32_16x16x32_bf16(
                a0, b, (f32x4){0.f, 0.f, 0.f, 0.f}, 0, 0, 0);
        }
    }
    #pragma unroll
    for (int t = 0; t < 4; t++)
        #pragma unroll
        for (int r = 0; r < 4; r++)
            hbuf[wv][grp * 4 + r][t * 16 + col] = f2bf(silu_f(acc[t][r]));

    {
        short8v aA = *(const short8v*)&hbuf[wv][col][8 * grp];
        short8v aB = *(const short8v*)&hbuf[wv][col][32 + 8 * grp];
        const unsigned short* bp = w1b + (size_t)lane * 8;
        #pragma unroll
        for (int t = 0; t < 4; t++) {
            short8v b0 = *(const short8v*)(bp + (size_t)(0 + t) * 512);
            short8v b1 = *(const short8v*)(bp + (size_t)(4 + t) * 512);
            f32x4 c = __builtin_amdgcn_mfma_f32_16x16x32_bf16(
                aA, b0, (f32x4){0.f, 0.f, 0.f, 0.f}, 0, 0, 0);
            acc[t] = __builtin_amdgcn_mfma_f32_16x16x32_bf16(aB, b1, c, 0, 0, 0);
        }
    }
    #pragma unroll
    for (int t = 0; t < 4; t++)
        #pragma unroll
        for (int r = 0; r < 4; r++)
            hbuf[wv][grp * 4 + r][t * 16 + col] = f2bf(silu_f(acc[t][r]));

    {
        short8v aA = *(const short8v*)&hbuf[wv][col][8 * grp];
        short8v aB = *(const short8v*)&hbuf[wv][col][32 + 8 * grp];
        const unsigned short* bp = w2b + (size_t)lane * 8;
        #pragma unroll
        for (int t = 0; t < 4; t++) {
            short8v b0 = *(const short8v*)(bp + (size_t)(0 + t) * 512);
            short8v b1 = *(const short8v*)(bp + (size_t)(4 + t) * 512);
            f32x4 c = __builtin_amdgcn_mfma_f32_16x16x32_bf16(
                aA, b0, (f32x4){0.f, 0.f, 0.f, 0.f}, 0, 0, 0);
            acc[t] = __builtin_amdgcn_mfma_f32_16x16x32_bf16(aB, b1, c, 0, 0, 0);
        }
    }
    #pragma unroll
    for (int t = 0; t < 4; t++)
        #pragma unroll
        for (int r = 0; r < 4; r++)
            hbuf[wv][grp * 4 + r][t * 16 + col] = f2bf(silu_f(acc[t][r]));

    short8v A0 = *(const short8v*)&hbuf[wv][col][8 * grp];
    short8v A1 = *(const short8v*)&hbuf[wv][col][32 + 8 * grp];

    f32x4 wacc[32];
    #pragma unroll
    for (int t = 0; t < 32; t++) wacc[t] = (f32x4){0.f, 0.f, 0.f, 0.f};

    const unsigned short* bbase = w3bs + (size_t)lane * 8;
    #pragma unroll
    for (int t = 0; t < 32; t++) {
        short8v b0 = *(const short8v*)(bbase + (size_t)(t * 2 + 0) * 512);
        short8v b1 = *(const short8v*)(bbase + (size_t)(t * 2 + 1) * 512);
        wacc[t] = __builtin_amdgcn_mfma_f32_16x16x32_bf16(A0, b0, wacc[t], 0, 0, 0);
        wacc[t] = __builtin_amdgcn_mfma_f32_16x16x32_bf16(A1, b1, wacc[t], 0, 0, 0);
    }

    const int rowq = grp * 4;
    const int jbase = rbk * 16 + rowq;
    #pragma unroll
    for (int t = 0; t < 16; t++) {
        #pragma unroll
        for (int rr = 0; rr < 4; rr++) {
            unsigned lo = f2bf(wacc[t][rr]);
            unsigned hi = f2bf(wacc[t + 16][rr]);
            Wq[(size_t)(jbase + rr) * 256 + t * 16 + col] = lo | (hi << 16);
        }
    }
}

// ---------------- tier A gather: edge-major, 4-edge unrolled ----------------
__global__ __launch_bounds__(256, 4) void k_gather_em(
    const int* __restrict__ off, const float4* __restrict__ up,
    const int* __restrict__ sp, const unsigned int* __restrict__ Wq,
    const float* __restrict__ y0, const float* __restrict__ y1, int NP,
    float* __restrict__ agg_s, float* __restrict__ agg_v) {
    const int r = blockIdx.x;
    const int tid = threadIdx.x;
    const int half = tid >> 7;
    const int c = tid & 127;
    const int start = off[r];
    const int end = off[r + 1];

    float accs = 0.f, av0 = 0.f, av1 = 0.f, av2 = 0.f;
    const float SQ3 = 1.7320508075688772f;

    auto proc = [&](unsigned wq, float4 u, int s) {
        float wa = bf2f((unsigned short)(wq & 0xFFFFu));
        float wb = bf2f((unsigned short)(wq >> 16));
        if (half == 0) {
            float f = y0[(size_t)s * CC + c];
            accs += f * wa;
            float bb = f * wb * SQ3;
            av0 += bb * u.x; av1 += bb * u.y; av2 += bb * u.z;
        } else {
            float f0 = y1[0 * NP + s * CC + c];
            float f1 = y1[1 * NP + s * CC + c];
            float f2 = y1[2 * NP + s * CC + c];
            accs += (f0 * u.x + f1 * u.y + f2 * u.z) * wa;
            av0 += f0 * wb; av1 += f1 * wb; av2 += f2 * wb;
        }
    };

    int j = start;
    for (; j + 4 <= end; j += 4) {
        unsigned wq0 = Wq[(size_t)(j + 0) * 256 + tid];
        unsigned wq1 = Wq[(size_t)(j + 1) * 256 + tid];
        unsigned wq2 = Wq[(size_t)(j + 2) * 256 + tid];
        unsigned wq3 = Wq[(size_t)(j + 3) * 256 + tid];
        float4 u0 = up[j + 0], u1 = up[j + 1], u2 = up[j + 2], u3 = up[j + 3];
        int s0 = __builtin_amdgcn_readfirstlane(sp[j + 0]);
        int s1 = __builtin_amdgcn_readfirstlane(sp[j + 1]);
        int s2 = __builtin_amdgcn_readfirstlane(sp[j + 2]);
        int s3 = __builtin_amdgcn_readfirstlane(sp[j + 3]);
        proc(wq0, u0, s0);
        proc(wq1, u1, s1);
        proc(wq2, u2, s2);
        proc(wq3, u3, s3);
    }
    for (; j < end; j++) {
        unsigned wq = Wq[(size_t)j * 256 + tid];
        float4 u = up[j];
        int s = __builtin_amdgcn_readfirstlane(sp[j]);
        proc(wq, u, s);
    }

    agg_s[(size_t)r * 256 + tid] = accs;
    float* o = agg_v + ((size_t)r * 256 + tid) * 3;
    o[0] = av0; o[1] = av1; o[2] = av2;
}

// ---------------- tier B: VALU writer (grouped layout) + its gather ----------------
__global__ __launch_bounds__(256) void k_mlp_wp(
    const float* __restrict__ rb, const int* __restrict__ elist,
    const float* __restrict__ w0T, const float* __restrict__ w1T,
    const float* __restrict__ w2T, const float* __restrict__ w3T,
    unsigned short* __restrict__ Wp, int E_) {
    int p = blockIdx.x * blockDim.x + threadIdx.x;
    if (p >= E_) return;
    int e = elist[p];
    const int c0 = blockIdx.y * 128;

    float4 a[16];
    mlp_body(rb, e, w0T, w1T, w2T, a);

    const size_t E4 = (size_t)E_ * 4;
    for (int c = c0; c < c0 + 128; c += 8) {
        float s[8];
        #pragma unroll
        for (int q = 0; q < 8; q++) {
            const float* rp = w3T + (size_t)(c + q) * 64;
            float t0 = 0.f, t1 = 0.f, t2 = 0.f, t3 = 0.f;
            #pragma unroll
            for (int k = 0; k < 16; k++) {
                float4 h = a[k];
                t0 += h.x * rp[4 * k + 0];
                t1 += h.y * rp[4 * k + 1];
                t2 += h.z * rp[4 * k + 2];
                t3 += h.w * rp[4 * k + 3];
            }
            s[q] = (t0 + t1) + (t2 + t3);
        }
        ushort4 pk0 = make_ushort4(f2bf(s[0]), f2bf(s[1]), f2bf(s[2]), f2bf(s[3]));
        ushort4 pk1 = make_ushort4(f2bf(s[4]), f2bf(s[5]), f2bf(s[6]), f2bf(s[7]));
        *(ushort4*)(Wp + (size_t)(c >> 2) * E4 + (size_t)p * 4) = pk0;
        *(ushort4*)(Wp + (size_t)((c >> 2) + 1) * E4 + (size_t)p * 4) = pk1;
    }
}

__global__ __launch_bounds__(512, 2) void k_gather_wg(
    const int* __restrict__ off, const int* __restrict__ elist,
    const int* __restrict__ snd, const float* __restrict__ evec,
    const unsigned short* __restrict__ Wp, int E_,
    const float* __restrict__ y0, const float* __restrict__ y1, int NP,
    float* __restrict__ agg_s, float* __restrict__ agg_v) {
    const int r = blockIdx.x;
    const int tid = threadIdx.x;
    const int part = tid >> 7;
    const int c = tid & 127;

    const int start = off[r];
    const int end = off[r + 1];

    const unsigned short* __restrict__ wstream =
        Wp + (size_t)(tid >> 2) * ((size_t)E_ * 4) + (tid & 3);

    float acc0 = 0.f, acc1 = 0.f, acc2 = 0.f;
    const float SQ3 = 1.7320508075688772f;

    #pragma unroll 2
    for (int j = start; j < end; j++) {
        int e = elist[j];
        e = __builtin_amdgcn_readfirstlane(e);
        int s = snd[e];
        s = __builtin_amdgcn_readfirstlane(s);

        float e0 = evec[(size_t)e * 3 + 0];
        float e1 = evec[(size_t)e * 3 + 1];
        float e2 = evec[(size_t)e * 3 + 2];
        float rn = sqrtf(e0 * e0 + e1 * e1 + e2 * e2);
        float inv = 1.0f / fmaxf(rn, 1e-12f);
        float ux = e0 * inv, uy = e1 * inv, uz = e2 * inv;

        float w = bf2f(wstream[(size_t)j * 4]);

        if (part == 0) {
            acc0 += y0[(size_t)s * CC + c] * w;
        } else if (part == 1) {
            float f = y1[0 * NP + s * CC + c] * ux
                    + y1[1 * NP + s * CC + c] * uy
                    + y1[2 * NP + s * CC + c] * uz;
            acc0 += f * w;
        } else if (part == 2) {
            float bb = y0[(size_t)s * CC + c] * w * SQ3;
            acc0 += bb * ux; acc1 += bb * uy; acc2 += bb * uz;
        } else {
            acc0 += y1[0 * NP + s * CC + c] * w;
            acc1 += y1[1 * NP + s * CC + c] * w;
            acc2 += y1[2 * NP + s * CC + c] * w;
        }
    }

    if (part == 0) {
        agg_s[(size_t)r * 256 + c] = acc0;
    } else if (part == 1) {
        agg_s[(size_t)r * 256 + 128 + c] = acc0;
    } else if (part == 2) {
        float* o = agg_v + ((size_t)r * 256 + c) * 3;
        o[0] = acc0; o[1] = acc1; o[2] = acc2;
    } else {
        float* o = agg_v + ((size_t)r * 256 + 128 + c) * 3;
        o[0] = acc0; o[1] = acc1; o[2] = acc2;
    }
}

// ---------------- tier C: f32 h2 fallback ----------------
__global__ void k_mlp(const float* __restrict__ rb,
                      const float* __restrict__ w0T, const float* __restrict__ w1T,
                      const float* __restrict__ w2T,
                      float* __restrict__ h2, int E_) {
    int e = blockIdx.x * blockDim.x + threadIdx.x;
    if (e >= E_) return;
    float4 a[16];
    mlp_body(rb, e, w0T, w1T, w2T, a);
    float4* out = (float4*)(h2 + (size_t)e * HH);
    #pragma unroll
    for (int q = 0; q < 16; q++) out[q] = a[q];
}

__global__ __launch_bounds__(512, 1) void k_gather_h2(
    const int* __restrict__ off, const int* __restrict__ elist,
    const int* __restrict__ snd, const float* __restrict__ evec,
    const float* __restrict__ h2, const float* __restrict__ w3T,
    const float* __restrict__ y0, const float* __restrict__ y1, int NP,
    float* __restrict__ agg_s, float* __restrict__ agg_v) {
    const int r = blockIdx.x;
    const int tid = threadIdx.x;
    const int part = tid >> 7;
    const int c = tid & 127;

    const float4* wp = (const float4*)(w3T + (size_t)tid * 64);
    const int start = off[r];
    const int end = off[r + 1];

    float acc0 = 0.f, acc1 = 0.f, acc2 = 0.f;
    const float SQ3 = 1.7320508075688772f;

    for (int j = start; j < end; j++) {
        int e = elist[j];
        e = __builtin_amdgcn_readfirstlane(e);
        int s = snd[e];
        s = __builtin_amdgcn_readfirstlane(s);

        float e0 = evec[(size_t)e * 3 + 0];
        float e1 = evec[(size_t)e * 3 + 1];
        float e2 = evec[(size_t)e * 3 + 2];
        float rn = sqrtf(e0 * e0 + e1 * e1 + e2 * e2);
        float inv = 1.0f / fmaxf(rn, 1e-12f);
        float ux = e0 * inv, uy = e1 * inv, uz = e2 * inv;

        const float4* __restrict__ hp = (const float4*)(h2 + ((size_t)e << 6));
        float ws0 = 0.f, ws1 = 0.f, ws2 = 0.f, ws3 = 0.f;
        #pragma unroll
        for (int k = 0; k < 16; k++) {
            float4 h = hp[k];
            float4 wv = wp[k];
            ws0 += h.x * wv.x; ws1 += h.y * wv.y; ws2 += h.z * wv.z; ws3 += h.w * wv.w;
        }
        float w = (ws0 + ws1) + (ws2 + ws3);

        if (part == 0) {
            acc0 += y0[(size_t)s * CC + c] * w;
        } else if (part == 1) {
            float f = y1[0 * NP + s * CC + c] * ux
                    + y1[1 * NP + s * CC + c] * uy
                    + y1[2 * NP + s * CC + c] * uz;
            acc0 += f * w;
        } else if (part == 2) {
            float bb = y0[(size_t)s * CC + c] * w * SQ3;
            acc0 += bb * ux; acc1 += bb * uy; acc2 += bb * uz;
        } else {
            acc0 += y1[0 * NP + s * CC + c] * w;
            acc1 += y1[1 * NP + s * CC + c] * w;
            acc2 += y1[2 * NP + s * CC + c] * w;
        }
    }

    if (part == 0) {
        agg_s[(size_t)r * 256 + c] = acc0;
    } else if (part == 1) {
        agg_s[(size_t)r * 256 + 128 + c] = acc0;
    } else if (part == 2) {
        float* o = agg_v + ((size_t)r * 256 + c) * 3;
        o[0] = acc0; o[1] = acc1; o[2] = acc2;
    } else {
        float* o = agg_v + ((size_t)r * 256 + 128 + c) * 3;
        o[0] = acc0; o[1] = acc1; o[2] = acc2;
    }
}

// ---------------- node output (r15 structure: species-sorted, coalesced W) ----
__global__ __launch_bounds__(256) void k_node_out(
    const float* __restrict__ agg_s, const float* __restrict__ agg_v,
    const float* __restrict__ xs, const float* __restrict__ xv,
    const float* __restrict__ W20, const float* __restrict__ W21,
    const float* __restrict__ Wsk0, const float* __restrict__ Wsk1,
    const int* __restrict__ nlist, const int* __restrict__ species,
    float* __restrict__ out, int N) {
    const int tid = threadIdx.x;
    const int b0 = blockIdx.x * 4;
    const int nid0 = nlist[min(b0 + 0, N - 1)];
    const int nid1 = nlist[min(b0 + 1, N - 1)];
    const int nid2 = nlist[min(b0 + 2, N - 1)];
    const int nid3 = nlist[min(b0 + 3, N - 1)];

    __shared__ float as_l[4 * 256];
    __shared__ float av_l[4 * 768];
    __shared__ float xs_l[4 * 128];
    __shared__ float xv_l[4 * 384];
    __shared__ float s_l[4 * 256];

    {
        as_l[0 * 256 + tid] = agg_s[(size_t)nid0 * 256 + tid];
        as_l[1 * 256 + tid] = agg_s[(size_t)nid1 * 256 + tid];
        as_l[2 * 256 + tid] = agg_s[(size_t)nid2 * 256 + tid];
        as_l[3 * 256 + tid] = agg_s[(size_t)nid3 * 256 + tid];
        for (int i = tid; i < 768; i += 256) {
            av_l[0 * 768 + i] = agg_v[(size_t)nid0 * 768 + i];
            av_l[1 * 768 + i] = agg_v[(size_t)nid1 * 768 + i];
            av_l[2 * 768 + i] = agg_v[(size_t)nid2 * 768 + i];
            av_l[3 * 768 + i] = agg_v[(size_t)nid3 * 768 + i];
        }
        if (tid < 128) {
            xs_l[0 * 128 + tid] = xs[(size_t)nid0 * 128 + tid];
            xs_l[1 * 128 + tid] = xs[(size_t)nid1 * 128 + tid];
            xs_l[2 * 128 + tid] = xs[(size_t)nid2 * 128 + tid];
            xs_l[3 * 128 + tid] = xs[(size_t)nid3 * 128 + tid];
        }
        for (int i = tid; i < 384; i += 256) {
            xv_l[0 * 384 + i] = xv[(size_t)nid0 * 384 + i];
            xv_l[1 * 384 + i] = xv[(size_t)nid1 * 384 + i];
            xv_l[2 * 384 + i] = xv[(size_t)nid2 * 384 + i];
            xv_l[3 * 384 + i] = xv[(size_t)nid3 * 384 + i];
        }
    }
    const int sp0 = species[nid0], sp1 = species[nid1];
    const int sp2 = species[nid2], sp3 = species[nid3];
    const bool uni = (sp0 == sp1) && (sp1 == sp2) && (sp2 == sp3);
    __syncthreads();

    const float k_mat = 0.17677669529663687f * 0.0625f; // inv_nb * inv_2c
    const float inv_c = 0.08838834764831845f;

    {
        const int d = tid;
        float am[4] = {0.f, 0.f, 0.f, 0.f};
        for (int cc = 0; cc < 256; cc++) {
            float w = W20[cc * 256 + d];
            #pragma unroll
            for (int n = 0; n < 4; n++) am[n] += as_l[n * 256 + cc] * w;
        }
        float ak[4] = {0.f, 0.f, 0.f, 0.f};
        if (uni) {
            for (int cc = 0; cc < 128; cc++) {
                float w = Wsk0[((size_t)sp0 * 128 + cc) * 256 + d];
                #pragma unroll
                for (int n = 0; n < 4; n++) ak[n] += xs_l[n * 128 + cc] * w;
            }
        } else {
            for (int cc = 0; cc < 128; cc++) {
                float w0v = Wsk0[((size_t)sp0 * 128 + cc) * 256 + d];
                float w1v = Wsk0[((size_t)sp1 * 128 + cc) * 256 + d];
                float w2v = Wsk0[((size_t)sp2 * 128 + cc) * 256 + d];
                float w3v = Wsk0[((size_t)sp3 * 128 + cc) * 256 + d];
                ak[0] += xs_l[0 * 128 + cc] * w0v;
                ak[1] += xs_l[1 * 128 + cc] * w1v;
                ak[2] += xs_l[2 * 128 + cc] * w2v;
                ak[3] += xs_l[3 * 128 + cc] * w3v;
            }
        }
        #pragma unroll
        for (int n = 0; n < 4; n++) s_l[n * 256 + d] = am[n] * k_mat + ak[n] * inv_c;
    }
    __syncthreads();

    if (tid < 128) {
        out[(size_t)nid0 * 512 + tid] = silu_f(s_l[0 * 256 + tid]);
        out[(size_t)nid1 * 512 + tid] = silu_f(s_l[1 * 256 + tid]);
        out[(size_t)nid2 * 512 + tid] = silu_f(s_l[2 * 256 + tid]);
        out[(size_t)nid3 * 512 + tid] = silu_f(s_l[3 * 256 + tid]);
    }

    {
        const int d = tid & 127;
        const int half = tid >> 7;
        const int nA = half ? nid2 : nid0;
        const int nB = half ? nid3 : nid1;
        const int sA = half ? sp2 : sp0;
        const int sB = half ? sp3 : sp1;
        const int la = half ? 2 : 0;
        const int lb = half ? 3 : 1;

        float am[2][3] = {};
        for (int cc = 0; cc < 256; cc++) {
            float w = W21[cc * 128 + d];
            #pragma unroll
            for (int i = 0; i < 3; i++) {
                am[0][i] += av_l[la * 768 + cc * 3 + i] * w;
                am[1][i] += av_l[lb * 768 + cc * 3 + i] * w;
            }
        }
        float ak[2][3] = {};
        if (uni) {
            for (int cc = 0; cc < 128; cc++) {
                float w = Wsk1[((size_t)sp0 * 128 + cc) * 128 + d];
                #pragma unroll
                for (int i = 0; i < 3; i++) {
                    ak[0][i] += xv_l[la * 384 + cc * 3 + i] * w;
                    ak[1][i] += xv_l[lb * 384 + cc * 3 + i] * w;
                }
            }
        } else {
            for (int cc = 0; cc < 128; cc++) {
                float wA = Wsk1[((size_t)sA * 128 + cc) * 128 + d];
                float wB = Wsk1[((size_t)sB * 128 + cc) * 128 + d];
                #pragma unroll
                for (int i = 0; i < 3; i++) {
                    ak[0][i] += xv_l[la * 384 + cc * 3 + i] * wA;
                    ak[1][i] += xv_l[lb * 384 + cc * 3 + i] * wB;
                }
            }
        }
        float gA = silu_f(s_l[la * 256 + 128 + d]);
        float gB = silu_f(s_l[lb * 256 + 128 + d]);
        float* oA = out + (size_t)nA * 512 + 128 + d * 3;
        float* oB = out + (size_t)nB * 512 + 128 + d * 3;
        #pragma unroll
        for (int i = 0; i < 3; i++) {
            oA[i] = (am[0][i] * k_mat + ak[0][i] * inv_c) * gA;
            oB[i] = (am[1][i] * k_mat + ak[1][i] * inv_c) * gB;
        }
    }
}

extern "C" void kernel_launch(void* const* d_in, const int* in_sizes, int n_in,
                              void* d_out, int out_size, void* d_ws, size_t ws_size,
                              hipStream_t stream) {
    const float* xs   = (const float*)d_in[0];
    const float* xv   = (const float*)d_in[1];
    const float* evec = (const float*)d_in[2];
    const float* rb   = (const float*)d_in[3];
    const float* W10  = (const float*)d_in[4];
    const float* W11  = (const float*)d_in[5];
    const float* w0   = (const float*)d_in[6];
    const float* w1   = (const float*)d_in[7];
    const float* w2   = (const float*)d_in[8];
    const float* w3   = (const float*)d_in[9];
    const float* W20  = (const float*)d_in[10];
    const float* W21  = (const float*)d_in[11];
    const float* Wsk0 = (const float*)d_in[12];
    const float* Wsk1 = (const float*)d_in[13];
    const int* species = (const int*)d_in[14];
    const int* snd = (const int*)d_in[15];
    const int* rcv = (const int*)d_in[16];

    const int N = in_sizes[0] / CC;   // 4000
    const int E = in_sizes[2] / 3;    // 128000
    const int NP = N * CC;
    int NS = in_sizes[12] / (CC * 2 * CC);   // 5
    if (NS < 1) NS = 1;
    if (NS > 63) NS = 63;

    float* ws   = (float*)d_ws;
    float* y0   = ws;
    float* y1   = y0 + (size_t)N * CC;
    float* aggs = y1 + (size_t)N * CC * 3;
    float* aggv = aggs + (size_t)N * 2 * CC;
    float* w0T  = aggv + (size_t)N * 2 * CC * 3;
    float* w1T  = w0T + 64 * 8;
    float* w2T  = w1T + 64 * 64;
    float* w3T  = w2T + 64 * 64;
    unsigned short* w3bs = (unsigned short*)(w3T + 512 * 64);
    unsigned short* w0b  = w3bs + 32768;
    unsigned short* w1b  = w0b + 2048;
    unsigned short* w2b  = w1b + 4096;
    // contiguous counter block (single memset): deg, cur, scnt, soff, scur
    int*   deg  = (int*)(w2b + 4096);
    int*   cur  = deg + 4096;
    int*   scnt = cur + 4096;                // 64
    int*   soff = scnt + 64;                 // 72
    int*   scur = soff + 72;                 // 64
    int*   off  = scur + 64;                 // 4160
    int*   elist = off + 4160;
    float4* up  = (float4*)(elist + E);
    int*   sp   = (int*)(up + E);
    int*   nlist = sp + E;                   // N
    void*  big  = (void*)(nlist + N);

    size_t base_bytes = (size_t)((char*)big - (char*)d_ws);
    size_t wq_bytes   = (size_t)E * 256 * sizeof(unsigned int);
    size_t need_A = base_bytes + wq_bytes;
    size_t need_B = base_bytes + (size_t)E * WDIM * sizeof(unsigned short);

    unsigned int*   Wq  = (unsigned int*)big;
    unsigned short* Wp  = (unsigned short*)big;

    hipMemsetAsync(deg, 0, (4096 + 4096 + 64 + 72 + 64) * sizeof(int), stream);
    hipLaunchKernelGGL(k_hist, dim3((E + 255) / 256), dim3(256), 0, stream,
                       rcv, deg, E, species, scnt, N);
    hipLaunchKernelGGL(k_scan, dim3(1), dim3(1024), 0, stream,
                       deg, off, N, scnt, soff, NS);
    hipLaunchKernelGGL(k_scatter, dim3((E + 255) / 256), dim3(256), 0, stream,
                       rcv, off, cur, elist, E, species, soff, scur, nlist, N);
    hipLaunchKernelGGL(k_prep, dim3(128), dim3(256), 0, stream,
                       w0, w1, w2, w3, w0T, w1T, w2T, w3T, w3bs, w0b, w1b, w2b);
    hipLaunchKernelGGL(k_node_lin, dim3(N / 2), dim3(128), 0, stream,
                       xs, xv, W10, W11, y0, y1, N);

    if (ws_size >= need_A && (E % 64) == 0) {
        hipLaunchKernelGGL(k_mlpw3, dim3(E / 64), dim3(256), 0, stream,
                           rb, elist, snd, evec, w0b, w1b, w2b, w3bs, Wq, up, sp, E);
        hipLaunchKernelGGL(k_gather_em, dim3(N), dim3(256), 0, stream,
                           off, up, sp, Wq, y0, y1, NP, aggs, aggv);
    } else if (ws_size >= need_B) {
        hipLaunchKernelGGL(k_mlp_wp, dim3((E + 255) / 256, 4), dim3(256), 0, stream,
                           rb, elist, w0T, w1T, w2T, w3T, Wp, E);
        hipLaunchKernelGGL(k_gather_wg, dim3(N), dim3(512), 0, stream,
                           off, elist, snd, evec, Wp, E, y0, y1, NP, aggs, aggv);
    } else {
        hipLaunchKernelGGL(k_mlp, dim3((E + 255) / 256), dim3(256), 0, stream,
                           rb, w0T, w1T, w2T, (float*)big, E);
        hipLaunchKernelGGL(k_gather_h2, dim3(N), dim3(512), 0, stream,
                           off, elist, snd, evec, (const float*)big, w3T,
                           y0, y1, NP, aggs, aggv);
    }

    hipLaunchKernelGGL(k_node_out, dim3((N + 3) / 4), dim3(256), 0, stream,
                       aggs, aggv, xs, xv, W20, W21, Wsk0, Wsk1, nlist, species,
                       (float*)d_out, N);
}

// Round 19
// 272.816 us; speedup vs baseline: 1.3003x; 1.0531x over previous
//
#include <hip/hip_runtime.h>
#include <math.h>

#define CC 128
#define HH 64
#define RBD 8
#define WDIM 512

typedef __attribute__((ext_vector_type(8))) short short8v;
typedef __attribute__((ext_vector_type(4))) float f32x4;

__device__ __forceinline__ float silu_f(float x) {
    return x / (1.0f + __expf(-x));
}

__device__ __forceinline__ unsigned short f2bf(float x) {
    unsigned int b = __float_as_uint(x);
    unsigned int r = (b + 0x7FFFu + ((b >> 16) & 1u)) >> 16;
    return (unsigned short)r;
}

__device__ __forceinline__ float bf2f(unsigned short u) {
    return __uint_as_float(((unsigned int)u) << 16);
}

// ---------------- merged prep + histograms ----------------
__global__ void k_prep_hist(const float* __restrict__ w0, const float* __restrict__ w1,
                            const float* __restrict__ w2, const float* __restrict__ w3,
                            float* __restrict__ w0T, float* __restrict__ w1T,
                            float* __restrict__ w2T, float* __restrict__ w3T,
                            unsigned short* __restrict__ w3bs,
                            unsigned short* __restrict__ w0b,
                            unsigned short* __restrict__ w1b,
                            unsigned short* __restrict__ w2b,
                            const int* __restrict__ rcv, int* __restrict__ deg, int E_,
                            const int* __restrict__ species, int* __restrict__ scnt, int N) {
    int i = blockIdx.x * blockDim.x + threadIdx.x;
    if (i < E_) atomicAdd(&deg[rcv[i]], 1);
    if (i < N) atomicAdd(&scnt[species[i]], 1);
    if (i < 64 * 8) { int m = i / 8, k = i % 8; w0T[i] = w0[k * 64 + m]; }
    if (i < 64 * 64) { int m = i / 64, k = i % 64; w1T[i] = w1[k * 64 + m]; w2T[i] = w2[k * 64 + m]; }
    if (i < 512 * 64) { int j = i / 64, k = i % 64; w3T[i] = w3[k * 512 + j]; }
    if (i < 32768) {
        int t = i >> 10, ch = (i >> 9) & 1, lane = (i >> 3) & 63, j = i & 7;
        int k = ch * 32 + 8 * (lane >> 4) + j;
        int n = t * 16 + (lane & 15);
        w3bs[i] = f2bf(w3[k * 512 + n]);
    }
    if (i < 2048) {
        int t = i >> 9, lane = (i >> 3) & 63, j = i & 7;
        int k = 8 * (lane >> 4) + j;
        int col = t * 16 + (lane & 15);
        w0b[i] = (k < RBD) ? f2bf(w0[k * 64 + col]) : (unsigned short)0;
    }
    if (i < 4096) {
        int f = i >> 9, lane = (i >> 3) & 63, j = i & 7;
        int ks = f >> 2, t = f & 3;
        int k = ks * 32 + 8 * (lane >> 4) + j;
        int col = t * 16 + (lane & 15);
        w1b[i] = f2bf(w1[k * 64 + col]);
        w2b[i] = f2bf(w2[k * 64 + col]);
    }
}

__global__ __launch_bounds__(1024) void k_scan(const int* __restrict__ deg,
                                               int* __restrict__ off, int N,
                                               const int* __restrict__ scnt,
                                               int* __restrict__ soff, int NS) {
    __shared__ int s[1024];
    int t = threadIdx.x;
    int b = t * 4;
    int a0 = (b + 0 < N) ? deg[b + 0] : 0;
    int a1 = (b + 1 < N) ? deg[b + 1] : 0;
    int a2 = (b + 2 < N) ? deg[b + 2] : 0;
    int a3 = (b + 3 < N) ? deg[b + 3] : 0;
    int part = a0 + a1 + a2 + a3;
    s[t] = part;
    __syncthreads();
    for (int d = 1; d < 1024; d <<= 1) {
        int v = (t >= d) ? s[t - d] : 0;
        __syncthreads();
        s[t] += v;
        __syncthreads();
    }
    int excl = s[t] - part;
    if (b + 0 <= N) off[b + 0] = excl;
    if (b + 1 <= N) off[b + 1] = excl + a0;
    if (b + 2 <= N) off[b + 2] = excl + a0 + a1;
    if (b + 3 <= N) off[b + 3] = excl + a0 + a1 + a2;
    if (t == 0) {
        int acc = 0;
        for (int q = 0; q < NS; q++) { soff[q] = acc; acc += scnt[q]; }
        soff[NS] = acc;
    }
}

__global__ void k_scatter(const int* __restrict__ rcv, const int* __restrict__ off,
                          int* __restrict__ cur, int* __restrict__ elist, int E_,
                          const int* __restrict__ species, const int* __restrict__ soff,
                          int* __restrict__ scur, int* __restrict__ nlist, int N) {
    int e = blockIdx.x * blockDim.x + threadIdx.x;
    if (e < E_) {
        int r = rcv[e];
        int p = atomicAdd(&cur[r], 1);
        elist[off[r] + p] = e;
    }
    if (e < N) {
        int s = species[e];
        int p = atomicAdd(&scur[s], 1);
        nlist[soff[s] + p] = e;
    }
}

// ---------------- standalone node_lin (tiers B/C): LDS-staged ----------------
__global__ __launch_bounds__(256) void k_node_lin(
    const float* __restrict__ xs, const float* __restrict__ xv,
    const float* __restrict__ W10, const float* __restrict__ W11,
    float* __restrict__ y0, float* __restrict__ y1, int N) {
    const int tid = threadIdx.x;
    const int n0 = blockIdx.x * 2;
    const int NP = N * CC;
    const int d = tid & 127;
    const int nn = tid >> 7;
    const float inv_c = 0.08838834764831845f;

    __shared__ float xsl[2][128];
    __shared__ float xvl[2][384];
    if (tid < 256) xsl[tid >> 7][tid & 127] = xs[(size_t)n0 * 128 + tid];
    for (int i = tid; i < 768; i += 256) xvl[i / 384][i % 384] = xv[(size_t)n0 * 384 + i];
    __syncthreads();

    float a0 = 0.f, av0 = 0.f, av1 = 0.f, av2 = 0.f;
    #pragma unroll 4
    for (int c = 0; c < CC; c++) {
        float w10 = W10[c * CC + d];
        float w11 = W11[c * CC + d];
        float xsv = xsl[nn][c];
        a0 += xsv * w10;
        av0 += xvl[nn][c * 3 + 0] * w11;
        av1 += xvl[nn][c * 3 + 1] * w11;
        av2 += xvl[nn][c * 3 + 2] * w11;
    }
    y0[(size_t)(n0 + nn) * CC + d] = a0 * inv_c;
    y1[0 * NP + (size_t)(n0 + nn) * CC + d] = av0 * inv_c;
    y1[1 * NP + (size_t)(n0 + nn) * CC + d] = av1 * inv_c;
    y1[2 * NP + (size_t)(n0 + nn) * CC + d] = av2 * inv_c;
}

// ---------------- shared VALU MLP body (tiers B/C) ----------------
__device__ __forceinline__ void layer64(const float4* a, float4* b,
                                        const float* __restrict__ W) {
    #pragma unroll
    for (int m = 0; m < 16; m++) {
        float s0 = 0.f, s1 = 0.f, s2 = 0.f, s3 = 0.f;
        const float* w0p = W + (4 * m + 0) * 64;
        const float* w1p = W + (4 * m + 1) * 64;
        const float* w2p = W + (4 * m + 2) * 64;
        const float* w3p = W + (4 * m + 3) * 64;
        #pragma unroll
        for (int k = 0; k < 16; k++) {
            float4 av = a[k];
            s0 += av.x * w0p[4 * k + 0] + av.y * w0p[4 * k + 1] + av.z * w0p[4 * k + 2] + av.w * w0p[4 * k + 3];
            s1 += av.x * w1p[4 * k + 0] + av.y * w1p[4 * k + 1] + av.z * w1p[4 * k + 2] + av.w * w1p[4 * k + 3];
            s2 += av.x * w2p[4 * k + 0] + av.y * w2p[4 * k + 1] + av.z * w2p[4 * k + 2] + av.w * w2p[4 * k + 3];
            s3 += av.x * w3p[4 * k + 0] + av.y * w3p[4 * k + 1] + av.z * w3p[4 * k + 2] + av.w * w3p[4 * k + 3];
        }
        b[m] = make_float4(silu_f(s0), silu_f(s1), silu_f(s2), silu_f(s3));
    }
}

__device__ __forceinline__ void mlp_body(
    const float* __restrict__ rb, int e,
    const float* __restrict__ w0T, const float* __restrict__ w1T,
    const float* __restrict__ w2T, float4* a) {
    float rbv[RBD];
    #pragma unroll
    for (int k = 0; k < RBD; k++) rbv[k] = rb[(size_t)e * RBD + k];
    float4 b[16];
    #pragma unroll
    for (int m = 0; m < 16; m++) {
        float s0 = 0.f, s1 = 0.f, s2 = 0.f, s3 = 0.f;
        #pragma unroll
        for (int k = 0; k < RBD; k++) {
            float rv = rbv[k];
            s0 += rv * w0T[(4 * m + 0) * RBD + k];
            s1 += rv * w0T[(4 * m + 1) * RBD + k];
            s2 += rv * w0T[(4 * m + 2) * RBD + k];
            s3 += rv * w0T[(4 * m + 3) * RBD + k];
        }
        a[m] = make_float4(silu_f(s0), silu_f(s1), silu_f(s2), silu_f(s3));
    }
    layer64(a, b, w1T);
    layer64(b, a, w2T);   // a holds h2
}

// ---------------- tier A: fused {MFMA MLP + w3 GEMM + emeta} | node_lin ------
// Blocks [0, nblk_mlp): per-wave-private MLP pipeline (no barriers).
// Blocks [nblk_mlp, ...): LDS-staged node_lin (2 nodes, 256 threads).
// Branch is block-uniform -> barrier in the node_lin path is safe.
__global__ __launch_bounds__(256) void k_mlpw3(
    const float* __restrict__ rb, const int* __restrict__ elist,
    const int* __restrict__ snd, const float* __restrict__ evec,
    const unsigned short* __restrict__ w0b, const unsigned short* __restrict__ w1b,
    const unsigned short* __restrict__ w2b, const unsigned short* __restrict__ w3bs,
    unsigned int* __restrict__ Wq, float4* __restrict__ up, int* __restrict__ sp,
    int E_, int nblk_mlp,
    const float* __restrict__ xs, const float* __restrict__ xv,
    const float* __restrict__ W10, const float* __restrict__ W11,
    float* __restrict__ y0, float* __restrict__ y1, int NP) {
    __shared__ unsigned short hbuf[4][16][72];
    __shared__ float xsl[2][128];
    __shared__ float xvl[2][384];

    if (blockIdx.x >= nblk_mlp) {
        // ---------- node_lin tail ----------
        const int tid = threadIdx.x;
        const int n0 = (blockIdx.x - nblk_mlp) * 2;
        const int d = tid & 127;
        const int nn = tid >> 7;
        const float inv_c = 0.08838834764831845f;

        xsl[tid >> 7][tid & 127] = xs[(size_t)n0 * 128 + tid];
        for (int i = tid; i < 768; i += 256) xvl[i / 384][i % 384] = xv[(size_t)n0 * 384 + i];
        __syncthreads();

        float a0 = 0.f, av0 = 0.f, av1 = 0.f, av2 = 0.f;
        #pragma unroll 4
        for (int c = 0; c < CC; c++) {
            float w10 = W10[c * CC + d];
            float w11 = W11[c * CC + d];
            float xsv = xsl[nn][c];
            a0 += xsv * w10;
            av0 += xvl[nn][c * 3 + 0] * w11;
            av1 += xvl[nn][c * 3 + 1] * w11;
            av2 += xvl[nn][c * 3 + 2] * w11;
        }
        y0[(size_t)(n0 + nn) * CC + d] = a0 * inv_c;
        y1[0 * NP + (size_t)(n0 + nn) * CC + d] = av0 * inv_c;
        y1[1 * NP + (size_t)(n0 + nn) * CC + d] = av1 * inv_c;
        y1[2 * NP + (size_t)(n0 + nn) * CC + d] = av2 * inv_c;
        return;
    }

    // ---------- MLP + w3 GEMM ----------
    const int lane = threadIdx.x & 63;
    const int wv = threadIdx.x >> 6;
    const int rbk = blockIdx.x * 4 + wv;
    const int col = lane & 15;
    const int grp = lane >> 4;

    if (threadIdx.x < 64) {
        int p = blockIdx.x * 64 + threadIdx.x;
        if (p < E_) {
            int e = elist[p];
            float e0 = evec[(size_t)e * 3 + 0];
            float e1 = evec[(size_t)e * 3 + 1];
            float e2 = evec[(size_t)e * 3 + 2];
            float rn = sqrtf(e0 * e0 + e1 * e1 + e2 * e2);
            float inv = 1.0f / fmaxf(rn, 1e-12f);
            up[p] = make_float4(e0 * inv, e1 * inv, e2 * inv, 0.f);
            sp[p] = snd[e];
        }
    }

    short8v a0 = (short8v){0, 0, 0, 0, 0, 0, 0, 0};
    if (grp == 0) {
        int e = elist[rbk * 16 + col];
        const float* rp = rb + (size_t)e * RBD;
        #pragma unroll
        for (int j = 0; j < RBD; j++) a0[j] = (short)f2bf(rp[j]);
    }
    f32x4 acc[4];
    {
        const unsigned short* bp = w0b + (size_t)lane * 8;
        #pragma unroll
        for (int t = 0; t < 4; t++) {
            short8v b = *(const short8v*)(bp + (size_t)t * 512);
            acc[t] = __builtin_amdgcn_mfma_f32_16x16x32_bf16(
                a0, b, (f32x4){0.f, 0.f, 0.f, 0.f}, 0, 0, 0);
        }
    }
    #pragma unroll
    for (int t = 0; t < 4; t++)
        #pragma unroll
        for (int r = 0; r < 4; r++)
            hbuf[wv][grp * 4 + r][t * 16 + col] = f2bf(silu_f(acc[t][r]));

    {
        short8v aA = *(const short8v*)&hbuf[wv][col][8 * grp];
        short8v aB = *(const short8v*)&hbuf[wv][col][32 + 8 * grp];
        const unsigned short* bp = w1b + (size_t)lane * 8;
        #pragma unroll
        for (int t = 0; t < 4; t++) {
            short8v b0 = *(const short8v*)(bp + (size_t)(0 + t) * 512);
            short8v b1 = *(const short8v*)(bp + (size_t)(4 + t) * 512);
            f32x4 c = __builtin_amdgcn_mfma_f32_16x16x32_bf16(
                aA, b0, (f32x4){0.f, 0.f, 0.f, 0.f}, 0, 0, 0);
            acc[t] = __builtin_amdgcn_mfma_f32_16x16x32_bf16(aB, b1, c, 0, 0, 0);
        }
    }
    #pragma unroll
    for (int t = 0; t < 4; t++)
        #pragma unroll
        for (int r = 0; r < 4; r++)
            hbuf[wv][grp * 4 + r][t * 16 + col] = f2bf(silu_f(acc[t][r]));

    {
        short8v aA = *(const short8v*)&hbuf[wv][col][8 * grp];
        short8v aB = *(const short8v*)&hbuf[wv][col][32 + 8 * grp];
        const unsigned short* bp = w2b + (size_t)lane * 8;
        #pragma unroll
        for (int t = 0; t < 4; t++) {
            short8v b0 = *(const short8v*)(bp + (size_t)(0 + t) * 512);
            short8v b1 = *(const short8v*)(bp + (size_t)(4 + t) * 512);
            f32x4 c = __builtin_amdgcn_mfma_f32_16x16x32_bf16(
                aA, b0, (f32x4){0.f, 0.f, 0.f, 0.f}, 0, 0, 0);
            acc[t] = __builtin_amdgcn_mfma_f32_16x16x32_bf16(aB, b1, c, 0, 0, 0);
        }
    }
    #pragma unroll
    for (int t = 0; t < 4; t++)
        #pragma unroll
        for (int r = 0; r < 4; r++)
            hbuf[wv][grp * 4 + r][t * 16 + col] = f2bf(silu_f(acc[t][r]));

    short8v A0 = *(const short8v*)&hbuf[wv][col][8 * grp];
    short8v A1 = *(const short8v*)&hbuf[wv][col][32 + 8 * grp];

    f32x4 wacc[32];
    #pragma unroll
    for (int t = 0; t < 32; t++) wacc[t] = (f32x4){0.f, 0.f, 0.f, 0.f};

    const unsigned short* bbase = w3bs + (size_t)lane * 8;
    #pragma unroll
    for (int t = 0; t < 32; t++) {
        short8v b0 = *(const short8v*)(bbase + (size_t)(t * 2 + 0) * 512);
        short8v b1 = *(const short8v*)(bbase + (size_t)(t * 2 + 1) * 512);
        wacc[t] = __builtin_amdgcn_mfma_f32_16x16x32_bf16(A0, b0, wacc[t], 0, 0, 0);
        wacc[t] = __builtin_amdgcn_mfma_f32_16x16x32_bf16(A1, b1, wacc[t], 0, 0, 0);
    }

    const int rowq = grp * 4;
    const int jbase = rbk * 16 + rowq;
    #pragma unroll
    for (int t = 0; t < 16; t++) {
        #pragma unroll
        for (int rr = 0; rr < 4; rr++) {
            unsigned lo = f2bf(wacc[t][rr]);
            unsigned hi = f2bf(wacc[t + 16][rr]);
            Wq[(size_t)(jbase + rr) * 256 + t * 16 + col] = lo | (hi << 16);
        }
    }
}

// ---------------- tier A gather: edge-major, 4-edge unrolled ----------------
__global__ __launch_bounds__(256, 4) void k_gather_em(
    const int* __restrict__ off, const float4* __restrict__ up,
    const int* __restrict__ sp, const unsigned int* __restrict__ Wq,
    const float* __restrict__ y0, const float* __restrict__ y1, int NP,
    float* __restrict__ agg_s, float* __restrict__ agg_v) {
    const int r = blockIdx.x;
    const int tid = threadIdx.x;
    const int half = tid >> 7;
    const int c = tid & 127;
    const int start = off[r];
    const int end = off[r + 1];

    float accs = 0.f, av0 = 0.f, av1 = 0.f, av2 = 0.f;
    const float SQ3 = 1.7320508075688772f;

    auto proc = [&](unsigned wq, float4 u, int s) {
        float wa = bf2f((unsigned short)(wq & 0xFFFFu));
        float wb = bf2f((unsigned short)(wq >> 16));
        if (half == 0) {
            float f = y0[(size_t)s * CC + c];
            accs += f * wa;
            float bb = f * wb * SQ3;
            av0 += bb * u.x; av1 += bb * u.y; av2 += bb * u.z;
        } else {
            float f0 = y1[0 * NP + s * CC + c];
            float f1 = y1[1 * NP + s * CC + c];
            float f2 = y1[2 * NP + s * CC + c];
            accs += (f0 * u.x + f1 * u.y + f2 * u.z) * wa;
            av0 += f0 * wb; av1 += f1 * wb; av2 += f2 * wb;
        }
    };

    int j = start;
    for (; j + 4 <= end; j += 4) {
        unsigned wq0 = Wq[(size_t)(j + 0) * 256 + tid];
        unsigned wq1 = Wq[(size_t)(j + 1) * 256 + tid];
        unsigned wq2 = Wq[(size_t)(j + 2) * 256 + tid];
        unsigned wq3 = Wq[(size_t)(j + 3) * 256 + tid];
        float4 u0 = up[j + 0], u1 = up[j + 1], u2 = up[j + 2], u3 = up[j + 3];
        int s0 = __builtin_amdgcn_readfirstlane(sp[j + 0]);
        int s1 = __builtin_amdgcn_readfirstlane(sp[j + 1]);
        int s2 = __builtin_amdgcn_readfirstlane(sp[j + 2]);
        int s3 = __builtin_amdgcn_readfirstlane(sp[j + 3]);
        proc(wq0, u0, s0);
        proc(wq1, u1, s1);
        proc(wq2, u2, s2);
        proc(wq3, u3, s3);
    }
    for (; j < end; j++) {
        unsigned wq = Wq[(size_t)j * 256 + tid];
        float4 u = up[j];
        int s = __builtin_amdgcn_readfirstlane(sp[j]);
        proc(wq, u, s);
    }

    agg_s[(size_t)r * 256 + tid] = accs;
    float* o = agg_v + ((size_t)r * 256 + tid) * 3;
    o[0] = av0; o[1] = av1; o[2] = av2;
}

// ---------------- tier B: VALU writer (grouped layout) + its gather ----------------
__global__ __launch_bounds__(256) void k_mlp_wp(
    const float* __restrict__ rb, const int* __restrict__ elist,
    const float* __restrict__ w0T, const float* __restrict__ w1T,
    const float* __restrict__ w2T, const float* __restrict__ w3T,
    unsigned short* __restrict__ Wp, int E_) {
    int p = blockIdx.x * blockDim.x + threadIdx.x;
    if (p >= E_) return;
    int e = elist[p];
    const int c0 = blockIdx.y * 128;

    float4 a[16];
    mlp_body(rb, e, w0T, w1T, w2T, a);

    const size_t E4 = (size_t)E_ * 4;
    for (int c = c0; c < c0 + 128; c += 8) {
        float s[8];
        #pragma unroll
        for (int q = 0; q < 8; q++) {
            const float* rp = w3T + (size_t)(c + q) * 64;
            float t0 = 0.f, t1 = 0.f, t2 = 0.f, t3 = 0.f;
            #pragma unroll
            for (int k = 0; k < 16; k++) {
                float4 h = a[k];
                t0 += h.x * rp[4 * k + 0];
                t1 += h.y * rp[4 * k + 1];
                t2 += h.z * rp[4 * k + 2];
                t3 += h.w * rp[4 * k + 3];
            }
            s[q] = (t0 + t1) + (t2 + t3);
        }
        ushort4 pk0 = make_ushort4(f2bf(s[0]), f2bf(s[1]), f2bf(s[2]), f2bf(s[3]));
        ushort4 pk1 = make_ushort4(f2bf(s[4]), f2bf(s[5]), f2bf(s[6]), f2bf(s[7]));
        *(ushort4*)(Wp + (size_t)(c >> 2) * E4 + (size_t)p * 4) = pk0;
        *(ushort4*)(Wp + (size_t)((c >> 2) + 1) * E4 + (size_t)p * 4) = pk1;
    }
}

__global__ __launch_bounds__(512, 2) void k_gather_wg(
    const int* __restrict__ off, const int* __restrict__ elist,
    const int* __restrict__ snd, const float* __restrict__ evec,
    const unsigned short* __restrict__ Wp, int E_,
    const float* __restrict__ y0, const float* __restrict__ y1, int NP,
    float* __restrict__ agg_s, float* __restrict__ agg_v) {
    const int r = blockIdx.x;
    const int tid = threadIdx.x;
    const int part = tid >> 7;
    const int c = tid & 127;

    const int start = off[r];
    const int end = off[r + 1];

    const unsigned short* __restrict__ wstream =
        Wp + (size_t)(tid >> 2) * ((size_t)E_ * 4) + (tid & 3);

    float acc0 = 0.f, acc1 = 0.f, acc2 = 0.f;
    const float SQ3 = 1.7320508075688772f;

    #pragma unroll 2
    for (int j = start; j < end; j++) {
        int e = elist[j];
        e = __builtin_amdgcn_readfirstlane(e);
        int s = snd[e];
        s = __builtin_amdgcn_readfirstlane(s);

        float e0 = evec[(size_t)e * 3 + 0];
        float e1 = evec[(size_t)e * 3 + 1];
        float e2 = evec[(size_t)e * 3 + 2];
        float rn = sqrtf(e0 * e0 + e1 * e1 + e2 * e2);
        float inv = 1.0f / fmaxf(rn, 1e-12f);
        float ux = e0 * inv, uy = e1 * inv, uz = e2 * inv;

        float w = bf2f(wstream[(size_t)j * 4]);

        if (part == 0) {
            acc0 += y0[(size_t)s * CC + c] * w;
        } else if (part == 1) {
            float f = y1[0 * NP + s * CC + c] * ux
                    + y1[1 * NP + s * CC + c] * uy
                    + y1[2 * NP + s * CC + c] * uz;
            acc0 += f * w;
        } else if (part == 2) {
            float bb = y0[(size_t)s * CC + c] * w * SQ3;
            acc0 += bb * ux; acc1 += bb * uy; acc2 += bb * uz;
        } else {
            acc0 += y1[0 * NP + s * CC + c] * w;
            acc1 += y1[1 * NP + s * CC + c] * w;
            acc2 += y1[2 * NP + s * CC + c] * w;
        }
    }

    if (part == 0) {
        agg_s[(size_t)r * 256 + c] = acc0;
    } else if (part == 1) {
        agg_s[(size_t)r * 256 + 128 + c] = acc0;
    } else if (part == 2) {
        float* o = agg_v + ((size_t)r * 256 + c) * 3;
        o[0] = acc0; o[1] = acc1; o[2] = acc2;
    } else {
        float* o = agg_v + ((size_t)r * 256 + 128 + c) * 3;
        o[0] = acc0; o[1] = acc1; o[2] = acc2;
    }
}

// ---------------- tier C: f32 h2 fallback ----------------
__global__ void k_mlp(const float* __restrict__ rb,
                      const float* __restrict__ w0T, const float* __restrict__ w1T,
                      const float* __restrict__ w2T,
                      float* __restrict__ h2, int E_) {
    int e = blockIdx.x * blockDim.x + threadIdx.x;
    if (e >= E_) return;
    float4 a[16];
    mlp_body(rb, e, w0T, w1T, w2T, a);
    float4* out = (float4*)(h2 + (size_t)e * HH);
    #pragma unroll
    for (int q = 0; q < 16; q++) out[q] = a[q];
}

__global__ __launch_bounds__(512, 1) void k_gather_h2(
    const int* __restrict__ off, const int* __restrict__ elist,
    const int* __restrict__ snd, const float* __restrict__ evec,
    const float* __restrict__ h2, const float* __restrict__ w3T,
    const float* __restrict__ y0, const float* __restrict__ y1, int NP,
    float* __restrict__ agg_s, float* __restrict__ agg_v) {
    const int r = blockIdx.x;
    const int tid = threadIdx.x;
    const int part = tid >> 7;
    const int c = tid & 127;

    const float4* wp = (const float4*)(w3T + (size_t)tid * 64);
    const int start = off[r];
    const int end = off[r + 1];

    float acc0 = 0.f, acc1 = 0.f, acc2 = 0.f;
    const float SQ3 = 1.7320508075688772f;

    for (int j = start; j < end; j++) {
        int e = elist[j];
        e = __builtin_amdgcn_readfirstlane(e);
        int s = snd[e];
        s = __builtin_amdgcn_readfirstlane(s);

        float e0 = evec[(size_t)e * 3 + 0];
        float e1 = evec[(size_t)e * 3 + 1];
        float e2 = evec[(size_t)e * 3 + 2];
        float rn = sqrtf(e0 * e0 + e1 * e1 + e2 * e2);
        float inv = 1.0f / fmaxf(rn, 1e-12f);
        float ux = e0 * inv, uy = e1 * inv, uz = e2 * inv;

        const float4* __restrict__ hp = (const float4*)(h2 + ((size_t)e << 6));
        float ws0 = 0.f, ws1 = 0.f, ws2 = 0.f, ws3 = 0.f;
        #pragma unroll
        for (int k = 0; k < 16; k++) {
            float4 h = hp[k];
            float4 wv = wp[k];
            ws0 += h.x * wv.x; ws1 += h.y * wv.y; ws2 += h.z * wv.z; ws3 += h.w * wv.w;
        }
        float w = (ws0 + ws1) + (ws2 + ws3);

        if (part == 0) {
            acc0 += y0[(size_t)s * CC + c] * w;
        } else if (part == 1) {
            float f = y1[0 * NP + s * CC + c] * ux
                    + y1[1 * NP + s * CC + c] * uy
                    + y1[2 * NP + s * CC + c] * uz;
            acc0 += f * w;
        } else if (part == 2) {
            float bb = y0[(size_t)s * CC + c] * w * SQ3;
            acc0 += bb * ux; acc1 += bb * uy; acc2 += bb * uz;
        } else {
            acc0 += y1[0 * NP + s * CC + c] * w;
            acc1 += y1[1 * NP + s * CC + c] * w;
            acc2 += y1[2 * NP + s * CC + c] * w;
        }
    }

    if (part == 0) {
        agg_s[(size_t)r * 256 + c] = acc0;
    } else if (part == 1) {
        agg_s[(size_t)r * 256 + 128 + c] = acc0;
    } else if (part == 2) {
        float* o = agg_v + ((size_t)r * 256 + c) * 3;
        o[0] = acc0; o[1] = acc1; o[2] = acc2;
    } else {
        float* o = agg_v + ((size_t)r * 256 + 128 + c) * 3;
        o[0] = acc0; o[1] = acc1; o[2] = acc2;
    }
}

// ---------------- node output (species-sorted, coalesced W) ----------------
__global__ __launch_bounds__(256) void k_node_out(
    const float* __restrict__ agg_s, const float* __restrict__ agg_v,
    const float* __restrict__ xs, const float* __restrict__ xv,
    const float* __restrict__ W20, const float* __restrict__ W21,
    const float* __restrict__ Wsk0, const float* __restrict__ Wsk1,
    const int* __restrict__ nlist, const int* __restrict__ species,
    float* __restrict__ out, int N) {
    const int tid = threadIdx.x;
    const int b0 = blockIdx.x * 4;
    const int nid0 = nlist[min(b0 + 0, N - 1)];
    const int nid1 = nlist[min(b0 + 1, N - 1)];
    const int nid2 = nlist[min(b0 + 2, N - 1)];
    const int nid3 = nlist[min(b0 + 3, N - 1)];

    __shared__ float as_l[4 * 256];
    __shared__ float av_l[4 * 768];
    __shared__ float xs_l[4 * 128];
    __shared__ float xv_l[4 * 384];
    __shared__ float s_l[4 * 256];

    {
        as_l[0 * 256 + tid] = agg_s[(size_t)nid0 * 256 + tid];
        as_l[1 * 256 + tid] = agg_s[(size_t)nid1 * 256 + tid];
        as_l[2 * 256 + tid] = agg_s[(size_t)nid2 * 256 + tid];
        as_l[3 * 256 + tid] = agg_s[(size_t)nid3 * 256 + tid];
        for (int i = tid; i < 768; i += 256) {
            av_l[0 * 768 + i] = agg_v[(size_t)nid0 * 768 + i];
            av_l[1 * 768 + i] = agg_v[(size_t)nid1 * 768 + i];
            av_l[2 * 768 + i] = agg_v[(size_t)nid2 * 768 + i];
            av_l[3 * 768 + i] = agg_v[(size_t)nid3 * 768 + i];
        }
        if (tid < 128) {
            xs_l[0 * 128 + tid] = xs[(size_t)nid0 * 128 + tid];
            xs_l[1 * 128 + tid] = xs[(size_t)nid1 * 128 + tid];
            xs_l[2 * 128 + tid] = xs[(size_t)nid2 * 128 + tid];
            xs_l[3 * 128 + tid] = xs[(size_t)nid3 * 128 + tid];
        }
        for (int i = tid; i < 384; i += 256) {
            xv_l[0 * 384 + i] = xv[(size_t)nid0 * 384 + i];
            xv_l[1 * 384 + i] = xv[(size_t)nid1 * 384 + i];
            xv_l[2 * 384 + i] = xv[(size_t)nid2 * 384 + i];
            xv_l[3 * 384 + i] = xv[(size_t)nid3 * 384 + i];
        }
    }
    const int sp0 = species[nid0], sp1 = species[nid1];
    const int sp2 = species[nid2], sp3 = species[nid3];
    const bool uni = (sp0 == sp1) && (sp1 == sp2) && (sp2 == sp3);
    __syncthreads();

    const float k_mat = 0.17677669529663687f * 0.0625f; // inv_nb * inv_2c
    const float inv_c = 0.08838834764831845f;

    {
        const int d = tid;
        float am[4] = {0.f, 0.f, 0.f, 0.f};
        for (int cc = 0; cc < 256; cc++) {
            float w = W20[cc * 256 + d];
            #pragma unroll
            for (int n = 0; n < 4; n++) am[n] += as_l[n * 256 + cc] * w;
        }
        float ak[4] = {0.f, 0.f, 0.f, 0.f};
        if (uni) {
            for (int cc = 0; cc < 128; cc++) {
                float w = Wsk0[((size_t)sp0 * 128 + cc) * 256 + d];
                #pragma unroll
                for (int n = 0; n < 4; n++) ak[n] += xs_l[n * 128 + cc] * w;
            }
        } else {
            for (int cc = 0; cc < 128; cc++) {
                float w0v = Wsk0[((size_t)sp0 * 128 + cc) * 256 + d];
                float w1v = Wsk0[((size_t)sp1 * 128 + cc) * 256 + d];
                float w2v = Wsk0[((size_t)sp2 * 128 + cc) * 256 + d];
                float w3v = Wsk0[((size_t)sp3 * 128 + cc) * 256 + d];
                ak[0] += xs_l[0 * 128 + cc] * w0v;
                ak[1] += xs_l[1 * 128 + cc] * w1v;
                ak[2] += xs_l[2 * 128 + cc] * w2v;
                ak[3] += xs_l[3 * 128 + cc] * w3v;
            }
        }
        #pragma unroll
        for (int n = 0; n < 4; n++) s_l[n * 256 + d] = am[n] * k_mat + ak[n] * inv_c;
    }
    __syncthreads();

    if (tid < 128) {
        out[(size_t)nid0 * 512 + tid] = silu_f(s_l[0 * 256 + tid]);
        out[(size_t)nid1 * 512 + tid] = silu_f(s_l[1 * 256 + tid]);
        out[(size_t)nid2 * 512 + tid] = silu_f(s_l[2 * 256 + tid]);
        out[(size_t)nid3 * 512 + tid] = silu_f(s_l[3 * 256 + tid]);
    }

    {
        const int d = tid & 127;
        const int half = tid >> 7;
        const int nA = half ? nid2 : nid0;
        const int nB = half ? nid3 : nid1;
        const int sA = half ? sp2 : sp0;
        const int sB = half ? sp3 : sp1;
        const int la = half ? 2 : 0;
        const int lb = half ? 3 : 1;

        float am[2][3] = {};
        for (int cc = 0; cc < 256; cc++) {
            float w = W21[cc * 128 + d];
            #pragma unroll
            for (int i = 0; i < 3; i++) {
                am[0][i] += av_l[la * 768 + cc * 3 + i] * w;
                am[1][i] += av_l[lb * 768 + cc * 3 + i] * w;
            }
        }
        float ak[2][3] = {};
        if (uni) {
            for (int cc = 0; cc < 128; cc++) {
                float w = Wsk1[((size_t)sp0 * 128 + cc) * 128 + d];
                #pragma unroll
                for (int i = 0; i < 3; i++) {
                    ak[0][i] += xv_l[la * 384 + cc * 3 + i] * w;
                    ak[1][i] += xv_l[lb * 384 + cc * 3 + i] * w;
                }
            }
        } else {
            for (int cc = 0; cc < 128; cc++) {
                float wA = Wsk1[((size_t)sA * 128 + cc) * 128 + d];
                float wB = Wsk1[((size_t)sB * 128 + cc) * 128 + d];
                #pragma unroll
                for (int i = 0; i < 3; i++) {
                    ak[0][i] += xv_l[la * 384 + cc * 3 + i] * wA;
                    ak[1][i] += xv_l[lb * 384 + cc * 3 + i] * wB;
                }
            }
        }
        float gA = silu_f(s_l[la * 256 + 128 + d]);
        float gB = silu_f(s_l[lb * 256 + 128 + d]);
        float* oA = out + (size_t)nA * 512 + 128 + d * 3;
        float* oB = out + (size_t)nB * 512 + 128 + d * 3;
        #pragma unroll
        for (int i = 0; i < 3; i++) {
            oA[i] = (am[0][i] * k_mat + ak[0][i] * inv_c) * gA;
            oB[i] = (am[1][i] * k_mat + ak[1][i] * inv_c) * gB;
        }
    }
}

extern "C" void kernel_launch(void* const* d_in, const int* in_sizes, int n_in,
                              void* d_out, int out_size, void* d_ws, size_t ws_size,
                              hipStream_t stream) {
    const float* xs   = (const float*)d_in[0];
    const float* xv   = (const float*)d_in[1];
    const float* evec = (const float*)d_in[2];
    const float* rb   = (const float*)d_in[3];
    const float* W10  = (const float*)d_in[4];
    const float* W11  = (const float*)d_in[5];
    const float* w0   = (const float*)d_in[6];
    const float* w1   = (const float*)d_in[7];
    const float* w2   = (const float*)d_in[8];
    const float* w3   = (const float*)d_in[9];
    const float* W20  = (const float*)d_in[10];
    const float* W21  = (const float*)d_in[11];
    const float* Wsk0 = (const float*)d_in[12];
    const float* Wsk1 = (const float*)d_in[13];
    const int* species = (const int*)d_in[14];
    const int* snd = (const int*)d_in[15];
    const int* rcv = (const int*)d_in[16];

    const int N = in_sizes[0] / CC;   // 4000
    const int E = in_sizes[2] / 3;    // 128000
    const int NP = N * CC;
    int NS = in_sizes[12] / (CC * 2 * CC);   // 5
    if (NS < 1) NS = 1;
    if (NS > 63) NS = 63;

    float* ws   = (float*)d_ws;
    float* y0   = ws;
    float* y1   = y0 + (size_t)N * CC;
    float* aggs = y1 + (size_t)N * CC * 3;
    float* aggv = aggs + (size_t)N * 2 * CC;
    float* w0T  = aggv + (size_t)N * 2 * CC * 3;
    float* w1T  = w0T + 64 * 8;
    float* w2T  = w1T + 64 * 64;
    float* w3T  = w2T + 64 * 64;
    unsigned short* w3bs = (unsigned short*)(w3T + 512 * 64);
    unsigned short* w0b  = w3bs + 32768;
    unsigned short* w1b  = w0b + 2048;
    unsigned short* w2b  = w1b + 4096;
    int*   deg  = (int*)(w2b + 4096);
    int*   cur  = deg + 4096;
    int*   scnt = cur + 4096;                // 64
    int*   soff = scnt + 64;                 // 72
    int*   scur = soff + 72;                 // 64
    int*   off  = scur + 64;                 // 4160
    int*   elist = off + 4160;
    float4* up  = (float4*)(elist + E);
    int*   sp   = (int*)(up + E);
    int*   nlist = sp + E;                   // N
    void*  big  = (void*)(nlist + N);

    size_t base_bytes = (size_t)((char*)big - (char*)d_ws);
    size_t wq_bytes   = (size_t)E * 256 * sizeof(unsigned int);
    size_t need_A = base_bytes + wq_bytes;
    size_t need_B = base_bytes + (size_t)E * WDIM * sizeof(unsigned short);

    unsigned int*   Wq  = (unsigned int*)big;
    unsigned short* Wp  = (unsigned short*)big;

    hipMemsetAsync(deg, 0, (4096 + 4096 + 64 + 72 + 64) * sizeof(int), stream);
    hipLaunchKernelGGL(k_prep_hist, dim3((E + 255) / 256), dim3(256), 0, stream,
                       w0, w1, w2, w3, w0T, w1T, w2T, w3T, w3bs, w0b, w1b, w2b,
                       rcv, deg, E, species, scnt, N);
    hipLaunchKernelGGL(k_scan, dim3(1), dim3(1024), 0, stream,
                       deg, off, N, scnt, soff, NS);
    hipLaunchKernelGGL(k_scatter, dim3((E + 255) / 256), dim3(256), 0, stream,
                       rcv, off, cur, elist, E, species, soff, scur, nlist, N);

    if (ws_size >= need_A && (E % 64) == 0 && (N % 2) == 0) {
        const int nblk_mlp = E / 64;
        hipLaunchKernelGGL(k_mlpw3, dim3(nblk_mlp + N / 2), dim3(256), 0, stream,
                           rb, elist, snd, evec, w0b, w1b, w2b, w3bs, Wq, up, sp,
                           E, nblk_mlp, xs, xv, W10, W11, y0, y1, NP);
        hipLaunchKernelGGL(k_gather_em, dim3(N), dim3(256), 0, stream,
                           off, up, sp, Wq, y0, y1, NP, aggs, aggv);
    } else if (ws_size >= need_B) {
        hipLaunchKernelGGL(k_node_lin, dim3((N + 1) / 2), dim3(256), 0, stream,
                           xs, xv, W10, W11, y0, y1, N);
        hipLaunchKernelGGL(k_mlp_wp, dim3((E + 255) / 256, 4), dim3(256), 0, stream,
                           rb, elist, w0T, w1T, w2T, w3T, Wp, E);
        hipLaunchKernelGGL(k_gather_wg, dim3(N), dim3(512), 0, stream,
                           off, elist, snd, evec, Wp, E, y0, y1, NP, aggs, aggv);
    } else {
        hipLaunchKernelGGL(k_node_lin, dim3((N + 1) / 2), dim3(256), 0, stream,
                           xs, xv, W10, W11, y0, y1, N);
        hipLaunchKernelGGL(k_mlp, dim3((E + 255) / 256), dim3(256), 0, stream,
                           rb, w0T, w1T, w2T, (float*)big, E);
        hipLaunchKernelGGL(k_gather_h2, dim3(N), dim3(512), 0, stream,
                           off, elist, snd, evec, (const float*)big, w3T,
                           y0, y1, NP, aggs, aggv);
    }

    hipLaunchKernelGGL(k_node_out, dim3((N + 3) / 4), dim3(256), 0, stream,
                       aggs, aggv, xs, xv, W20, W21, Wsk0, Wsk1, nlist, species,
                       (float*)d_out, N);
}

// Round 20
// 244.911 us; speedup vs baseline: 1.4485x; 1.1139x over previous
//
#include <hip/hip_runtime.h>
#include <math.h>

#define CC 128
#define HH 64
#define RBD 8
#define WDIM 512

typedef __attribute__((ext_vector_type(8))) short short8v;
typedef __attribute__((ext_vector_type(4))) float f32x4;

__device__ __forceinline__ float silu_f(float x) {
    return x / (1.0f + __expf(-x));
}

__device__ __forceinline__ unsigned short f2bf(float x) {
    unsigned int b = __float_as_uint(x);
    unsigned int r = (b + 0x7FFFu + ((b >> 16) & 1u)) >> 16;
    return (unsigned short)r;
}

__device__ __forceinline__ float bf2f(unsigned short u) {
    return __uint_as_float(((unsigned int)u) << 16);
}

// ---------------- merged prep + histograms ----------------
__global__ void k_prep_hist(const float* __restrict__ w0, const float* __restrict__ w1,
                            const float* __restrict__ w2, const float* __restrict__ w3,
                            float* __restrict__ w0T, float* __restrict__ w1T,
                            float* __restrict__ w2T, float* __restrict__ w3T,
                            unsigned short* __restrict__ w3bs,
                            unsigned short* __restrict__ w0b,
                            unsigned short* __restrict__ w1b,
                            unsigned short* __restrict__ w2b,
                            const int* __restrict__ rcv, int* __restrict__ deg, int E_,
                            const int* __restrict__ species, int* __restrict__ scnt, int N) {
    int i = blockIdx.x * blockDim.x + threadIdx.x;
    if (i < E_) atomicAdd(&deg[rcv[i]], 1);
    if (i < N) atomicAdd(&scnt[species[i]], 1);
    if (i < 64 * 8) { int m = i / 8, k = i % 8; w0T[i] = w0[k * 64 + m]; }
    if (i < 64 * 64) { int m = i / 64, k = i % 64; w1T[i] = w1[k * 64 + m]; w2T[i] = w2[k * 64 + m]; }
    if (i < 512 * 64) { int j = i / 64, k = i % 64; w3T[i] = w3[k * 512 + j]; }
    if (i < 32768) {
        int t = i >> 10, ch = (i >> 9) & 1, lane = (i >> 3) & 63, j = i & 7;
        int k = ch * 32 + 8 * (lane >> 4) + j;
        int n = t * 16 + (lane & 15);
        w3bs[i] = f2bf(w3[k * 512 + n]);
    }
    if (i < 2048) {
        int t = i >> 9, lane = (i >> 3) & 63, j = i & 7;
        int k = 8 * (lane >> 4) + j;
        int col = t * 16 + (lane & 15);
        w0b[i] = (k < RBD) ? f2bf(w0[k * 64 + col]) : (unsigned short)0;
    }
    if (i < 4096) {
        int f = i >> 9, lane = (i >> 3) & 63, j = i & 7;
        int ks = f >> 2, t = f & 3;
        int k = ks * 32 + 8 * (lane >> 4) + j;
        int col = t * 16 + (lane & 15);
        w1b[i] = f2bf(w1[k * 64 + col]);
        w2b[i] = f2bf(w2[k * 64 + col]);
    }
}

__global__ __launch_bounds__(1024) void k_scan(const int* __restrict__ deg,
                                               int* __restrict__ off, int N,
                                               const int* __restrict__ scnt,
                                               int* __restrict__ soff, int NS) {
    __shared__ int s[1024];
    int t = threadIdx.x;
    int b = t * 4;
    int a0 = (b + 0 < N) ? deg[b + 0] : 0;
    int a1 = (b + 1 < N) ? deg[b + 1] : 0;
    int a2 = (b + 2 < N) ? deg[b + 2] : 0;
    int a3 = (b + 3 < N) ? deg[b + 3] : 0;
    int part = a0 + a1 + a2 + a3;
    s[t] = part;
    __syncthreads();
    for (int d = 1; d < 1024; d <<= 1) {
        int v = (t >= d) ? s[t - d] : 0;
        __syncthreads();
        s[t] += v;
        __syncthreads();
    }
    int excl = s[t] - part;
    if (b + 0 <= N) off[b + 0] = excl;
    if (b + 1 <= N) off[b + 1] = excl + a0;
    if (b + 2 <= N) off[b + 2] = excl + a0 + a1;
    if (b + 3 <= N) off[b + 3] = excl + a0 + a1 + a2;
    if (t == 0) {
        int acc = 0;
        for (int q = 0; q < NS; q++) { soff[q] = acc; acc += scnt[q]; }
        soff[NS] = acc;
    }
}

__global__ void k_scatter(const int* __restrict__ rcv, const int* __restrict__ off,
                          int* __restrict__ cur, int* __restrict__ elist, int E_,
                          const int* __restrict__ species, const int* __restrict__ soff,
                          int* __restrict__ scur, int* __restrict__ nlist, int N) {
    int e = blockIdx.x * blockDim.x + threadIdx.x;
    if (e < E_) {
        int r = rcv[e];
        int p = atomicAdd(&cur[r], 1);
        elist[off[r] + p] = e;
    }
    if (e < N) {
        int s = species[e];
        int p = atomicAdd(&scur[s], 1);
        nlist[soff[s] + p] = e;
    }
}

// ---------------- standalone node_lin (tiers B/C): LDS-staged ----------------
__global__ __launch_bounds__(256) void k_node_lin(
    const float* __restrict__ xs, const float* __restrict__ xv,
    const float* __restrict__ W10, const float* __restrict__ W11,
    float* __restrict__ y0, float* __restrict__ y1, int N) {
    const int tid = threadIdx.x;
    const int n0 = blockIdx.x * 2;
    const int NP = N * CC;
    const int d = tid & 127;
    const int nn = tid >> 7;
    const float inv_c = 0.08838834764831845f;

    __shared__ float xsl[2][128];
    __shared__ float xvl[2][384];
    xsl[tid >> 7][tid & 127] = xs[(size_t)n0 * 128 + tid];
    for (int i = tid; i < 768; i += 256) xvl[i / 384][i % 384] = xv[(size_t)n0 * 384 + i];
    __syncthreads();

    float a0 = 0.f, av0 = 0.f, av1 = 0.f, av2 = 0.f;
    #pragma unroll 4
    for (int c = 0; c < CC; c++) {
        float w10 = W10[c * CC + d];
        float w11 = W11[c * CC + d];
        float xsv = xsl[nn][c];
        a0 += xsv * w10;
        av0 += xvl[nn][c * 3 + 0] * w11;
        av1 += xvl[nn][c * 3 + 1] * w11;
        av2 += xvl[nn][c * 3 + 2] * w11;
    }
    y0[(size_t)(n0 + nn) * CC + d] = a0 * inv_c;
    y1[0 * NP + (size_t)(n0 + nn) * CC + d] = av0 * inv_c;
    y1[1 * NP + (size_t)(n0 + nn) * CC + d] = av1 * inv_c;
    y1[2 * NP + (size_t)(n0 + nn) * CC + d] = av2 * inv_c;
}

// ---------------- shared VALU MLP body (tiers B/C) ----------------
__device__ __forceinline__ void layer64(const float4* a, float4* b,
                                        const float* __restrict__ W) {
    #pragma unroll
    for (int m = 0; m < 16; m++) {
        float s0 = 0.f, s1 = 0.f, s2 = 0.f, s3 = 0.f;
        const float* w0p = W + (4 * m + 0) * 64;
        const float* w1p = W + (4 * m + 1) * 64;
        const float* w2p = W + (4 * m + 2) * 64;
        const float* w3p = W + (4 * m + 3) * 64;
        #pragma unroll
        for (int k = 0; k < 16; k++) {
            float4 av = a[k];
            s0 += av.x * w0p[4 * k + 0] + av.y * w0p[4 * k + 1] + av.z * w0p[4 * k + 2] + av.w * w0p[4 * k + 3];
            s1 += av.x * w1p[4 * k + 0] + av.y * w1p[4 * k + 1] + av.z * w1p[4 * k + 2] + av.w * w1p[4 * k + 3];
            s2 += av.x * w2p[4 * k + 0] + av.y * w2p[4 * k + 1] + av.z * w2p[4 * k + 2] + av.w * w2p[4 * k + 3];
            s3 += av.x * w3p[4 * k + 0] + av.y * w3p[4 * k + 1] + av.z * w3p[4 * k + 2] + av.w * w3p[4 * k + 3];
        }
        b[m] = make_float4(silu_f(s0), silu_f(s1), silu_f(s2), silu_f(s3));
    }
}

__device__ __forceinline__ void mlp_body(
    const float* __restrict__ rb, int e,
    const float* __restrict__ w0T, const float* __restrict__ w1T,
    const float* __restrict__ w2T, float4* a) {
    float rbv[RBD];
    #pragma unroll
    for (int k = 0; k < RBD; k++) rbv[k] = rb[(size_t)e * RBD + k];
    float4 b[16];
    #pragma unroll
    for (int m = 0; m < 16; m++) {
        float s0 = 0.f, s1 = 0.f, s2 = 0.f, s3 = 0.f;
        #pragma unroll
        for (int k = 0; k < RBD; k++) {
            float rv = rbv[k];
            s0 += rv * w0T[(4 * m + 0) * RBD + k];
            s1 += rv * w0T[(4 * m + 1) * RBD + k];
            s2 += rv * w0T[(4 * m + 2) * RBD + k];
            s3 += rv * w0T[(4 * m + 3) * RBD + k];
        }
        a[m] = make_float4(silu_f(s0), silu_f(s1), silu_f(s2), silu_f(s3));
    }
    layer64(a, b, w1T);
    layer64(b, a, w2T);   // a holds h2
}

// ---------------- tier A: fused {MFMA MLP + w3 GEMM + emeta} | node_lin ------
// w3 GEMM runs as TWO sequential passes of 16 accumulators (pass p covers
// t in {8p..8p+7} U {16+8p..16+8p+7}, so each pass holds complete (t, t+16)
// pack-pairs). Halves the live acc registers 128 -> 64 on the unified
// VGPR/AGPR file -> +1 wave/SIMD occupancy.
__global__ __launch_bounds__(256) void k_mlpw3(
    const float* __restrict__ rb, const int* __restrict__ elist,
    const int* __restrict__ snd, const float* __restrict__ evec,
    const unsigned short* __restrict__ w0b, const unsigned short* __restrict__ w1b,
    const unsigned short* __restrict__ w2b, const unsigned short* __restrict__ w3bs,
    unsigned int* __restrict__ Wq, float4* __restrict__ up, int* __restrict__ sp,
    int E_, int nblk_mlp,
    const float* __restrict__ xs, const float* __restrict__ xv,
    const float* __restrict__ W10, const float* __restrict__ W11,
    float* __restrict__ y0, float* __restrict__ y1, int NP) {
    __shared__ unsigned short hbuf[4][16][72];
    __shared__ float xsl[2][128];
    __shared__ float xvl[2][384];

    if (blockIdx.x >= nblk_mlp) {
        // ---------- node_lin tail ----------
        const int tid = threadIdx.x;
        const int n0 = (blockIdx.x - nblk_mlp) * 2;
        const int d = tid & 127;
        const int nn = tid >> 7;
        const float inv_c = 0.08838834764831845f;

        xsl[tid >> 7][tid & 127] = xs[(size_t)n0 * 128 + tid];
        for (int i = tid; i < 768; i += 256) xvl[i / 384][i % 384] = xv[(size_t)n0 * 384 + i];
        __syncthreads();

        float a0 = 0.f, av0 = 0.f, av1 = 0.f, av2 = 0.f;
        #pragma unroll 4
        for (int c = 0; c < CC; c++) {
            float w10 = W10[c * CC + d];
            float w11 = W11[c * CC + d];
            float xsv = xsl[nn][c];
            a0 += xsv * w10;
            av0 += xvl[nn][c * 3 + 0] * w11;
            av1 += xvl[nn][c * 3 + 1] * w11;
            av2 += xvl[nn][c * 3 + 2] * w11;
        }
        y0[(size_t)(n0 + nn) * CC + d] = a0 * inv_c;
        y1[0 * NP + (size_t)(n0 + nn) * CC + d] = av0 * inv_c;
        y1[1 * NP + (size_t)(n0 + nn) * CC + d] = av1 * inv_c;
        y1[2 * NP + (size_t)(n0 + nn) * CC + d] = av2 * inv_c;
        return;
    }

    // ---------- MLP + w3 GEMM ----------
    const int lane = threadIdx.x & 63;
    const int wv = threadIdx.x >> 6;
    const int rbk = blockIdx.x * 4 + wv;
    const int col = lane & 15;
    const int grp = lane >> 4;

    if (threadIdx.x < 64) {
        int p = blockIdx.x * 64 + threadIdx.x;
        if (p < E_) {
            int e = elist[p];
            float e0 = evec[(size_t)e * 3 + 0];
            float e1 = evec[(size_t)e * 3 + 1];
            float e2 = evec[(size_t)e * 3 + 2];
            float rn = sqrtf(e0 * e0 + e1 * e1 + e2 * e2);
            float inv = 1.0f / fmaxf(rn, 1e-12f);
            up[p] = make_float4(e0 * inv, e1 * inv, e2 * inv, 0.f);
            sp[p] = snd[e];
        }
    }

    short8v a0 = (short8v){0, 0, 0, 0, 0, 0, 0, 0};
    if (grp == 0) {
        int e = elist[rbk * 16 + col];
        const float* rp = rb + (size_t)e * RBD;
        #pragma unroll
        for (int j = 0; j < RBD; j++) a0[j] = (short)f2bf(rp[j]);
    }
    f32x4 acc[4];
    {
        const unsigned short* bp = w0b + (size_t)lane * 8;
        #pragma unroll
        for (int t = 0; t < 4; t++) {
            short8v b = *(const short8v*)(bp + (size_t)t * 512);
            acc[t] = __builtin_amdgcn_mfma_f32_16x16x32_bf16(
                a0, b, (f32x4){0.f, 0.f, 0.f, 0.f}, 0, 0, 0);
        }
    }
    #pragma unroll
    for (int t = 0; t < 4; t++)
        #pragma unroll
        for (int r = 0; r < 4; r++)
            hbuf[wv][grp * 4 + r][t * 16 + col] = f2bf(silu_f(acc[t][r]));

    {
        short8v aA = *(const short8v*)&hbuf[wv][col][8 * grp];
        short8v aB = *(const short8v*)&hbuf[wv][col][32 + 8 * grp];
        const unsigned short* bp = w1b + (size_t)lane * 8;
        #pragma unroll
        for (int t = 0; t < 4; t++) {
            short8v b0 = *(const short8v*)(bp + (size_t)(0 + t) * 512);
            short8v b1 = *(const short8v*)(bp + (size_t)(4 + t) * 512);
            f32x4 c = __builtin_amdgcn_mfma_f32_16x16x32_bf16(
                aA, b0, (f32x4){0.f, 0.f, 0.f, 0.f}, 0, 0, 0);
            acc[t] = __builtin_amdgcn_mfma_f32_16x16x32_bf16(aB, b1, c, 0, 0, 0);
        }
    }
    #pragma unroll
    for (int t = 0; t < 4; t++)
        #pragma unroll
        for (int r = 0; r < 4; r++)
            hbuf[wv][grp * 4 + r][t * 16 + col] = f2bf(silu_f(acc[t][r]));

    {
        short8v aA = *(const short8v*)&hbuf[wv][col][8 * grp];
        short8v aB = *(const short8v*)&hbuf[wv][col][32 + 8 * grp];
        const unsigned short* bp = w2b + (size_t)lane * 8;
        #pragma unroll
        for (int t = 0; t < 4; t++) {
            short8v b0 = *(const short8v*)(bp + (size_t)(0 + t) * 512);
            short8v b1 = *(const short8v*)(bp + (size_t)(4 + t) * 512);
            f32x4 c = __builtin_amdgcn_mfma_f32_16x16x32_bf16(
                aA, b0, (f32x4){0.f, 0.f, 0.f, 0.f}, 0, 0, 0);
            acc[t] = __builtin_amdgcn_mfma_f32_16x16x32_bf16(aB, b1, c, 0, 0, 0);
        }
    }
    #pragma unroll
    for (int t = 0; t < 4; t++)
        #pragma unroll
        for (int r = 0; r < 4; r++)
            hbuf[wv][grp * 4 + r][t * 16 + col] = f2bf(silu_f(acc[t][r]));

    short8v A0 = *(const short8v*)&hbuf[wv][col][8 * grp];
    short8v A1 = *(const short8v*)&hbuf[wv][col][32 + 8 * grp];

    const unsigned short* bbase = w3bs + (size_t)lane * 8;
    const int rowq = grp * 4;
    const int jbase = rbk * 16 + rowq;

    #pragma unroll 1
    for (int pass = 0; pass < 2; pass++) {
        f32x4 wacc[16];
        #pragma unroll
        for (int q = 0; q < 16; q++) wacc[q] = (f32x4){0.f, 0.f, 0.f, 0.f};
        #pragma unroll
        for (int q = 0; q < 16; q++) {
            int t = (q < 8) ? (pass * 8 + q) : (16 + pass * 8 + (q - 8));
            short8v b0 = *(const short8v*)(bbase + (size_t)(t * 2 + 0) * 512);
            short8v b1 = *(const short8v*)(bbase + (size_t)(t * 2 + 1) * 512);
            wacc[q] = __builtin_amdgcn_mfma_f32_16x16x32_bf16(A0, b0, wacc[q], 0, 0, 0);
            wacc[q] = __builtin_amdgcn_mfma_f32_16x16x32_bf16(A1, b1, wacc[q], 0, 0, 0);
        }
        #pragma unroll
        for (int q = 0; q < 8; q++) {
            int t = pass * 8 + q;
            #pragma unroll
            for (int rr = 0; rr < 4; rr++) {
                unsigned lo = f2bf(wacc[q][rr]);
                unsigned hi = f2bf(wacc[q + 8][rr]);
                Wq[(size_t)(jbase + rr) * 256 + t * 16 + col] = lo | (hi << 16);
            }
        }
    }
}

// ---------------- tier A gather: edge-major, 4-edge unrolled ----------------
__global__ __launch_bounds__(256, 4) void k_gather_em(
    const int* __restrict__ off, const float4* __restrict__ up,
    const int* __restrict__ sp, const unsigned int* __restrict__ Wq,
    const float* __restrict__ y0, const float* __restrict__ y1, int NP,
    float* __restrict__ agg_s, float* __restrict__ agg_v) {
    const int r = blockIdx.x;
    const int tid = threadIdx.x;
    const int half = tid >> 7;
    const int c = tid & 127;
    const int start = off[r];
    const int end = off[r + 1];

    float accs = 0.f, av0 = 0.f, av1 = 0.f, av2 = 0.f;
    const float SQ3 = 1.7320508075688772f;

    auto proc = [&](unsigned wq, float4 u, int s) {
        float wa = bf2f((unsigned short)(wq & 0xFFFFu));
        float wb = bf2f((unsigned short)(wq >> 16));
        if (half == 0) {
            float f = y0[(size_t)s * CC + c];
            accs += f * wa;
            float bb = f * wb * SQ3;
            av0 += bb * u.x; av1 += bb * u.y; av2 += bb * u.z;
        } else {
            float f0 = y1[0 * NP + s * CC + c];
            float f1 = y1[1 * NP + s * CC + c];
            float f2 = y1[2 * NP + s * CC + c];
            accs += (f0 * u.x + f1 * u.y + f2 * u.z) * wa;
            av0 += f0 * wb; av1 += f1 * wb; av2 += f2 * wb;
        }
    };

    int j = start;
    for (; j + 4 <= end; j += 4) {
        unsigned wq0 = Wq[(size_t)(j + 0) * 256 + tid];
        unsigned wq1 = Wq[(size_t)(j + 1) * 256 + tid];
        unsigned wq2 = Wq[(size_t)(j + 2) * 256 + tid];
        unsigned wq3 = Wq[(size_t)(j + 3) * 256 + tid];
        float4 u0 = up[j + 0], u1 = up[j + 1], u2 = up[j + 2], u3 = up[j + 3];
        int s0 = __builtin_amdgcn_readfirstlane(sp[j + 0]);
        int s1 = __builtin_amdgcn_readfirstlane(sp[j + 1]);
        int s2 = __builtin_amdgcn_readfirstlane(sp[j + 2]);
        int s3 = __builtin_amdgcn_readfirstlane(sp[j + 3]);
        proc(wq0, u0, s0);
        proc(wq1, u1, s1);
        proc(wq2, u2, s2);
        proc(wq3, u3, s3);
    }
    for (; j < end; j++) {
        unsigned wq = Wq[(size_t)j * 256 + tid];
        float4 u = up[j];
        int s = __builtin_amdgcn_readfirstlane(sp[j]);
        proc(wq, u, s);
    }

    agg_s[(size_t)r * 256 + tid] = accs;
    float* o = agg_v + ((size_t)r * 256 + tid) * 3;
    o[0] = av0; o[1] = av1; o[2] = av2;
}

// ---------------- tier B: VALU writer (grouped layout) + its gather ----------------
__global__ __launch_bounds__(256) void k_mlp_wp(
    const float* __restrict__ rb, const int* __restrict__ elist,
    const float* __restrict__ w0T, const float* __restrict__ w1T,
    const float* __restrict__ w2T, const float* __restrict__ w3T,
    unsigned short* __restrict__ Wp, int E_) {
    int p = blockIdx.x * blockDim.x + threadIdx.x;
    if (p >= E_) return;
    int e = elist[p];
    const int c0 = blockIdx.y * 128;

    float4 a[16];
    mlp_body(rb, e, w0T, w1T, w2T, a);

    const size_t E4 = (size_t)E_ * 4;
    for (int c = c0; c < c0 + 128; c += 8) {
        float s[8];
        #pragma unroll
        for (int q = 0; q < 8; q++) {
            const float* rp = w3T + (size_t)(c + q) * 64;
            float t0 = 0.f, t1 = 0.f, t2 = 0.f, t3 = 0.f;
            #pragma unroll
            for (int k = 0; k < 16; k++) {
                float4 h = a[k];
                t0 += h.x * rp[4 * k + 0];
                t1 += h.y * rp[4 * k + 1];
                t2 += h.z * rp[4 * k + 2];
                t3 += h.w * rp[4 * k + 3];
            }
            s[q] = (t0 + t1) + (t2 + t3);
        }
        ushort4 pk0 = make_ushort4(f2bf(s[0]), f2bf(s[1]), f2bf(s[2]), f2bf(s[3]));
        ushort4 pk1 = make_ushort4(f2bf(s[4]), f2bf(s[5]), f2bf(s[6]), f2bf(s[7]));
        *(ushort4*)(Wp + (size_t)(c >> 2) * E4 + (size_t)p * 4) = pk0;
        *(ushort4*)(Wp + (size_t)((c >> 2) + 1) * E4 + (size_t)p * 4) = pk1;
    }
}

__global__ __launch_bounds__(512, 2) void k_gather_wg(
    const int* __restrict__ off, const int* __restrict__ elist,
    const int* __restrict__ snd, const float* __restrict__ evec,
    const unsigned short* __restrict__ Wp, int E_,
    const float* __restrict__ y0, const float* __restrict__ y1, int NP,
    float* __restrict__ agg_s, float* __restrict__ agg_v) {
    const int r = blockIdx.x;
    const int tid = threadIdx.x;
    const int part = tid >> 7;
    const int c = tid & 127;

    const int start = off[r];
    const int end = off[r + 1];

    const unsigned short* __restrict__ wstream =
        Wp + (size_t)(tid >> 2) * ((size_t)E_ * 4) + (tid & 3);

    float acc0 = 0.f, acc1 = 0.f, acc2 = 0.f;
    const float SQ3 = 1.7320508075688772f;

    #pragma unroll 2
    for (int j = start; j < end; j++) {
        int e = elist[j];
        e = __builtin_amdgcn_readfirstlane(e);
        int s = snd[e];
        s = __builtin_amdgcn_readfirstlane(s);

        float e0 = evec[(size_t)e * 3 + 0];
        float e1 = evec[(size_t)e * 3 + 1];
        float e2 = evec[(size_t)e * 3 + 2];
        float rn = sqrtf(e0 * e0 + e1 * e1 + e2 * e2);
        float inv = 1.0f / fmaxf(rn, 1e-12f);
        float ux = e0 * inv, uy = e1 * inv, uz = e2 * inv;

        float w = bf2f(wstream[(size_t)j * 4]);

        if (part == 0) {
            acc0 += y0[(size_t)s * CC + c] * w;
        } else if (part == 1) {
            float f = y1[0 * NP + s * CC + c] * ux
                    + y1[1 * NP + s * CC + c] * uy
                    + y1[2 * NP + s * CC + c] * uz;
            acc0 += f * w;
        } else if (part == 2) {
            float bb = y0[(size_t)s * CC + c] * w * SQ3;
            acc0 += bb * ux; acc1 += bb * uy; acc2 += bb * uz;
        } else {
            acc0 += y1[0 * NP + s * CC + c] * w;
            acc1 += y1[1 * NP + s * CC + c] * w;
            acc2 += y1[2 * NP + s * CC + c] * w;
        }
    }

    if (part == 0) {
        agg_s[(size_t)r * 256 + c] = acc0;
    } else if (part == 1) {
        agg_s[(size_t)r * 256 + 128 + c] = acc0;
    } else if (part == 2) {
        float* o = agg_v + ((size_t)r * 256 + c) * 3;
        o[0] = acc0; o[1] = acc1; o[2] = acc2;
    } else {
        float* o = agg_v + ((size_t)r * 256 + 128 + c) * 3;
        o[0] = acc0; o[1] = acc1; o[2] = acc2;
    }
}

// ---------------- tier C: f32 h2 fallback ----------------
__global__ void k_mlp(const float* __restrict__ rb,
                      const float* __restrict__ w0T, const float* __restrict__ w1T,
                      const float* __restrict__ w2T,
                      float* __restrict__ h2, int E_) {
    int e = blockIdx.x * blockDim.x + threadIdx.x;
    if (e >= E_) return;
    float4 a[16];
    mlp_body(rb, e, w0T, w1T, w2T, a);
    float4* out = (float4*)(h2 + (size_t)e * HH);
    #pragma unroll
    for (int q = 0; q < 16; q++) out[q] = a[q];
}

__global__ __launch_bounds__(512, 1) void k_gather_h2(
    const int* __restrict__ off, const int* __restrict__ elist,
    const int* __restrict__ snd, const float* __restrict__ evec,
    const float* __restrict__ h2, const float* __restrict__ w3T,
    const float* __restrict__ y0, const float* __restrict__ y1, int NP,
    float* __restrict__ agg_s, float* __restrict__ agg_v) {
    const int r = blockIdx.x;
    const int tid = threadIdx.x;
    const int part = tid >> 7;
    const int c = tid & 127;

    const float4* wp = (const float4*)(w3T + (size_t)tid * 64);
    const int start = off[r];
    const int end = off[r + 1];

    float acc0 = 0.f, acc1 = 0.f, acc2 = 0.f;
    const float SQ3 = 1.7320508075688772f;

    for (int j = start; j < end; j++) {
        int e = elist[j];
        e = __builtin_amdgcn_readfirstlane(e);
        int s = snd[e];
        s = __builtin_amdgcn_readfirstlane(s);

        float e0 = evec[(size_t)e * 3 + 0];
        float e1 = evec[(size_t)e * 3 + 1];
        float e2 = evec[(size_t)e * 3 + 2];
        float rn = sqrtf(e0 * e0 + e1 * e1 + e2 * e2);
        float inv = 1.0f / fmaxf(rn, 1e-12f);
        float ux = e0 * inv, uy = e1 * inv, uz = e2 * inv;

        const float4* __restrict__ hp = (const float4*)(h2 + ((size_t)e << 6));
        float ws0 = 0.f, ws1 = 0.f, ws2 = 0.f, ws3 = 0.f;
        #pragma unroll
        for (int k = 0; k < 16; k++) {
            float4 h = hp[k];
            float4 wv = wp[k];
            ws0 += h.x * wv.x; ws1 += h.y * wv.y; ws2 += h.z * wv.z; ws3 += h.w * wv.w;
        }
        float w = (ws0 + ws1) + (ws2 + ws3);

        if (part == 0) {
            acc0 += y0[(size_t)s * CC + c] * w;
        } else if (part == 1) {
            float f = y1[0 * NP + s * CC + c] * ux
                    + y1[1 * NP + s * CC + c] * uy
                    + y1[2 * NP + s * CC + c] * uz;
            acc0 += f * w;
        } else if (part == 2) {
            float bb = y0[(size_t)s * CC + c] * w * SQ3;
            acc0 += bb * ux; acc1 += bb * uy; acc2 += bb * uz;
        } else {
            acc0 += y1[0 * NP + s * CC + c] * w;
            acc1 += y1[1 * NP + s * CC + c] * w;
            acc2 += y1[2 * NP + s * CC + c] * w;
        }
    }

    if (part == 0) {
        agg_s[(size_t)r * 256 + c] = acc0;
    } else if (part == 1) {
        agg_s[(size_t)r * 256 + 128 + c] = acc0;
    } else if (part == 2) {
        float* o = agg_v + ((size_t)r * 256 + c) * 3;
        o[0] = acc0; o[1] = acc1; o[2] = acc2;
    } else {
        float* o = agg_v + ((size_t)r * 256 + 128 + c) * 3;
        o[0] = acc0; o[1] = acc1; o[2] = acc2;
    }
}

// ---------------- node output (species-sorted, coalesced W) ----------------
__global__ __launch_bounds__(256) void k_node_out(
    const float* __restrict__ agg_s, const float* __restrict__ agg_v,
    const float* __restrict__ xs, const float* __restrict__ xv,
    const float* __restrict__ W20, const float* __restrict__ W21,
    const float* __restrict__ Wsk0, const float* __restrict__ Wsk1,
    const int* __restrict__ nlist, const int* __restrict__ species,
    float* __restrict__ out, int N) {
    const int tid = threadIdx.x;
    const int b0 = blockIdx.x * 4;
    const int nid0 = nlist[min(b0 + 0, N - 1)];
    const int nid1 = nlist[min(b0 + 1, N - 1)];
    const int nid2 = nlist[min(b0 + 2, N - 1)];
    const int nid3 = nlist[min(b0 + 3, N - 1)];

    __shared__ float as_l[4 * 256];
    __shared__ float av_l[4 * 768];
    __shared__ float xs_l[4 * 128];
    __shared__ float xv_l[4 * 384];
    __shared__ float s_l[4 * 256];

    {
        as_l[0 * 256 + tid] = agg_s[(size_t)nid0 * 256 + tid];
        as_l[1 * 256 + tid] = agg_s[(size_t)nid1 * 256 + tid];
        as_l[2 * 256 + tid] = agg_s[(size_t)nid2 * 256 + tid];
        as_l[3 * 256 + tid] = agg_s[(size_t)nid3 * 256 + tid];
        for (int i = tid; i < 768; i += 256) {
            av_l[0 * 768 + i] = agg_v[(size_t)nid0 * 768 + i];
            av_l[1 * 768 + i] = agg_v[(size_t)nid1 * 768 + i];
            av_l[2 * 768 + i] = agg_v[(size_t)nid2 * 768 + i];
            av_l[3 * 768 + i] = agg_v[(size_t)nid3 * 768 + i];
        }
        if (tid < 128) {
            xs_l[0 * 128 + tid] = xs[(size_t)nid0 * 128 + tid];
            xs_l[1 * 128 + tid] = xs[(size_t)nid1 * 128 + tid];
            xs_l[2 * 128 + tid] = xs[(size_t)nid2 * 128 + tid];
            xs_l[3 * 128 + tid] = xs[(size_t)nid3 * 128 + tid];
        }
        for (int i = tid; i < 384; i += 256) {
            xv_l[0 * 384 + i] = xv[(size_t)nid0 * 384 + i];
            xv_l[1 * 384 + i] = xv[(size_t)nid1 * 384 + i];
            xv_l[2 * 384 + i] = xv[(size_t)nid2 * 384 + i];
            xv_l[3 * 384 + i] = xv[(size_t)nid3 * 384 + i];
        }
    }
    const int sp0 = species[nid0], sp1 = species[nid1];
    const int sp2 = species[nid2], sp3 = species[nid3];
    const bool uni = (sp0 == sp1) && (sp1 == sp2) && (sp2 == sp3);
    __syncthreads();

    const float k_mat = 0.17677669529663687f * 0.0625f; // inv_nb * inv_2c
    const float inv_c = 0.08838834764831845f;

    {
        const int d = tid;
        float am[4] = {0.f, 0.f, 0.f, 0.f};
        for (int cc = 0; cc < 256; cc++) {
            float w = W20[cc * 256 + d];
            #pragma unroll
            for (int n = 0; n < 4; n++) am[n] += as_l[n * 256 + cc] * w;
        }
        float ak[4] = {0.f, 0.f, 0.f, 0.f};
        if (uni) {
            for (int cc = 0; cc < 128; cc++) {
                float w = Wsk0[((size_t)sp0 * 128 + cc) * 256 + d];
                #pragma unroll
                for (int n = 0; n < 4; n++) ak[n] += xs_l[n * 128 + cc] * w;
            }
        } else {
            for (int cc = 0; cc < 128; cc++) {
                float w0v = Wsk0[((size_t)sp0 * 128 + cc) * 256 + d];
                float w1v = Wsk0[((size_t)sp1 * 128 + cc) * 256 + d];
                float w2v = Wsk0[((size_t)sp2 * 128 + cc) * 256 + d];
                float w3v = Wsk0[((size_t)sp3 * 128 + cc) * 256 + d];
                ak[0] += xs_l[0 * 128 + cc] * w0v;
                ak[1] += xs_l[1 * 128 + cc] * w1v;
                ak[2] += xs_l[2 * 128 + cc] * w2v;
                ak[3] += xs_l[3 * 128 + cc] * w3v;
            }
        }
        #pragma unroll
        for (int n = 0; n < 4; n++) s_l[n * 256 + d] = am[n] * k_mat + ak[n] * inv_c;
    }
    __syncthreads();

    if (tid < 128) {
        out[(size_t)nid0 * 512 + tid] = silu_f(s_l[0 * 256 + tid]);
        out[(size_t)nid1 * 512 + tid] = silu_f(s_l[1 * 256 + tid]);
        out[(size_t)nid2 * 512 + tid] = silu_f(s_l[2 * 256 + tid]);
        out[(size_t)nid3 * 512 + tid] = silu_f(s_l[3 * 256 + tid]);
    }

    {
        const int d = tid & 127;
        const int half = tid >> 7;
        const int nA = half ? nid2 : nid0;
        const int nB = half ? nid3 : nid1;
        const int sA = half ? sp2 : sp0;
        const int sB = half ? sp3 : sp1;
        const int la = half ? 2 : 0;
        const int lb = half ? 3 : 1;

        float am[2][3] = {};
        for (int cc = 0; cc < 256; cc++) {
            float w = W21[cc * 128 + d];
            #pragma unroll
            for (int i = 0; i < 3; i++) {
                am[0][i] += av_l[la * 768 + cc * 3 + i] * w;
                am[1][i] += av_l[lb * 768 + cc * 3 + i] * w;
            }
        }
        float ak[2][3] = {};
        if (uni) {
            for (int cc = 0; cc < 128; cc++) {
                float w = Wsk1[((size_t)sp0 * 128 + cc) * 128 + d];
                #pragma unroll
                for (int i = 0; i < 3; i++) {
                    ak[0][i] += xv_l[la * 384 + cc * 3 + i] * w;
                    ak[1][i] += xv_l[lb * 384 + cc * 3 + i] * w;
                }
            }
        } else {
            for (int cc = 0; cc < 128; cc++) {
                float wA = Wsk1[((size_t)sA * 128 + cc) * 128 + d];
                float wB = Wsk1[((size_t)sB * 128 + cc) * 128 + d];
                #pragma unroll
                for (int i = 0; i < 3; i++) {
                    ak[0][i] += xv_l[la * 384 + cc * 3 + i] * wA;
                    ak[1][i] += xv_l[lb * 384 + cc * 3 + i] * wB;
                }
            }
        }
        float gA = silu_f(s_l[la * 256 + 128 + d]);
        float gB = silu_f(s_l[lb * 256 + 128 + d]);
        float* oA = out + (size_t)nA * 512 + 128 + d * 3;
        float* oB = out + (size_t)nB * 512 + 128 + d * 3;
        #pragma unroll
        for (int i = 0; i < 3; i++) {
            oA[i] = (am[0][i] * k_mat + ak[0][i] * inv_c) * gA;
            oB[i] = (am[1][i] * k_mat + ak[1][i] * inv_c) * gB;
        }
    }
}

extern "C" void kernel_launch(void* const* d_in, const int* in_sizes, int n_in,
                              void* d_out, int out_size, void* d_ws, size_t ws_size,
                              hipStream_t stream) {
    const float* xs   = (const float*)d_in[0];
    const float* xv   = (const float*)d_in[1];
    const float* evec = (const float*)d_in[2];
    const float* rb   = (const float*)d_in[3];
    const float* W10  = (const float*)d_in[4];
    const float* W11  = (const float*)d_in[5];
    const float* w0   = (const float*)d_in[6];
    const float* w1   = (const float*)d_in[7];
    const float* w2   = (const float*)d_in[8];
    const float* w3   = (const float*)d_in[9];
    const float* W20  = (const float*)d_in[10];
    const float* W21  = (const float*)d_in[11];
    const float* Wsk0 = (const float*)d_in[12];
    const float* Wsk1 = (const float*)d_in[13];
    const int* species = (const int*)d_in[14];
    const int* snd = (const int*)d_in[15];
    const int* rcv = (const int*)d_in[16];

    const int N = in_sizes[0] / CC;   // 4000
    const int E = in_sizes[2] / 3;    // 128000
    const int NP = N * CC;
    int NS = in_sizes[12] / (CC * 2 * CC);   // 5
    if (NS < 1) NS = 1;
    if (NS > 63) NS = 63;

    float* ws   = (float*)d_ws;
    float* y0   = ws;
    float* y1   = y0 + (size_t)N * CC;
    float* aggs = y1 + (size_t)N * CC * 3;
    float* aggv = aggs + (size_t)N * 2 * CC;
    float* w0T  = aggv + (size_t)N * 2 * CC * 3;
    float* w1T  = w0T + 64 * 8;
    float* w2T  = w1T + 64 * 64;
    float* w3T  = w2T + 64 * 64;
    unsigned short* w3bs = (unsigned short*)(w3T + 512 * 64);
    unsigned short* w0b  = w3bs + 32768;
    unsigned short* w1b  = w0b + 2048;
    unsigned short* w2b  = w1b + 4096;
    int*   deg  = (int*)(w2b + 4096);
    int*   cur  = deg + 4096;
    int*   scnt = cur + 4096;                // 64
    int*   soff = scnt + 64;                 // 72
    int*   scur = soff + 72;                 // 64
    int*   off  = scur + 64;                 // 4160
    int*   elist = off + 4160;
    float4* up  = (float4*)(elist + E);
    int*   sp   = (int*)(up + E);
    int*   nlist = sp + E;                   // N
    void*  big  = (void*)(nlist + N);

    size_t base_bytes = (size_t)((char*)big - (char*)d_ws);
    size_t wq_bytes   = (size_t)E * 256 * sizeof(unsigned int);
    size_t need_A = base_bytes + wq_bytes;
    size_t need_B = base_bytes + (size_t)E * WDIM * sizeof(unsigned short);

    unsigned int*   Wq  = (unsigned int*)big;
    unsigned short* Wp  = (unsigned short*)big;

    hipMemsetAsync(deg, 0, (4096 + 4096 + 64 + 72 + 64) * sizeof(int), stream);
    hipLaunchKernelGGL(k_prep_hist, dim3((E + 255) / 256), dim3(256), 0, stream,
                       w0, w1, w2, w3, w0T, w1T, w2T, w3T, w3bs, w0b, w1b, w2b,
                       rcv, deg, E, species, scnt, N);
    hipLaunchKernelGGL(k_scan, dim3(1), dim3(1024), 0, stream,
                       deg, off, N, scnt, soff, NS);
    hipLaunchKernelGGL(k_scatter, dim3((E + 255) / 256), dim3(256), 0, stream,
                       rcv, off, cur, elist, E, species, soff, scur, nlist, N);

    if (ws_size >= need_A && (E % 64) == 0 && (N % 2) == 0) {
        const int nblk_mlp = E / 64;
        hipLaunchKernelGGL(k_mlpw3, dim3(nblk_mlp + N / 2), dim3(256), 0, stream,
                           rb, elist, snd, evec, w0b, w1b, w2b, w3bs, Wq, up, sp,
                           E, nblk_mlp, xs, xv, W10, W11, y0, y1, NP);
        hipLaunchKernelGGL(k_gather_em, dim3(N), dim3(256), 0, stream,
                           off, up, sp, Wq, y0, y1, NP, aggs, aggv);
    } else if (ws_size >= need_B) {
        hipLaunchKernelGGL(k_node_lin, dim3((N + 1) / 2), dim3(256), 0, stream,
                           xs, xv, W10, W11, y0, y1, N);
        hipLaunchKernelGGL(k_mlp_wp, dim3((E + 255) / 256, 4), dim3(256), 0, stream,
                           rb, elist, w0T, w1T, w2T, w3T, Wp, E);
        hipLaunchKernelGGL(k_gather_wg, dim3(N), dim3(512), 0, stream,
                           off, elist, snd, evec, Wp, E, y0, y1, NP, aggs, aggv);
    } else {
        hipLaunchKernelGGL(k_node_lin, dim3((N + 1) / 2), dim3(256), 0, stream,
                           xs, xv, W10, W11, y0, y1, N);
        hipLaunchKernelGGL(k_mlp, dim3((E + 255) / 256), dim3(256), 0, stream,
                           rb, w0T, w1T, w2T, (float*)big, E);
        hipLaunchKernelGGL(k_gather_h2, dim3(N), dim3(512), 0, stream,
                           off, elist, snd, evec, (const float*)big, w3T,
                           y0, y1, NP, aggs, aggv);
    }

    hipLaunchKernelGGL(k_node_out, dim3((N + 3) / 4), dim3(256), 0, stream,
                       aggs, aggv, xs, xv, W20, W21, Wsk0, Wsk1, nlist, species,
                       (float*)d_out, N);
}

// Round 21
// 244.132 us; speedup vs baseline: 1.4531x; 1.0032x over previous
//
#include <hip/hip_runtime.h>
#include <math.h>

#define CC 128
#define HH 64
#define RBD 8
#define WDIM 512

typedef __attribute__((ext_vector_type(8))) short short8v;
typedef __attribute__((ext_vector_type(4))) float f32x4;

__device__ __forceinline__ float silu_f(float x) {
    return x / (1.0f + __expf(-x));
}

__device__ __forceinline__ unsigned short f2bf(float x) {
    unsigned int b = __float_as_uint(x);
    unsigned int r = (b + 0x7FFFu + ((b >> 16) & 1u)) >> 16;
    return (unsigned short)r;
}

__device__ __forceinline__ float bf2f(unsigned short u) {
    return __uint_as_float(((unsigned int)u) << 16);
}

// pack bf16(lo) | bf16(hi)<<16 in ONE instruction (RNE, same as f2bf)
__device__ __forceinline__ unsigned cvt_pk_bf16(float lo, float hi) {
    unsigned r;
    asm("v_cvt_pk_bf16_f32 %0, %1, %2" : "=v"(r) : "v"(lo), "v"(hi));
    return r;
}

// ---------------- merged prep + histograms ----------------
__global__ void k_prep_hist(const float* __restrict__ w0, const float* __restrict__ w1,
                            const float* __restrict__ w2, const float* __restrict__ w3,
                            float* __restrict__ w0T, float* __restrict__ w1T,
                            float* __restrict__ w2T, float* __restrict__ w3T,
                            unsigned short* __restrict__ w3bs,
                            unsigned short* __restrict__ w0b,
                            unsigned short* __restrict__ w1b,
                            unsigned short* __restrict__ w2b,
                            const int* __restrict__ rcv, int* __restrict__ deg, int E_,
                            const int* __restrict__ species, int* __restrict__ scnt, int N) {
    int i = blockIdx.x * blockDim.x + threadIdx.x;
    if (i < E_) atomicAdd(&deg[rcv[i]], 1);
    if (i < N) atomicAdd(&scnt[species[i]], 1);
    if (i < 64 * 8) { int m = i / 8, k = i % 8; w0T[i] = w0[k * 64 + m]; }
    if (i < 64 * 64) { int m = i / 64, k = i % 64; w1T[i] = w1[k * 64 + m]; w2T[i] = w2[k * 64 + m]; }
    if (i < 512 * 64) { int j = i / 64, k = i % 64; w3T[i] = w3[k * 512 + j]; }
    if (i < 32768) {
        int t = i >> 10, ch = (i >> 9) & 1, lane = (i >> 3) & 63, j = i & 7;
        int k = ch * 32 + 8 * (lane >> 4) + j;
        int n = t * 16 + (lane & 15);
        w3bs[i] = f2bf(w3[k * 512 + n]);
    }
    if (i < 2048) {
        int t = i >> 9, lane = (i >> 3) & 63, j = i & 7;
        int k = 8 * (lane >> 4) + j;
        int col = t * 16 + (lane & 15);
        w0b[i] = (k < RBD) ? f2bf(w0[k * 64 + col]) : (unsigned short)0;
    }
    if (i < 4096) {
        int f = i >> 9, lane = (i >> 3) & 63, j = i & 7;
        int ks = f >> 2, t = f & 3;
        int k = ks * 32 + 8 * (lane >> 4) + j;
        int col = t * 16 + (lane & 15);
        w1b[i] = f2bf(w1[k * 64 + col]);
        w2b[i] = f2bf(w2[k * 64 + col]);
    }
}

__global__ __launch_bounds__(1024) void k_scan(const int* __restrict__ deg,
                                               int* __restrict__ off, int N,
                                               const int* __restrict__ scnt,
                                               int* __restrict__ soff, int NS) {
    __shared__ int s[1024];
    int t = threadIdx.x;
    int b = t * 4;
    int a0 = (b + 0 < N) ? deg[b + 0] : 0;
    int a1 = (b + 1 < N) ? deg[b + 1] : 0;
    int a2 = (b + 2 < N) ? deg[b + 2] : 0;
    int a3 = (b + 3 < N) ? deg[b + 3] : 0;
    int part = a0 + a1 + a2 + a3;
    s[t] = part;
    __syncthreads();
    for (int d = 1; d < 1024; d <<= 1) {
        int v = (t >= d) ? s[t - d] : 0;
        __syncthreads();
        s[t] += v;
        __syncthreads();
    }
    int excl = s[t] - part;
    if (b + 0 <= N) off[b + 0] = excl;
    if (b + 1 <= N) off[b + 1] = excl + a0;
    if (b + 2 <= N) off[b + 2] = excl + a0 + a1;
    if (b + 3 <= N) off[b + 3] = excl + a0 + a1 + a2;
    if (t == 0) {
        int acc = 0;
        for (int q = 0; q < NS; q++) { soff[q] = acc; acc += scnt[q]; }
        soff[NS] = acc;
    }
}

__global__ void k_scatter(const int* __restrict__ rcv, const int* __restrict__ off,
                          int* __restrict__ cur, int* __restrict__ elist, int E_,
                          const int* __restrict__ species, const int* __restrict__ soff,
                          int* __restrict__ scur, int* __restrict__ nlist, int N) {
    int e = blockIdx.x * blockDim.x + threadIdx.x;
    if (e < E_) {
        int r = rcv[e];
        int p = atomicAdd(&cur[r], 1);
        elist[off[r] + p] = e;
    }
    if (e < N) {
        int s = species[e];
        int p = atomicAdd(&scur[s], 1);
        nlist[soff[s] + p] = e;
    }
}

// ---------------- standalone node_lin (tiers B/C): LDS-staged ----------------
__global__ __launch_bounds__(256) void k_node_lin(
    const float* __restrict__ xs, const float* __restrict__ xv,
    const float* __restrict__ W10, const float* __restrict__ W11,
    float* __restrict__ y0, float* __restrict__ y1, int N) {
    const int tid = threadIdx.x;
    const int n0 = blockIdx.x * 2;
    const int NP = N * CC;
    const int d = tid & 127;
    const int nn = tid >> 7;
    const float inv_c = 0.08838834764831845f;

    __shared__ float xsl[2][128];
    __shared__ float xvl[2][384];
    xsl[tid >> 7][tid & 127] = xs[(size_t)n0 * 128 + tid];
    for (int i = tid; i < 768; i += 256) xvl[i / 384][i % 384] = xv[(size_t)n0 * 384 + i];
    __syncthreads();

    float a0 = 0.f, av0 = 0.f, av1 = 0.f, av2 = 0.f;
    #pragma unroll 4
    for (int c = 0; c < CC; c++) {
        float w10 = W10[c * CC + d];
        float w11 = W11[c * CC + d];
        float xsv = xsl[nn][c];
        a0 += xsv * w10;
        av0 += xvl[nn][c * 3 + 0] * w11;
        av1 += xvl[nn][c * 3 + 1] * w11;
        av2 += xvl[nn][c * 3 + 2] * w11;
    }
    y0[(size_t)(n0 + nn) * CC + d] = a0 * inv_c;
    y1[0 * NP + (size_t)(n0 + nn) * CC + d] = av0 * inv_c;
    y1[1 * NP + (size_t)(n0 + nn) * CC + d] = av1 * inv_c;
    y1[2 * NP + (size_t)(n0 + nn) * CC + d] = av2 * inv_c;
}

// ---------------- shared VALU MLP body (tiers B/C) ----------------
__device__ __forceinline__ void layer64(const float4* a, float4* b,
                                        const float* __restrict__ W) {
    #pragma unroll
    for (int m = 0; m < 16; m++) {
        float s0 = 0.f, s1 = 0.f, s2 = 0.f, s3 = 0.f;
        const float* w0p = W + (4 * m + 0) * 64;
        const float* w1p = W + (4 * m + 1) * 64;
        const float* w2p = W + (4 * m + 2) * 64;
        const float* w3p = W + (4 * m + 3) * 64;
        #pragma unroll
        for (int k = 0; k < 16; k++) {
            float4 av = a[k];
            s0 += av.x * w0p[4 * k + 0] + av.y * w0p[4 * k + 1] + av.z * w0p[4 * k + 2] + av.w * w0p[4 * k + 3];
            s1 += av.x * w1p[4 * k + 0] + av.y * w1p[4 * k + 1] + av.z * w1p[4 * k + 2] + av.w * w1p[4 * k + 3];
            s2 += av.x * w2p[4 * k + 0] + av.y * w2p[4 * k + 1] + av.z * w2p[4 * k + 2] + av.w * w2p[4 * k + 3];
            s3 += av.x * w3p[4 * k + 0] + av.y * w3p[4 * k + 1] + av.z * w3p[4 * k + 2] + av.w * w3p[4 * k + 3];
        }
        b[m] = make_float4(silu_f(s0), silu_f(s1), silu_f(s2), silu_f(s3));
    }
}

__device__ __forceinline__ void mlp_body(
    const float* __restrict__ rb, int e,
    const float* __restrict__ w0T, const float* __restrict__ w1T,
    const float* __restrict__ w2T, float4* a) {
    float rbv[RBD];
    #pragma unroll
    for (int k = 0; k < RBD; k++) rbv[k] = rb[(size_t)e * RBD + k];
    float4 b[16];
    #pragma unroll
    for (int m = 0; m < 16; m++) {
        float s0 = 0.f, s1 = 0.f, s2 = 0.f, s3 = 0.f;
        #pragma unroll
        for (int k = 0; k < RBD; k++) {
            float rv = rbv[k];
            s0 += rv * w0T[(4 * m + 0) * RBD + k];
            s1 += rv * w0T[(4 * m + 1) * RBD + k];
            s2 += rv * w0T[(4 * m + 2) * RBD + k];
            s3 += rv * w0T[(4 * m + 3) * RBD + k];
        }
        a[m] = make_float4(silu_f(s0), silu_f(s1), silu_f(s2), silu_f(s3));
    }
    layer64(a, b, w1T);
    layer64(b, a, w2T);   // a holds h2
}

// ---------------- tier A: fused {MFMA MLP + w3 GEMM + emeta} | node_lin ------
// w3 GEMM runs as FOUR sequential passes of 8 accumulators (pass p covers
// t in {4p..4p+3} U {16+4p..16+4p+3}: complete pack-pairs). Live acc regs
// 128 -> 32 on the unified VGPR/AGPR file. Store epilogue uses
// v_cvt_pk_bf16_f32 (1 inst/pack vs ~10 for hand-rolled f2bf+or).
__global__ __launch_bounds__(256) void k_mlpw3(
    const float* __restrict__ rb, const int* __restrict__ elist,
    const int* __restrict__ snd, const float* __restrict__ evec,
    const unsigned short* __restrict__ w0b, const unsigned short* __restrict__ w1b,
    const unsigned short* __restrict__ w2b, const unsigned short* __restrict__ w3bs,
    unsigned int* __restrict__ Wq, float4* __restrict__ up, int* __restrict__ sp,
    int E_, int nblk_mlp,
    const float* __restrict__ xs, const float* __restrict__ xv,
    const float* __restrict__ W10, const float* __restrict__ W11,
    float* __restrict__ y0, float* __restrict__ y1, int NP) {
    __shared__ unsigned short hbuf[4][16][72];
    __shared__ float xsl[2][128];
    __shared__ float xvl[2][384];

    if (blockIdx.x >= nblk_mlp) {
        // ---------- node_lin tail ----------
        const int tid = threadIdx.x;
        const int n0 = (blockIdx.x - nblk_mlp) * 2;
        const int d = tid & 127;
        const int nn = tid >> 7;
        const float inv_c = 0.08838834764831845f;

        xsl[tid >> 7][tid & 127] = xs[(size_t)n0 * 128 + tid];
        for (int i = tid; i < 768; i += 256) xvl[i / 384][i % 384] = xv[(size_t)n0 * 384 + i];
        __syncthreads();

        float a0 = 0.f, av0 = 0.f, av1 = 0.f, av2 = 0.f;
        #pragma unroll 4
        for (int c = 0; c < CC; c++) {
            float w10 = W10[c * CC + d];
            float w11 = W11[c * CC + d];
            float xsv = xsl[nn][c];
            a0 += xsv * w10;
            av0 += xvl[nn][c * 3 + 0] * w11;
            av1 += xvl[nn][c * 3 + 1] * w11;
            av2 += xvl[nn][c * 3 + 2] * w11;
        }
        y0[(size_t)(n0 + nn) * CC + d] = a0 * inv_c;
        y1[0 * NP + (size_t)(n0 + nn) * CC + d] = av0 * inv_c;
        y1[1 * NP + (size_t)(n0 + nn) * CC + d] = av1 * inv_c;
        y1[2 * NP + (size_t)(n0 + nn) * CC + d] = av2 * inv_c;
        return;
    }

    // ---------- MLP + w3 GEMM ----------
    const int lane = threadIdx.x & 63;
    const int wv = threadIdx.x >> 6;
    const int rbk = blockIdx.x * 4 + wv;
    const int col = lane & 15;
    const int grp = lane >> 4;

    if (threadIdx.x < 64) {
        int p = blockIdx.x * 64 + threadIdx.x;
        if (p < E_) {
            int e = elist[p];
            float e0 = evec[(size_t)e * 3 + 0];
            float e1 = evec[(size_t)e * 3 + 1];
            float e2 = evec[(size_t)e * 3 + 2];
            float rn = sqrtf(e0 * e0 + e1 * e1 + e2 * e2);
            float inv = 1.0f / fmaxf(rn, 1e-12f);
            up[p] = make_float4(e0 * inv, e1 * inv, e2 * inv, 0.f);
            sp[p] = snd[e];
        }
    }

    short8v a0 = (short8v){0, 0, 0, 0, 0, 0, 0, 0};
    if (grp == 0) {
        int e = elist[rbk * 16 + col];
        const float* rp = rb + (size_t)e * RBD;
        #pragma unroll
        for (int j = 0; j < RBD; j++) a0[j] = (short)f2bf(rp[j]);
    }
    f32x4 acc[4];
    {
        const unsigned short* bp = w0b + (size_t)lane * 8;
        #pragma unroll
        for (int t = 0; t < 4; t++) {
            short8v b = *(const short8v*)(bp + (size_t)t * 512);
            acc[t] = __builtin_amdgcn_mfma_f32_16x16x32_bf16(
                a0, b, (f32x4){0.f, 0.f, 0.f, 0.f}, 0, 0, 0);
        }
    }
    #pragma unroll
    for (int t = 0; t < 4; t++)
        #pragma unroll
        for (int r = 0; r < 4; r++)
            hbuf[wv][grp * 4 + r][t * 16 + col] = f2bf(silu_f(acc[t][r]));

    {
        short8v aA = *(const short8v*)&hbuf[wv][col][8 * grp];
        short8v aB = *(const short8v*)&hbuf[wv][col][32 + 8 * grp];
        const unsigned short* bp = w1b + (size_t)lane * 8;
        #pragma unroll
        for (int t = 0; t < 4; t++) {
            short8v b0 = *(const short8v*)(bp + (size_t)(0 + t) * 512);
            short8v b1 = *(const short8v*)(bp + (size_t)(4 + t) * 512);
            f32x4 c = __builtin_amdgcn_mfma_f32_16x16x32_bf16(
                aA, b0, (f32x4){0.f, 0.f, 0.f, 0.f}, 0, 0, 0);
            acc[t] = __builtin_amdgcn_mfma_f32_16x16x32_bf16(aB, b1, c, 0, 0, 0);
        }
    }
    #pragma unroll
    for (int t = 0; t < 4; t++)
        #pragma unroll
        for (int r = 0; r < 4; r++)
            hbuf[wv][grp * 4 + r][t * 16 + col] = f2bf(silu_f(acc[t][r]));

    {
        short8v aA = *(const short8v*)&hbuf[wv][col][8 * grp];
        short8v aB = *(const short8v*)&hbuf[wv][col][32 + 8 * grp];
        const unsigned short* bp = w2b + (size_t)lane * 8;
        #pragma unroll
        for (int t = 0; t < 4; t++) {
            short8v b0 = *(const short8v*)(bp + (size_t)(0 + t) * 512);
            short8v b1 = *(const short8v*)(bp + (size_t)(4 + t) * 512);
            f32x4 c = __builtin_amdgcn_mfma_f32_16x16x32_bf16(
                aA, b0, (f32x4){0.f, 0.f, 0.f, 0.f}, 0, 0, 0);
            acc[t] = __builtin_amdgcn_mfma_f32_16x16x32_bf16(aB, b1, c, 0, 0, 0);
        }
    }
    #pragma unroll
    for (int t = 0; t < 4; t++)
        #pragma unroll
        for (int r = 0; r < 4; r++)
            hbuf[wv][grp * 4 + r][t * 16 + col] = f2bf(silu_f(acc[t][r]));

    short8v A0 = *(const short8v*)&hbuf[wv][col][8 * grp];
    short8v A1 = *(const short8v*)&hbuf[wv][col][32 + 8 * grp];

    const unsigned short* bbase = w3bs + (size_t)lane * 8;
    const int rowq = grp * 4;
    const int jbase = rbk * 16 + rowq;

    #pragma unroll 1
    for (int pass = 0; pass < 4; pass++) {
        f32x4 wacc[8];
        #pragma unroll
        for (int q = 0; q < 8; q++) wacc[q] = (f32x4){0.f, 0.f, 0.f, 0.f};
        #pragma unroll
        for (int q = 0; q < 8; q++) {
            int t = (q < 4) ? (pass * 4 + q) : (16 + pass * 4 + (q - 4));
            short8v b0 = *(const short8v*)(bbase + (size_t)(t * 2 + 0) * 512);
            short8v b1 = *(const short8v*)(bbase + (size_t)(t * 2 + 1) * 512);
            wacc[q] = __builtin_amdgcn_mfma_f32_16x16x32_bf16(A0, b0, wacc[q], 0, 0, 0);
            wacc[q] = __builtin_amdgcn_mfma_f32_16x16x32_bf16(A1, b1, wacc[q], 0, 0, 0);
        }
        #pragma unroll
        for (int q = 0; q < 4; q++) {
            int t = pass * 4 + q;
            #pragma unroll
            for (int rr = 0; rr < 4; rr++) {
                Wq[(size_t)(jbase + rr) * 256 + t * 16 + col] =
                    cvt_pk_bf16(wacc[q][rr], wacc[q + 4][rr]);
            }
        }
    }
}

// ---------------- tier A gather: edge-major, 4-edge unrolled ----------------
__global__ __launch_bounds__(256, 4) void k_gather_em(
    const int* __restrict__ off, const float4* __restrict__ up,
    const int* __restrict__ sp, const unsigned int* __restrict__ Wq,
    const float* __restrict__ y0, const float* __restrict__ y1, int NP,
    float* __restrict__ agg_s, float* __restrict__ agg_v) {
    const int r = blockIdx.x;
    const int tid = threadIdx.x;
    const int half = tid >> 7;
    const int c = tid & 127;
    const int start = off[r];
    const int end = off[r + 1];

    float accs = 0.f, av0 = 0.f, av1 = 0.f, av2 = 0.f;
    const float SQ3 = 1.7320508075688772f;

    auto proc = [&](unsigned wq, float4 u, int s) {
        float wa = bf2f((unsigned short)(wq & 0xFFFFu));
        float wb = bf2f((unsigned short)(wq >> 16));
        if (half == 0) {
            float f = y0[(size_t)s * CC + c];
            accs += f * wa;
            float bb = f * wb * SQ3;
            av0 += bb * u.x; av1 += bb * u.y; av2 += bb * u.z;
        } else {
            float f0 = y1[0 * NP + s * CC + c];
            float f1 = y1[1 * NP + s * CC + c];
            float f2 = y1[2 * NP + s * CC + c];
            accs += (f0 * u.x + f1 * u.y + f2 * u.z) * wa;
            av0 += f0 * wb; av1 += f1 * wb; av2 += f2 * wb;
        }
    };

    int j = start;
    for (; j + 4 <= end; j += 4) {
        unsigned wq0 = Wq[(size_t)(j + 0) * 256 + tid];
        unsigned wq1 = Wq[(size_t)(j + 1) * 256 + tid];
        unsigned wq2 = Wq[(size_t)(j + 2) * 256 + tid];
        unsigned wq3 = Wq[(size_t)(j + 3) * 256 + tid];
        float4 u0 = up[j + 0], u1 = up[j + 1], u2 = up[j + 2], u3 = up[j + 3];
        int s0 = __builtin_amdgcn_readfirstlane(sp[j + 0]);
        int s1 = __builtin_amdgcn_readfirstlane(sp[j + 1]);
        int s2 = __builtin_amdgcn_readfirstlane(sp[j + 2]);
        int s3 = __builtin_amdgcn_readfirstlane(sp[j + 3]);
        proc(wq0, u0, s0);
        proc(wq1, u1, s1);
        proc(wq2, u2, s2);
        proc(wq3, u3, s3);
    }
    for (; j < end; j++) {
        unsigned wq = Wq[(size_t)j * 256 + tid];
        float4 u = up[j];
        int s = __builtin_amdgcn_readfirstlane(sp[j]);
        proc(wq, u, s);
    }

    agg_s[(size_t)r * 256 + tid] = accs;
    float* o = agg_v + ((size_t)r * 256 + tid) * 3;
    o[0] = av0; o[1] = av1; o[2] = av2;
}

// ---------------- tier B: VALU writer (grouped layout) + its gather ----------------
__global__ __launch_bounds__(256) void k_mlp_wp(
    const float* __restrict__ rb, const int* __restrict__ elist,
    const float* __restrict__ w0T, const float* __restrict__ w1T,
    const float* __restrict__ w2T, const float* __restrict__ w3T,
    unsigned short* __restrict__ Wp, int E_) {
    int p = blockIdx.x * blockDim.x + threadIdx.x;
    if (p >= E_) return;
    int e = elist[p];
    const int c0 = blockIdx.y * 128;

    float4 a[16];
    mlp_body(rb, e, w0T, w1T, w2T, a);

    const size_t E4 = (size_t)E_ * 4;
    for (int c = c0; c < c0 + 128; c += 8) {
        float s[8];
        #pragma unroll
        for (int q = 0; q < 8; q++) {
            const float* rp = w3T + (size_t)(c + q) * 64;
            float t0 = 0.f, t1 = 0.f, t2 = 0.f, t3 = 0.f;
            #pragma unroll
            for (int k = 0; k < 16; k++) {
                float4 h = a[k];
                t0 += h.x * rp[4 * k + 0];
                t1 += h.y * rp[4 * k + 1];
                t2 += h.z * rp[4 * k + 2];
                t3 += h.w * rp[4 * k + 3];
            }
            s[q] = (t0 + t1) + (t2 + t3);
        }
        ushort4 pk0 = make_ushort4(f2bf(s[0]), f2bf(s[1]), f2bf(s[2]), f2bf(s[3]));
        ushort4 pk1 = make_ushort4(f2bf(s[4]), f2bf(s[5]), f2bf(s[6]), f2bf(s[7]));
        *(ushort4*)(Wp + (size_t)(c >> 2) * E4 + (size_t)p * 4) = pk0;
        *(ushort4*)(Wp + (size_t)((c >> 2) + 1) * E4 + (size_t)p * 4) = pk1;
    }
}

__global__ __launch_bounds__(512, 2) void k_gather_wg(
    const int* __restrict__ off, const int* __restrict__ elist,
    const int* __restrict__ snd, const float* __restrict__ evec,
    const unsigned short* __restrict__ Wp, int E_,
    const float* __restrict__ y0, const float* __restrict__ y1, int NP,
    float* __restrict__ agg_s, float* __restrict__ agg_v) {
    const int r = blockIdx.x;
    const int tid = threadIdx.x;
    const int part = tid >> 7;
    const int c = tid & 127;

    const int start = off[r];
    const int end = off[r + 1];

    const unsigned short* __restrict__ wstream =
        Wp + (size_t)(tid >> 2) * ((size_t)E_ * 4) + (tid & 3);

    float acc0 = 0.f, acc1 = 0.f, acc2 = 0.f;
    const float SQ3 = 1.7320508075688772f;

    #pragma unroll 2
    for (int j = start; j < end; j++) {
        int e = elist[j];
        e = __builtin_amdgcn_readfirstlane(e);
        int s = snd[e];
        s = __builtin_amdgcn_readfirstlane(s);

        float e0 = evec[(size_t)e * 3 + 0];
        float e1 = evec[(size_t)e * 3 + 1];
        float e2 = evec[(size_t)e * 3 + 2];
        float rn = sqrtf(e0 * e0 + e1 * e1 + e2 * e2);
        float inv = 1.0f / fmaxf(rn, 1e-12f);
        float ux = e0 * inv, uy = e1 * inv, uz = e2 * inv;

        float w = bf2f(wstream[(size_t)j * 4]);

        if (part == 0) {
            acc0 += y0[(size_t)s * CC + c] * w;
        } else if (part == 1) {
            float f = y1[0 * NP + s * CC + c] * ux
                    + y1[1 * NP + s * CC + c] * uy
                    + y1[2 * NP + s * CC + c] * uz;
            acc0 += f * w;
        } else if (part == 2) {
            float bb = y0[(size_t)s * CC + c] * w * SQ3;
            acc0 += bb * ux; acc1 += bb * uy; acc2 += bb * uz;
        } else {
            acc0 += y1[0 * NP + s * CC + c] * w;
            acc1 += y1[1 * NP + s * CC + c] * w;
            acc2 += y1[2 * NP + s * CC + c] * w;
        }
    }

    if (part == 0) {
        agg_s[(size_t)r * 256 + c] = acc0;
    } else if (part == 1) {
        agg_s[(size_t)r * 256 + 128 + c] = acc0;
    } else if (part == 2) {
        float* o = agg_v + ((size_t)r * 256 + c) * 3;
        o[0] = acc0; o[1] = acc1; o[2] = acc2;
    } else {
        float* o = agg_v + ((size_t)r * 256 + 128 + c) * 3;
        o[0] = acc0; o[1] = acc1; o[2] = acc2;
    }
}

// ---------------- tier C: f32 h2 fallback ----------------
__global__ void k_mlp(const float* __restrict__ rb,
                      const float* __restrict__ w0T, const float* __restrict__ w1T,
                      const float* __restrict__ w2T,
                      float* __restrict__ h2, int E_) {
    int e = blockIdx.x * blockDim.x + threadIdx.x;
    if (e >= E_) return;
    float4 a[16];
    mlp_body(rb, e, w0T, w1T, w2T, a);
    float4* out = (float4*)(h2 + (size_t)e * HH);
    #pragma unroll
    for (int q = 0; q < 16; q++) out[q] = a[q];
}

__global__ __launch_bounds__(512, 1) void k_gather_h2(
    const int* __restrict__ off, const int* __restrict__ elist,
    const int* __restrict__ snd, const float* __restrict__ evec,
    const float* __restrict__ h2, const float* __restrict__ w3T,
    const float* __restrict__ y0, const float* __restrict__ y1, int NP,
    float* __restrict__ agg_s, float* __restrict__ agg_v) {
    const int r = blockIdx.x;
    const int tid = threadIdx.x;
    const int part = tid >> 7;
    const int c = tid & 127;

    const float4* wp = (const float4*)(w3T + (size_t)tid * 64);
    const int start = off[r];
    const int end = off[r + 1];

    float acc0 = 0.f, acc1 = 0.f, acc2 = 0.f;
    const float SQ3 = 1.7320508075688772f;

    for (int j = start; j < end; j++) {
        int e = elist[j];
        e = __builtin_amdgcn_readfirstlane(e);
        int s = snd[e];
        s = __builtin_amdgcn_readfirstlane(s);

        float e0 = evec[(size_t)e * 3 + 0];
        float e1 = evec[(size_t)e * 3 + 1];
        float e2 = evec[(size_t)e * 3 + 2];
        float rn = sqrtf(e0 * e0 + e1 * e1 + e2 * e2);
        float inv = 1.0f / fmaxf(rn, 1e-12f);
        float ux = e0 * inv, uy = e1 * inv, uz = e2 * inv;

        const float4* __restrict__ hp = (const float4*)(h2 + ((size_t)e << 6));
        float ws0 = 0.f, ws1 = 0.f, ws2 = 0.f, ws3 = 0.f;
        #pragma unroll
        for (int k = 0; k < 16; k++) {
            float4 h = hp[k];
            float4 wv = wp[k];
            ws0 += h.x * wv.x; ws1 += h.y * wv.y; ws2 += h.z * wv.z; ws3 += h.w * wv.w;
        }
        float w = (ws0 + ws1) + (ws2 + ws3);

        if (part == 0) {
            acc0 += y0[(size_t)s * CC + c] * w;
        } else if (part == 1) {
            float f = y1[0 * NP + s * CC + c] * ux
                    + y1[1 * NP + s * CC + c] * uy
                    + y1[2 * NP + s * CC + c] * uz;
            acc0 += f * w;
        } else if (part == 2) {
            float bb = y0[(size_t)s * CC + c] * w * SQ3;
            acc0 += bb * ux; acc1 += bb * uy; acc2 += bb * uz;
        } else {
            acc0 += y1[0 * NP + s * CC + c] * w;
            acc1 += y1[1 * NP + s * CC + c] * w;
            acc2 += y1[2 * NP + s * CC + c] * w;
        }
    }

    if (part == 0) {
        agg_s[(size_t)r * 256 + c] = acc0;
    } else if (part == 1) {
        agg_s[(size_t)r * 256 + 128 + c] = acc0;
    } else if (part == 2) {
        float* o = agg_v + ((size_t)r * 256 + c) * 3;
        o[0] = acc0; o[1] = acc1; o[2] = acc2;
    } else {
        float* o = agg_v + ((size_t)r * 256 + 128 + c) * 3;
        o[0] = acc0; o[1] = acc1; o[2] = acc2;
    }
}

// ---------------- node output (species-sorted, coalesced W) ----------------
__global__ __launch_bounds__(256) void k_node_out(
    const float* __restrict__ agg_s, const float* __restrict__ agg_v,
    const float* __restrict__ xs, const float* __restrict__ xv,
    const float* __restrict__ W20, const float* __restrict__ W21,
    const float* __restrict__ Wsk0, const float* __restrict__ Wsk1,
    const int* __restrict__ nlist, const int* __restrict__ species,
    float* __restrict__ out, int N) {
    const int tid = threadIdx.x;
    const int b0 = blockIdx.x * 4;
    const int nid0 = nlist[min(b0 + 0, N - 1)];
    const int nid1 = nlist[min(b0 + 1, N - 1)];
    const int nid2 = nlist[min(b0 + 2, N - 1)];
    const int nid3 = nlist[min(b0 + 3, N - 1)];

    __shared__ float as_l[4 * 256];
    __shared__ float av_l[4 * 768];
    __shared__ float xs_l[4 * 128];
    __shared__ float xv_l[4 * 384];
    __shared__ float s_l[4 * 256];

    {
        as_l[0 * 256 + tid] = agg_s[(size_t)nid0 * 256 + tid];
        as_l[1 * 256 + tid] = agg_s[(size_t)nid1 * 256 + tid];
        as_l[2 * 256 + tid] = agg_s[(size_t)nid2 * 256 + tid];
        as_l[3 * 256 + tid] = agg_s[(size_t)nid3 * 256 + tid];
        for (int i = tid; i < 768; i += 256) {
            av_l[0 * 768 + i] = agg_v[(size_t)nid0 * 768 + i];
            av_l[1 * 768 + i] = agg_v[(size_t)nid1 * 768 + i];
            av_l[2 * 768 + i] = agg_v[(size_t)nid2 * 768 + i];
            av_l[3 * 768 + i] = agg_v[(size_t)nid3 * 768 + i];
        }
        if (tid < 128) {
            xs_l[0 * 128 + tid] = xs[(size_t)nid0 * 128 + tid];
            xs_l[1 * 128 + tid] = xs[(size_t)nid1 * 128 + tid];
            xs_l[2 * 128 + tid] = xs[(size_t)nid2 * 128 + tid];
            xs_l[3 * 128 + tid] = xs[(size_t)nid3 * 128 + tid];
        }
        for (int i = tid; i < 384; i += 256) {
            xv_l[0 * 384 + i] = xv[(size_t)nid0 * 384 + i];
            xv_l[1 * 384 + i] = xv[(size_t)nid1 * 384 + i];
            xv_l[2 * 384 + i] = xv[(size_t)nid2 * 384 + i];
            xv_l[3 * 384 + i] = xv[(size_t)nid3 * 384 + i];
        }
    }
    const int sp0 = species[nid0], sp1 = species[nid1];
    const int sp2 = species[nid2], sp3 = species[nid3];
    const bool uni = (sp0 == sp1) && (sp1 == sp2) && (sp2 == sp3);
    __syncthreads();

    const float k_mat = 0.17677669529663687f * 0.0625f; // inv_nb * inv_2c
    const float inv_c = 0.08838834764831845f;

    {
        const int d = tid;
        float am[4] = {0.f, 0.f, 0.f, 0.f};
        for (int cc = 0; cc < 256; cc++) {
            float w = W20[cc * 256 + d];
            #pragma unroll
            for (int n = 0; n < 4; n++) am[n] += as_l[n * 256 + cc] * w;
        }
        float ak[4] = {0.f, 0.f, 0.f, 0.f};
        if (uni) {
            for (int cc = 0; cc < 128; cc++) {
                float w = Wsk0[((size_t)sp0 * 128 + cc) * 256 + d];
                #pragma unroll
                for (int n = 0; n < 4; n++) ak[n] += xs_l[n * 128 + cc] * w;
            }
        } else {
            for (int cc = 0; cc < 128; cc++) {
                float w0v = Wsk0[((size_t)sp0 * 128 + cc) * 256 + d];
                float w1v = Wsk0[((size_t)sp1 * 128 + cc) * 256 + d];
                float w2v = Wsk0[((size_t)sp2 * 128 + cc) * 256 + d];
                float w3v = Wsk0[((size_t)sp3 * 128 + cc) * 256 + d];
                ak[0] += xs_l[0 * 128 + cc] * w0v;
                ak[1] += xs_l[1 * 128 + cc] * w1v;
                ak[2] += xs_l[2 * 128 + cc] * w2v;
                ak[3] += xs_l[3 * 128 + cc] * w3v;
            }
        }
        #pragma unroll
        for (int n = 0; n < 4; n++) s_l[n * 256 + d] = am[n] * k_mat + ak[n] * inv_c;
    }
    __syncthreads();

    if (tid < 128) {
        out[(size_t)nid0 * 512 + tid] = silu_f(s_l[0 * 256 + tid]);
        out[(size_t)nid1 * 512 + tid] = silu_f(s_l[1 * 256 + tid]);
        out[(size_t)nid2 * 512 + tid] = silu_f(s_l[2 * 256 + tid]);
        out[(size_t)nid3 * 512 + tid] = silu_f(s_l[3 * 256 + tid]);
    }

    {
        const int d = tid & 127;
        const int half = tid >> 7;
        const int nA = half ? nid2 : nid0;
        const int nB = half ? nid3 : nid1;
        const int sA = half ? sp2 : sp0;
        const int sB = half ? sp3 : sp1;
        const int la = half ? 2 : 0;
        const int lb = half ? 3 : 1;

        float am[2][3] = {};
        for (int cc = 0; cc < 256; cc++) {
            float w = W21[cc * 128 + d];
            #pragma unroll
            for (int i = 0; i < 3; i++) {
                am[0][i] += av_l[la * 768 + cc * 3 + i] * w;
                am[1][i] += av_l[lb * 768 + cc * 3 + i] * w;
            }
        }
        float ak[2][3] = {};
        if (uni) {
            for (int cc = 0; cc < 128; cc++) {
                float w = Wsk1[((size_t)sp0 * 128 + cc) * 128 + d];
                #pragma unroll
                for (int i = 0; i < 3; i++) {
                    ak[0][i] += xv_l[la * 384 + cc * 3 + i] * w;
                    ak[1][i] += xv_l[lb * 384 + cc * 3 + i] * w;
                }
            }
        } else {
            for (int cc = 0; cc < 128; cc++) {
                float wA = Wsk1[((size_t)sA * 128 + cc) * 128 + d];
                float wB = Wsk1[((size_t)sB * 128 + cc) * 128 + d];
                #pragma unroll
                for (int i = 0; i < 3; i++) {
                    ak[0][i] += xv_l[la * 384 + cc * 3 + i] * wA;
                    ak[1][i] += xv_l[lb * 384 + cc * 3 + i] * wB;
                }
            }
        }
        float gA = silu_f(s_l[la * 256 + 128 + d]);
        float gB = silu_f(s_l[lb * 256 + 128 + d]);
        float* oA = out + (size_t)nA * 512 + 128 + d * 3;
        float* oB = out + (size_t)nB * 512 + 128 + d * 3;
        #pragma unroll
        for (int i = 0; i < 3; i++) {
            oA[i] = (am[0][i] * k_mat + ak[0][i] * inv_c) * gA;
            oB[i] = (am[1][i] * k_mat + ak[1][i] * inv_c) * gB;
        }
    }
}

extern "C" void kernel_launch(void* const* d_in, const int* in_sizes, int n_in,
                              void* d_out, int out_size, void* d_ws, size_t ws_size,
                              hipStream_t stream) {
    const float* xs   = (const float*)d_in[0];
    const float* xv   = (const float*)d_in[1];
    const float* evec = (const float*)d_in[2];
    const float* rb   = (const float*)d_in[3];
    const float* W10  = (const float*)d_in[4];
    const float* W11  = (const float*)d_in[5];
    const float* w0   = (const float*)d_in[6];
    const float* w1   = (const float*)d_in[7];
    const float* w2   = (const float*)d_in[8];
    const float* w3   = (const float*)d_in[9];
    const float* W20  = (const float*)d_in[10];
    const float* W21  = (const float*)d_in[11];
    const float* Wsk0 = (const float*)d_in[12];
    const float* Wsk1 = (const float*)d_in[13];
    const int* species = (const int*)d_in[14];
    const int* snd = (const int*)d_in[15];
    const int* rcv = (const int*)d_in[16];

    const int N = in_sizes[0] / CC;   // 4000
    const int E = in_sizes[2] / 3;    // 128000
    const int NP = N * CC;
    int NS = in_sizes[12] / (CC * 2 * CC);   // 5
    if (NS < 1) NS = 1;
    if (NS > 63) NS = 63;

    float* ws   = (float*)d_ws;
    float* y0   = ws;
    float* y1   = y0 + (size_t)N * CC;
    float* aggs = y1 + (size_t)N * CC * 3;
    float* aggv = aggs + (size_t)N * 2 * CC;
    float* w0T  = aggv + (size_t)N * 2 * CC * 3;
    float* w1T  = w0T + 64 * 8;
    float* w2T  = w1T + 64 * 64;
    float* w3T  = w2T + 64 * 64;
    unsigned short* w3bs = (unsigned short*)(w3T + 512 * 64);
    unsigned short* w0b  = w3bs + 32768;
    unsigned short* w1b  = w0b + 2048;
    unsigned short* w2b  = w1b + 4096;
    int*   deg  = (int*)(w2b + 4096);
    int*   cur  = deg + 4096;
    int*   scnt = cur + 4096;                // 64
    int*   soff = scnt + 64;                 // 72
    int*   scur = soff + 72;                 // 64
    int*   off  = scur + 64;                 // 4160
    int*   elist = off + 4160;
    float4* up  = (float4*)(elist + E);
    int*   sp   = (int*)(up + E);
    int*   nlist = sp + E;                   // N
    void*  big  = (void*)(nlist + N);

    size_t base_bytes = (size_t)((char*)big - (char*)d_ws);
    size_t wq_bytes   = (size_t)E * 256 * sizeof(unsigned int);
    size_t need_A = base_bytes + wq_bytes;
    size_t need_B = base_bytes + (size_t)E * WDIM * sizeof(unsigned short);

    unsigned int*   Wq  = (unsigned int*)big;
    unsigned short* Wp  = (unsigned short*)big;

    hipMemsetAsync(deg, 0, (4096 + 4096 + 64 + 72 + 64) * sizeof(int), stream);
    hipLaunchKernelGGL(k_prep_hist, dim3((E + 255) / 256), dim3(256), 0, stream,
                       w0, w1, w2, w3, w0T, w1T, w2T, w3T, w3bs, w0b, w1b, w2b,
                       rcv, deg, E, species, scnt, N);
    hipLaunchKernelGGL(k_scan, dim3(1), dim3(1024), 0, stream,
                       deg, off, N, scnt, soff, NS);
    hipLaunchKernelGGL(k_scatter, dim3((E + 255) / 256), dim3(256), 0, stream,
                       rcv, off, cur, elist, E, species, soff, scur, nlist, N);

    if (ws_size >= need_A && (E % 64) == 0 && (N % 2) == 0) {
        const int nblk_mlp = E / 64;
        hipLaunchKernelGGL(k_mlpw3, dim3(nblk_mlp + N / 2), dim3(256), 0, stream,
                           rb, elist, snd, evec, w0b, w1b, w2b, w3bs, Wq, up, sp,
                           E, nblk_mlp, xs, xv, W10, W11, y0, y1, NP);
        hipLaunchKernelGGL(k_gather_em, dim3(N), dim3(256), 0, stream,
                           off, up, sp, Wq, y0, y1, NP, aggs, aggv);
    } else if (ws_size >= need_B) {
        hipLaunchKernelGGL(k_node_lin, dim3((N + 1) / 2), dim3(256), 0, stream,
                           xs, xv, W10, W11, y0, y1, N);
        hipLaunchKernelGGL(k_mlp_wp, dim3((E + 255) / 256, 4), dim3(256), 0, stream,
                           rb, elist, w0T, w1T, w2T, w3T, Wp, E);
        hipLaunchKernelGGL(k_gather_wg, dim3(N), dim3(512), 0, stream,
                           off, elist, snd, evec, Wp, E, y0, y1, NP, aggs, aggv);
    } else {
        hipLaunchKernelGGL(k_node_lin, dim3((N + 1) / 2), dim3(256), 0, stream,
                           xs, xv, W10, W11, y0, y1, N);
        hipLaunchKernelGGL(k_mlp, dim3((E + 255) / 256), dim3(256), 0, stream,
                           rb, w0T, w1T, w2T, (float*)big, E);
        hipLaunchKernelGGL(k_gather_h2, dim3(N), dim3(512), 0, stream,
                           off, elist, snd, evec, (const float*)big, w3T,
                           y0, y1, NP, aggs, aggv);
    }

    hipLaunchKernelGGL(k_node_out, dim3((N + 3) / 4), dim3(256), 0, stream,
                       aggs, aggv, xs, xv, W20, W21, Wsk0, Wsk1, nlist, species,
                       (float*)d_out, N);
}